// Round 1
// baseline (306.353 us; speedup 1.0000x reference)
//
#include <hip/hip_runtime.h>
#include <hip/hip_bf16.h>
#include <cstdint>

typedef __attribute__((ext_vector_type(8))) short short8;
typedef __attribute__((ext_vector_type(4))) float f32x4;

typedef const unsigned int __attribute__((address_space(1)))* gas_ptr;
typedef unsigned int __attribute__((address_space(3)))* las_ptr;

__device__ static inline void async16(const void* g, void* l) {
  __builtin_amdgcn_global_load_lds((gas_ptr)g, (las_ptr)l, 16, 0, 0);
}

__device__ static inline unsigned short f2bf(float f) {
  union { float f; uint32_t u; } v; v.f = f;
  uint32_t u = v.u;
  uint32_t r = (u + 0x7FFFu + ((u >> 16) & 1u)) >> 16;
  return (unsigned short)r;
}
__device__ static inline float bf2f(unsigned short s) {
  union { uint32_t u; float f; } v; v.u = ((uint32_t)s) << 16; return v.f;
}

__device__ static inline float wave_sum(float v) {
  v += __shfl_xor(v, 1);  v += __shfl_xor(v, 2);  v += __shfl_xor(v, 4);
  v += __shfl_xor(v, 8);  v += __shfl_xor(v, 16); v += __shfl_xor(v, 32);
  return v;
}

// ---------------- small utility kernels ----------------

__global__ __launch_bounds__(64) void k_init(float* sc) {
  if (threadIdx.x < 4) sc[threadIdx.x] = 0.0f;
}

// row-normalize weights: w_eff[r] = w[r] / (32*EPS + ||w[r]||), bf16 out, [rows][1024]
__global__ __launch_bounds__(256) void k_wnorm(const float* __restrict__ W,
                                               unsigned short* __restrict__ E, int rows) {
  int row = blockIdx.x * 4 + (threadIdx.x >> 6);
  int l = threadIdx.x & 63;
  if (row >= rows) return;
  const float* wr = W + (size_t)row * 1024;
  float4 v[4];
  float s = 0.f;
  for (int i = 0; i < 4; ++i) {
    v[i] = *(const float4*)(wr + i * 256 + l * 4);
    s += v[i].x * v[i].x + v[i].y * v[i].y + v[i].z * v[i].z + v[i].w * v[i].w;
  }
  s = wave_sum(s);
  float inv = 1.0f / (0.0032f + sqrtf(s));
  unsigned short* er = E + (size_t)row * 1024;
  for (int i = 0; i < 4; ++i) {
    ushort4 o = make_ushort4(f2bf(v[i].x * inv), f2bf(v[i].y * inv),
                             f2bf(v[i].z * inv), f2bf(v[i].w * inv));
    *(ushort4*)(er + i * 256 + l * 4) = o;
  }
}

// build x_ext bf16 [4224][1024]: rows b*1025+s (s<1024 from x, s==1024 sink), rows>=4100 zero
__global__ __launch_bounds__(256) void k_xext(const float* __restrict__ x,
    const float* __restrict__ sink, unsigned short* __restrict__ Xe) {
  int i = blockIdx.x * 256 + threadIdx.x;
  int row = i >> 8;
  int c4 = (i & 255) * 4;
  ushort4 o;
  if (row < 4100) {
    int b = row / 1025, s = row % 1025;
    const float* src = (s < 1024) ? (x + ((size_t)(b * 1024 + s)) * 1024 + c4) : (sink + c4);
    float4 v = *(const float4*)src;
    o = make_ushort4(f2bf(v.x), f2bf(v.y), f2bf(v.z), f2bf(v.w));
  } else {
    o = make_ushort4(0, 0, 0, 0);
  }
  *(ushort4*)(Xe + (size_t)row * 1024 + c4) = o;
}

// sum of row L2 norms (1024 cols) * mult -> atomicAdd(acc)
__global__ __launch_bounds__(256) void k_rownorm(const float* __restrict__ X, int rows,
                                                 float mult, float* __restrict__ acc) {
  int row = blockIdx.x * 4 + (threadIdx.x >> 6);
  int l = threadIdx.x & 63;
  if (row >= rows) return;
  const float* xr = X + (size_t)row * 1024;
  float s = 0.f;
  for (int i = 0; i < 4; ++i) {
    float4 v = *(const float4*)(xr + i * 256 + l * 4);
    s += v.x * v.x + v.y * v.y + v.z * v.z + v.w * v.w;
  }
  s = wave_sum(s);
  if (l == 0) atomicAdd(acc, mult * sqrtf(s));
}

__global__ __launch_bounds__(64) void k_ratio(float* sc) {
  if (threadIdx.x == 0) sc[2] = (sc[0] / 4100.0f) / (sc[1] / 4096.0f);
}

// h (f32) * ratio -> bf16
__global__ __launch_bounds__(256) void k_scalecast(const float* __restrict__ Hs,
    const float* __restrict__ sc, unsigned short* __restrict__ Hb) {
  int i = blockIdx.x * 256 + threadIdx.x;
  float ratio = sc[2];
  float4 v = *(const float4*)(Hs + (size_t)i * 4);
  ushort4 o = make_ushort4(f2bf(v.x * ratio), f2bf(v.y * ratio),
                           f2bf(v.z * ratio), f2bf(v.w * ratio));
  *(ushort4*)(Hb + (size_t)i * 4) = o;
}

// zero K pad rows 1025..1087 and Vt pad cols 1025..1087
__global__ __launch_bounds__(256) void k_zeropad(unsigned short* __restrict__ Kh,
                                                 unsigned short* __restrict__ Vt) {
  int i = blockIdx.x * 256 + threadIdx.x;
  const int total = 64 * 63 * 64;
  if (i >= total) return;
  int bh = i / (63 * 64);
  int rest = i % (63 * 64);
  int row = rest / 64, d = rest % 64;
  Kh[((size_t)bh * 1088 + 1025 + row) * 64 + d] = 0;
  Vt[((size_t)bh * 64 + d) * 1088 + 1025 + row] = 0;
}

// ---------------- GEMM: C[M][N] = A[M][K] * B[N][K]^T  (bf16 in, f32 out) ----------------
__global__ __launch_bounds__(256) void k_gemm(const unsigned short* __restrict__ A,
                                              const unsigned short* __restrict__ B,
                                              float* __restrict__ C, int M, int N, int K) {
  __shared__ __align__(16) short Al[128 * 64];
  __shared__ __align__(16) short Bl[128 * 64];
  const int t = threadIdx.x, l = t & 63, w = t >> 6;
  const int r = l & 15, g = l >> 4;
  const int wm = w >> 1, wn = w & 1;
  const size_t tm = (size_t)blockIdx.y * 128, tn = (size_t)blockIdx.x * 128;
  f32x4 acc[4][4] = {};
  for (int kt = 0; kt < K; kt += 64) {
    __syncthreads();
    for (int i = 0; i < 4; ++i) {
      int c = i * 256 + t;
      int row = c >> 3, k8 = (c & 7) * 8;
      async16(A + (tm + row) * K + kt + k8, Al + (i * 256 + w * 64) * 8);
    }
    for (int i = 0; i < 4; ++i) {
      int c = i * 256 + t;
      int row = c >> 3, k8 = (c & 7) * 8;
      async16(B + (tn + row) * K + kt + k8, Bl + (i * 256 + w * 64) * 8);
    }
    __syncthreads();
    for (int ks = 0; ks < 2; ++ks) {
      short8 af[4], bfr[4];
      for (int mi = 0; mi < 4; ++mi)
        af[mi] = *(const short8*)(Al + (wm * 64 + mi * 16 + r) * 64 + ks * 32 + g * 8);
      for (int ni = 0; ni < 4; ++ni)
        bfr[ni] = *(const short8*)(Bl + (wn * 64 + ni * 16 + r) * 64 + ks * 32 + g * 8);
      for (int mi = 0; mi < 4; ++mi)
        for (int ni = 0; ni < 4; ++ni)
          acc[mi][ni] = __builtin_amdgcn_mfma_f32_16x16x32_bf16(af[mi], bfr[ni], acc[mi][ni], 0, 0, 0);
    }
  }
  for (int mi = 0; mi < 4; ++mi)
    for (int ni = 0; ni < 4; ++ni)
      for (int j = 0; j < 4; ++j) {
        size_t row = tm + wm * 64 + mi * 16 + g * 4 + j;
        size_t col = tn + wn * 64 + ni * 16 + r;
        C[row * (size_t)N + col] = acc[mi][ni][j];
      }
}

// ---------------- qkv postprocess: rope + head L2-normalize, scatter to head-major ----------------
__global__ __launch_bounds__(256) void k_postproc(const float* __restrict__ qkv,
    const float* __restrict__ re,
    unsigned short* __restrict__ Qh, unsigned short* __restrict__ Kh,
    unsigned short* __restrict__ Vt) {
  const int rIdx = blockIdx.x;           // 0..4099 = b*1025+s
  const int b = rIdx / 1025, s = rIdx % 1025;
  const int w = threadIdx.x >> 6, l = threadIdx.x & 63;
  const float* rowp = qkv + (size_t)rIdx * 3072;
  float cs = 1.f, sn = 0.f, sgn = 1.f;
  if (s < 1024 && l < 32) {
    float f = re[s * 32 + l];
    cs = cosf(f); sn = sinf(f);
    sgn = (l < 16) ? -1.f : 1.f;
  }
  for (int hi = 0; hi < 4; ++hi) {
    int h = w * 4 + hi;
    float q = rowp[h * 64 + l];
    float k = rowp[1024 + h * 64 + l];
    float v = rowp[2048 + h * 64 + l];
    float qp = __shfl_xor(q, 16);
    float kp = __shfl_xor(k, 16);
    float q2 = q * cs + sgn * qp * sn;
    float k2 = k * cs + sgn * kp * sn;
    float nq = wave_sum(q2 * q2);
    float nk = wave_sum(k2 * k2);
    q2 /= sqrtf(nq);
    k2 /= sqrtf(nk);
    size_t bh = (size_t)(b * 16 + h);
    Qh[(bh * 1088 + s) * 64 + l] = f2bf(q2);
    Kh[(bh * 1088 + s) * 64 + l] = f2bf(k2);
    Vt[(bh * 64 + l) * 1088 + s] = f2bf(v);
  }
}

// ---------------- attention: causal + sink column, no-max softmax ----------------
__global__ __launch_bounds__(256) void k_attn(const unsigned short* __restrict__ Qh,
    const unsigned short* __restrict__ Kh, const unsigned short* __restrict__ Vt,
    float* __restrict__ H) {
  __shared__ __align__(16) short Kl[64 * 64];
  __shared__ __align__(16) short Vl[64 * 64];
  __shared__ __align__(16) short Pl[4 * 16 * 64];
  const int qb = blockIdx.x, bh = blockIdx.y;
  const int b = bh >> 4, hh = bh & 15;
  const int t = threadIdx.x, l = t & 63, w = t >> 6;
  const int r = l & 15, g = l >> 4;
  const int qrow0 = qb * 64 + w * 16;
  short8 qf[2];
  for (int ks = 0; ks < 2; ++ks)
    qf[ks] = *(const short8*)(Qh + ((size_t)bh * 1088 + qrow0 + r) * 64 + ks * 32 + g * 8);
  f32x4 oacc[4] = {};
  float lsum[4] = {0.f, 0.f, 0.f, 0.f};
  for (int kti = 0; kti <= qb + 1; ++kti) {
    const int kt = (kti <= qb) ? kti : 16;   // causal tiles then sink tile
    __syncthreads();
    for (int i = 0; i < 2; ++i) {
      int c = i * 256 + t;
      int rw = c >> 3, o8 = (c & 7) * 8;
      async16(Kh + ((size_t)bh * 1088 + kt * 64 + rw) * 64 + o8, Kl + (i * 256 + w * 64) * 8);
      async16(Vt + ((size_t)bh * 64 + rw) * 1088 + kt * 64 + o8, Vl + (i * 256 + w * 64) * 8);
    }
    __syncthreads();
    for (int nc = 0; nc < 4; ++nc) {
      f32x4 sc = {};
      for (int ks = 0; ks < 2; ++ks) {
        short8 kf = *(const short8*)(Kl + (nc * 16 + r) * 64 + ks * 32 + g * 8);
        sc = __builtin_amdgcn_mfma_f32_16x16x32_bf16(qf[ks], kf, sc, 0, 0, 0);
      }
      const int col = kt * 64 + nc * 16 + r;
      for (int j = 0; j < 4; ++j) {
        const int row = qrow0 + g * 4 + j;
        const bool valid = (col <= row) || (col == 1024);
        float p = valid ? __expf(sc[j]) : 0.0f;
        unsigned short pb = f2bf(p);
        lsum[j] += bf2f(pb);
        Pl[(w * 16 + g * 4 + j) * 64 + nc * 16 + r] = (short)pb;
      }
    }
    __syncthreads();
    for (int ks = 0; ks < 2; ++ks) {
      short8 pf = *(const short8*)(Pl + (w * 16 + r) * 64 + ks * 32 + g * 8);
      for (int nd = 0; nd < 4; ++nd) {
        short8 vf = *(const short8*)(Vl + (nd * 16 + r) * 64 + ks * 32 + g * 8);
        oacc[nd] = __builtin_amdgcn_mfma_f32_16x16x32_bf16(pf, vf, oacc[nd], 0, 0, 0);
      }
    }
  }
  for (int j = 0; j < 4; ++j) {
    float v = lsum[j];
    v += __shfl_xor(v, 1); v += __shfl_xor(v, 2);
    v += __shfl_xor(v, 4); v += __shfl_xor(v, 8);
    lsum[j] = v;
  }
  for (int nd = 0; nd < 4; ++nd)
    for (int j = 0; j < 4; ++j) {
      int s = qrow0 + g * 4 + j;
      H[((size_t)(b * 1024 + s)) * 1024 + hh * 64 + nd * 16 + r] = oacc[nd][j] / lsum[j];
    }
}

// ---------------- launcher ----------------
extern "C" void kernel_launch(void* const* d_in, const int* in_sizes, int n_in,
                              void* d_out, int out_size, void* d_ws, size_t ws_size,
                              hipStream_t stream) {
  const float* x     = (const float*)d_in[0];
  const float* re    = (const float*)d_in[1];
  const float* w_qkv = (const float*)d_in[3];
  const float* w_out = (const float*)d_in[4];
  const float* sink  = (const float*)d_in[5];
  char* ws = (char*)d_ws;

  unsigned short* Wq = (unsigned short*)(ws + 0);          // 3072*1024 bf16
  unsigned short* Wo = (unsigned short*)(ws + 6291456);    // 1024*1024 bf16
  unsigned short* Xe = (unsigned short*)(ws + 8388608);    // 4224*1024 bf16
  float*          qkv = (float*)(ws + 17039360);           // 4224*3072 f32
  float*          Hs  = (float*)(ws + 17039360);           // reuse: 4096*1024 f32
  unsigned short* Hb  = (unsigned short*)(ws + 17039360 + 16777216); // 4096*1024 bf16
  unsigned short* Qh = (unsigned short*)(ws + 68943872);   // 64*1088*64 bf16
  unsigned short* Kh = (unsigned short*)(ws + 77856768);   // 64*1088*64 bf16
  unsigned short* Vt = (unsigned short*)(ws + 86769664);   // 64*64*1088 bf16
  float*          sc = (float*)(ws + 95682560);            // scalars
  float*          out = (float*)d_out;

  k_init<<<1, 64, 0, stream>>>(sc);
  k_wnorm<<<768, 256, 0, stream>>>(w_qkv, Wq, 3072);
  k_wnorm<<<256, 256, 0, stream>>>(w_out, Wo, 1024);
  k_xext<<<4224, 256, 0, stream>>>(x, sink, Xe);
  k_rownorm<<<1024, 256, 0, stream>>>(x, 4096, 1.0f, sc + 0);
  k_rownorm<<<1, 256, 0, stream>>>(sink, 1, 4.0f, sc + 0);
  k_gemm<<<dim3(24, 33), 256, 0, stream>>>(Xe, Wq, qkv, 4224, 3072, 1024);
  k_postproc<<<4100, 256, 0, stream>>>(qkv, re, Qh, Kh, Vt);
  k_zeropad<<<(64 * 63 * 64 + 255) / 256, 256, 0, stream>>>(Kh, Vt);
  k_attn<<<dim3(16, 64), 256, 0, stream>>>(Qh, Kh, Vt, Hs);
  k_rownorm<<<1024, 256, 0, stream>>>(Hs, 4096, 1.0f, sc + 1);
  k_ratio<<<1, 64, 0, stream>>>(sc);
  k_scalecast<<<4096, 256, 0, stream>>>(Hs, sc, Hb);
  k_gemm<<<dim3(8, 32), 256, 0, stream>>>(Hb, Wo, out, 4096, 1024, 1024);
}

// Round 2
// 274.974 us; speedup vs baseline: 1.1141x; 1.1141x over previous
//
#include <hip/hip_runtime.h>
#include <hip/hip_bf16.h>
#include <cstdint>

typedef __attribute__((ext_vector_type(8))) short short8;
typedef __attribute__((ext_vector_type(4))) float f32x4;

typedef const unsigned int __attribute__((address_space(1)))* gas_ptr;
typedef unsigned int __attribute__((address_space(3)))* las_ptr;

__device__ static inline void async16(const void* g, void* l) {
  __builtin_amdgcn_global_load_lds((gas_ptr)g, (las_ptr)l, 16, 0, 0);
}

__device__ static inline unsigned short f2bf(float f) {
  union { float f; uint32_t u; } v; v.f = f;
  uint32_t u = v.u;
  uint32_t r = (u + 0x7FFFu + ((u >> 16) & 1u)) >> 16;
  return (unsigned short)r;
}
__device__ static inline float bf2f(unsigned short s) {
  union { uint32_t u; float f; } v; v.u = ((uint32_t)s) << 16; return v.f;
}

__device__ static inline float wave_sum(float v) {
  v += __shfl_xor(v, 1);  v += __shfl_xor(v, 2);  v += __shfl_xor(v, 4);
  v += __shfl_xor(v, 8);  v += __shfl_xor(v, 16); v += __shfl_xor(v, 32);
  return v;
}

// ---------------- small utility kernels ----------------

__global__ __launch_bounds__(64) void k_init(float* sc) {
  if (threadIdx.x < 4) sc[threadIdx.x] = 0.0f;
}

// row-normalize weights: w_eff[r] = w[r] / (32*EPS + ||w[r]||), bf16 out, [rows][1024]
__global__ __launch_bounds__(256) void k_wnorm(const float* __restrict__ W,
                                               unsigned short* __restrict__ E, int rows) {
  int row = blockIdx.x * 4 + (threadIdx.x >> 6);
  int l = threadIdx.x & 63;
  if (row >= rows) return;
  const float* wr = W + (size_t)row * 1024;
  float4 v[4];
  float s = 0.f;
  for (int i = 0; i < 4; ++i) {
    v[i] = *(const float4*)(wr + i * 256 + l * 4);
    s += v[i].x * v[i].x + v[i].y * v[i].y + v[i].z * v[i].z + v[i].w * v[i].w;
  }
  s = wave_sum(s);
  float inv = 1.0f / (0.0032f + sqrtf(s));
  unsigned short* er = E + (size_t)row * 1024;
  for (int i = 0; i < 4; ++i) {
    ushort4 o = make_ushort4(f2bf(v[i].x * inv), f2bf(v[i].y * inv),
                             f2bf(v[i].z * inv), f2bf(v[i].w * inv));
    *(ushort4*)(er + i * 256 + l * 4) = o;
  }
}

// build x_ext bf16 [4224][1024]: rows b*1025+s (s<1024 from x, s==1024 sink), rows>=4100 zero
__global__ __launch_bounds__(256) void k_xext(const float* __restrict__ x,
    const float* __restrict__ sink, unsigned short* __restrict__ Xe) {
  int i = blockIdx.x * 256 + threadIdx.x;
  int row = i >> 8;
  int c4 = (i & 255) * 4;
  ushort4 o;
  if (row < 4100) {
    int b = row / 1025, s = row % 1025;
    const float* src = (s < 1024) ? (x + ((size_t)(b * 1024 + s)) * 1024 + c4) : (sink + c4);
    float4 v = *(const float4*)src;
    o = make_ushort4(f2bf(v.x), f2bf(v.y), f2bf(v.z), f2bf(v.w));
  } else {
    o = make_ushort4(0, 0, 0, 0);
  }
  *(ushort4*)(Xe + (size_t)row * 1024 + c4) = o;
}

// sum of row L2 norms (1024 cols) * mult -> atomicAdd(acc)
__global__ __launch_bounds__(256) void k_rownorm(const float* __restrict__ X, int rows,
                                                 float mult, float* __restrict__ acc) {
  int row = blockIdx.x * 4 + (threadIdx.x >> 6);
  int l = threadIdx.x & 63;
  if (row >= rows) return;
  const float* xr = X + (size_t)row * 1024;
  float s = 0.f;
  for (int i = 0; i < 4; ++i) {
    float4 v = *(const float4*)(xr + i * 256 + l * 4);
    s += v.x * v.x + v.y * v.y + v.z * v.z + v.w * v.w;
  }
  s = wave_sum(s);
  if (l == 0) atomicAdd(acc, mult * sqrtf(s));
}

__global__ __launch_bounds__(64) void k_ratio(float* sc) {
  if (threadIdx.x == 0) sc[2] = (sc[0] / 4100.0f) / (sc[1] / 4096.0f);
}

// h (f32) * ratio -> bf16
__global__ __launch_bounds__(256) void k_scalecast(const float* __restrict__ Hs,
    const float* __restrict__ sc, unsigned short* __restrict__ Hb) {
  int i = blockIdx.x * 256 + threadIdx.x;
  float ratio = sc[2];
  float4 v = *(const float4*)(Hs + (size_t)i * 4);
  ushort4 o = make_ushort4(f2bf(v.x * ratio), f2bf(v.y * ratio),
                           f2bf(v.z * ratio), f2bf(v.w * ratio));
  *(ushort4*)(Hb + (size_t)i * 4) = o;
}

// ---------------- GEMM: C[M][N] = A[M][K] * B[N][K]^T  (bf16 in, f32 out) ----------------
__global__ __launch_bounds__(256) void k_gemm(const unsigned short* __restrict__ A,
                                              const unsigned short* __restrict__ B,
                                              float* __restrict__ C, int M, int N, int K) {
  __shared__ __align__(16) short Al[128 * 64];
  __shared__ __align__(16) short Bl[128 * 64];
  const int t = threadIdx.x, l = t & 63, w = t >> 6;
  const int r = l & 15, g = l >> 4;
  const int wm = w >> 1, wn = w & 1;
  const size_t tm = (size_t)blockIdx.y * 128, tn = (size_t)blockIdx.x * 128;
  f32x4 acc[4][4] = {};
  for (int kt = 0; kt < K; kt += 64) {
    __syncthreads();
    for (int i = 0; i < 4; ++i) {
      int c = i * 256 + t;
      int row = c >> 3, k8 = (c & 7) * 8;
      async16(A + (tm + row) * K + kt + k8, Al + (i * 256 + w * 64) * 8);
    }
    for (int i = 0; i < 4; ++i) {
      int c = i * 256 + t;
      int row = c >> 3, k8 = (c & 7) * 8;
      async16(B + (tn + row) * K + kt + k8, Bl + (i * 256 + w * 64) * 8);
    }
    __syncthreads();
    for (int ks = 0; ks < 2; ++ks) {
      short8 af[4], bfr[4];
      for (int mi = 0; mi < 4; ++mi)
        af[mi] = *(const short8*)(Al + (wm * 64 + mi * 16 + r) * 64 + ks * 32 + g * 8);
      for (int ni = 0; ni < 4; ++ni)
        bfr[ni] = *(const short8*)(Bl + (wn * 64 + ni * 16 + r) * 64 + ks * 32 + g * 8);
      for (int mi = 0; mi < 4; ++mi)
        for (int ni = 0; ni < 4; ++ni)
          acc[mi][ni] = __builtin_amdgcn_mfma_f32_16x16x32_bf16(af[mi], bfr[ni], acc[mi][ni], 0, 0, 0);
    }
  }
  for (int mi = 0; mi < 4; ++mi)
    for (int ni = 0; ni < 4; ++ni)
      for (int j = 0; j < 4; ++j) {
        size_t row = tm + wm * 64 + mi * 16 + g * 4 + j;
        size_t col = tn + wn * 64 + ni * 16 + r;
        C[row * (size_t)N + col] = acc[mi][ni][j];
      }
}

// ---------------- qkv postprocess: rope + head L2-normalize, coalesced scatter ----------------
// grid (17, 64): block = (s-tile of 64, bh). Writes Qh/Kh row-major, Vt transposed via LDS.
// Also zeroes pad rows/cols (ss in 1025..1087).
__global__ __launch_bounds__(256) void k_postproc(const float* __restrict__ qkv,
    const float* __restrict__ re,
    unsigned short* __restrict__ Qh, unsigned short* __restrict__ Kh,
    unsigned short* __restrict__ Vt) {
  __shared__ short Vs[64][66];
  const int st = blockIdx.x, bh = blockIdx.y;
  const int b = bh >> 4, h = bh & 15;
  const int w = threadIdx.x >> 6, l = threadIdx.x & 63;
  for (int i = 0; i < 16; ++i) {
    const int ss = st * 64 + w * 16 + i;         // wave-uniform
    float q = 0.f, k = 0.f, v = 0.f;
    if (ss <= 1024) {
      const float* rowp = qkv + ((size_t)(b * 1025 + ss)) * 3072 + h * 64;
      q = rowp[l]; k = rowp[1024 + l]; v = rowp[2048 + l];
    }
    float cs = 1.f, sn = 0.f, sgn = 1.f;
    if (ss < 1024 && l < 32) {
      float f = re[ss * 32 + l];
      cs = cosf(f); sn = sinf(f);
      sgn = (l < 16) ? -1.f : 1.f;
    }
    float qp = __shfl_xor(q, 16), kp = __shfl_xor(k, 16);
    float q2 = q * cs + sgn * qp * sn;
    float k2 = k * cs + sgn * kp * sn;
    float nq = wave_sum(q2 * q2);
    float nk = wave_sum(k2 * k2);
    float iq = (ss <= 1024) ? 1.0f / sqrtf(nq) : 0.f;
    float ik = (ss <= 1024) ? 1.0f / sqrtf(nk) : 0.f;
    Qh[((size_t)bh * 1088 + ss) * 64 + l] = f2bf(q2 * iq);
    Kh[((size_t)bh * 1088 + ss) * 64 + l] = f2bf(k2 * ik);
    Vs[w * 16 + i][l] = (short)f2bf(v);
  }
  __syncthreads();
  for (int i = 0; i < 16; ++i) {
    const int d = w * 16 + i;
    Vt[((size_t)bh * 64 + d) * 1088 + st * 64 + l] = (unsigned short)Vs[l][d];
  }
}

// ---------------- attention: causal + sink, balanced strip pairs, swizzled LDS ----------------
// 128 threads (2 waves), QBLK=32. Block handles strips (p, 31-p): 19 tiles each.
// XCD remap keeps all strips of one bh on one XCD.
__global__ __launch_bounds__(128) void k_attn(const unsigned short* __restrict__ Qh,
    const unsigned short* __restrict__ Kh, const unsigned short* __restrict__ Vt,
    float* __restrict__ H) {
  __shared__ __align__(16) short Kl[2][64 * 64];
  __shared__ __align__(16) short Vl[2][64 * 64];
  __shared__ __align__(16) short Pl[2 * 16 * 64];
  const int wid = blockIdx.x;
  const int xcd = wid & 7, jj = wid >> 3;
  const int bh = xcd + 8 * (jj >> 4), pp = jj & 15;
  const int b = bh >> 4, hh = bh & 15;
  const int t = threadIdx.x, l = t & 63, w = t >> 6;
  const int r = l & 15, g = l >> 4;

  auto stage = [&](int buf, int kt) {
    for (int i = 0; i < 4; ++i) {
      int c = i * 128 + t;
      int row = c >> 3, ch = c & 7;
      int sch = ch ^ (row & 7);
      async16(Kh + ((size_t)bh * 1088 + kt * 64 + row) * 64 + sch * 8,
              Kl[buf] + (i * 128 + w * 64) * 8);
      async16(Vt + ((size_t)bh * 64 + row) * 1088 + kt * 64 + sch * 8,
              Vl[buf] + (i * 128 + w * 64) * 8);
    }
  };

  for (int sidx = 0; sidx < 2; ++sidx) {
    const int strip = sidx == 0 ? pp : 31 - pp;
    const int qrow0 = strip * 32 + w * 16;
    short8 qf[2];
    for (int ks = 0; ks < 2; ++ks)
      qf[ks] = *(const short8*)(Qh + ((size_t)bh * 1088 + qrow0 + r) * 64 + ks * 32 + g * 8);
    const int nt = strip / 2 + 2;     // causal tiles 0..strip/2, then sink tile
    f32x4 oacc[4] = {};
    float lsum[4] = {0.f, 0.f, 0.f, 0.f};
    stage(0, 0);
    __syncthreads();
    int cur = 0;
    for (int i = 0; i < nt; ++i) {
      const int kt = (i < nt - 1) ? i : 16;
      if (i + 1 < nt) stage(cur ^ 1, (i + 1 < nt - 1) ? (i + 1) : 16);
      // QK^T + masked exp + P to LDS (swizzled, wave-private rows)
      for (int nc = 0; nc < 4; ++nc) {
        f32x4 sc = {};
        for (int ks = 0; ks < 2; ++ks) {
          const int row = nc * 16 + r;
          const short8 kf = *(const short8*)(Kl[cur] + row * 64 + (((ks * 4 + g) ^ (row & 7)) << 3));
          sc = __builtin_amdgcn_mfma_f32_16x16x32_bf16(qf[ks], kf, sc, 0, 0, 0);
        }
        const int col = kt * 64 + nc * 16 + r;
        for (int j = 0; j < 4; ++j) {
          const int qrow = qrow0 + g * 4 + j;
          const bool valid = (col <= qrow) || (col == 1024);
          float p = valid ? __expf(sc[j]) : 0.0f;
          unsigned short pb = f2bf(p);
          lsum[j] += bf2f(pb);
          const int prow = w * 16 + g * 4 + j;
          const int bir = (nc * 16 + r) * 2;
          char* pd = (char*)Pl + prow * 128 + ((((unsigned)bir >> 4) ^ (prow & 7)) << 4) + (bir & 15);
          *(short*)pd = (short)pb;
        }
      }
      // PV (P rows are wave-private: no barrier needed, lgkmcnt ordering suffices)
      for (int ks = 0; ks < 2; ++ks) {
        const int prow = w * 16 + r;
        const short8 pf = *(const short8*)((char*)Pl + prow * 128 + (((ks * 4 + g) ^ (r & 7)) << 4));
        for (int nd = 0; nd < 4; ++nd) {
          const int vrow = nd * 16 + r;
          const short8 vf = *(const short8*)(Vl[cur] + vrow * 64 + (((ks * 4 + g) ^ (vrow & 7)) << 3));
          oacc[nd] = __builtin_amdgcn_mfma_f32_16x16x32_bf16(pf, vf, oacc[nd], 0, 0, 0);
        }
      }
      __syncthreads();
      cur ^= 1;
    }
    for (int j = 0; j < 4; ++j) {
      float v = lsum[j];
      v += __shfl_xor(v, 1); v += __shfl_xor(v, 2);
      v += __shfl_xor(v, 4); v += __shfl_xor(v, 8);
      lsum[j] = v;
    }
    for (int nd = 0; nd < 4; ++nd)
      for (int j = 0; j < 4; ++j) {
        const int srow = qrow0 + g * 4 + j;
        H[((size_t)(b * 1024 + srow)) * 1024 + hh * 64 + nd * 16 + r] = oacc[nd][j] / lsum[j];
      }
  }
}

// ---------------- launcher ----------------
extern "C" void kernel_launch(void* const* d_in, const int* in_sizes, int n_in,
                              void* d_out, int out_size, void* d_ws, size_t ws_size,
                              hipStream_t stream) {
  const float* x     = (const float*)d_in[0];
  const float* re    = (const float*)d_in[1];
  const float* w_qkv = (const float*)d_in[3];
  const float* w_out = (const float*)d_in[4];
  const float* sink  = (const float*)d_in[5];
  char* ws = (char*)d_ws;

  unsigned short* Wq = (unsigned short*)(ws + 0);          // 3072*1024 bf16
  unsigned short* Wo = (unsigned short*)(ws + 6291456);    // 1024*1024 bf16
  unsigned short* Xe = (unsigned short*)(ws + 8388608);    // 4224*1024 bf16
  float*          qkv = (float*)(ws + 17039360);           // 4224*3072 f32
  float*          Hs  = (float*)(ws + 17039360);           // reuse: 4096*1024 f32
  unsigned short* Hb  = (unsigned short*)(ws + 17039360 + 16777216); // 4096*1024 bf16
  unsigned short* Qh = (unsigned short*)(ws + 68943872);   // 64*1088*64 bf16
  unsigned short* Kh = (unsigned short*)(ws + 77856768);   // 64*1088*64 bf16
  unsigned short* Vt = (unsigned short*)(ws + 86769664);   // 64*64*1088 bf16
  float*          sc = (float*)(ws + 95682560);            // scalars
  float*          out = (float*)d_out;

  k_init<<<1, 64, 0, stream>>>(sc);
  k_wnorm<<<768, 256, 0, stream>>>(w_qkv, Wq, 3072);
  k_wnorm<<<256, 256, 0, stream>>>(w_out, Wo, 1024);
  k_xext<<<4224, 256, 0, stream>>>(x, sink, Xe);
  k_rownorm<<<1024, 256, 0, stream>>>(x, 4096, 1.0f, sc + 0);
  k_rownorm<<<1, 256, 0, stream>>>(sink, 1, 4.0f, sc + 0);
  k_gemm<<<dim3(24, 33), 256, 0, stream>>>(Xe, Wq, qkv, 4224, 3072, 1024);
  k_postproc<<<dim3(17, 64), 256, 0, stream>>>(qkv, re, Qh, Kh, Vt);
  k_attn<<<1024, 128, 0, stream>>>(Qh, Kh, Vt, Hs);
  k_rownorm<<<1024, 256, 0, stream>>>(Hs, 4096, 1.0f, sc + 1);
  k_ratio<<<1, 64, 0, stream>>>(sc);
  k_scalecast<<<4096, 256, 0, stream>>>(Hs, sc, Hb);
  k_gemm<<<dim3(8, 32), 256, 0, stream>>>(Hb, Wo, out, 4096, 1024, 1024);
}

// Round 3
// 262.265 us; speedup vs baseline: 1.1681x; 1.0485x over previous
//
#include <hip/hip_runtime.h>
#include <hip/hip_bf16.h>
#include <cstdint>

typedef __attribute__((ext_vector_type(8))) short short8;
typedef __attribute__((ext_vector_type(4))) float f32x4;

typedef const unsigned int __attribute__((address_space(1)))* gas_ptr;
typedef unsigned int __attribute__((address_space(3)))* las_ptr;

__device__ static inline void async16(const void* g, void* l) {
  __builtin_amdgcn_global_load_lds((gas_ptr)g, (las_ptr)l, 16, 0, 0);
}

__device__ static inline unsigned short f2bf(float f) {
  union { float f; uint32_t u; } v; v.f = f;
  uint32_t u = v.u;
  uint32_t r = (u + 0x7FFFu + ((u >> 16) & 1u)) >> 16;
  return (unsigned short)r;
}
__device__ static inline float bf2f(unsigned short s) {
  union { uint32_t u; float f; } v; v.u = ((uint32_t)s) << 16; return v.f;
}

__device__ static inline float wave_sum(float v) {
  v += __shfl_xor(v, 1);  v += __shfl_xor(v, 2);  v += __shfl_xor(v, 4);
  v += __shfl_xor(v, 8);  v += __shfl_xor(v, 16); v += __shfl_xor(v, 32);
  return v;
}

#define SBAR __builtin_amdgcn_sched_barrier(0)
#define PRE_MFMA do { SBAR; __builtin_amdgcn_s_barrier(); \
  asm volatile("s_waitcnt lgkmcnt(0)" ::: "memory"); SBAR; \
  __builtin_amdgcn_s_setprio(1); } while (0)
#define POST_MFMA do { __builtin_amdgcn_s_setprio(0); SBAR; \
  __builtin_amdgcn_s_barrier(); } while (0)

// ---------------- small utility kernels ----------------

__global__ __launch_bounds__(64) void k_init(float* sc) {
  if (threadIdx.x < 4) sc[threadIdx.x] = 0.0f;
}

__global__ __launch_bounds__(256) void k_wnorm(const float* __restrict__ W,
                                               unsigned short* __restrict__ E, int rows) {
  int row = blockIdx.x * 4 + (threadIdx.x >> 6);
  int l = threadIdx.x & 63;
  if (row >= rows) return;
  const float* wr = W + (size_t)row * 1024;
  float4 v[4];
  float s = 0.f;
  for (int i = 0; i < 4; ++i) {
    v[i] = *(const float4*)(wr + i * 256 + l * 4);
    s += v[i].x * v[i].x + v[i].y * v[i].y + v[i].z * v[i].z + v[i].w * v[i].w;
  }
  s = wave_sum(s);
  float inv = 1.0f / (0.0032f + sqrtf(s));
  unsigned short* er = E + (size_t)row * 1024;
  for (int i = 0; i < 4; ++i) {
    ushort4 o = make_ushort4(f2bf(v[i].x * inv), f2bf(v[i].y * inv),
                             f2bf(v[i].z * inv), f2bf(v[i].w * inv));
    *(ushort4*)(er + i * 256 + l * 4) = o;
  }
}

// build x_ext bf16 [4352][1024]: rows b*1025+s (s<1024 from x, s==1024 sink), rows>=4100 zero
__global__ __launch_bounds__(256) void k_xext(const float* __restrict__ x,
    const float* __restrict__ sink, unsigned short* __restrict__ Xe) {
  int i = blockIdx.x * 256 + threadIdx.x;
  int row = i >> 8;
  int c4 = (i & 255) * 4;
  ushort4 o;
  if (row < 4100) {
    int b = row / 1025, s = row % 1025;
    const float* src = (s < 1024) ? (x + ((size_t)(b * 1024 + s)) * 1024 + c4) : (sink + c4);
    float4 v = *(const float4*)src;
    o = make_ushort4(f2bf(v.x), f2bf(v.y), f2bf(v.z), f2bf(v.w));
  } else {
    o = make_ushort4(0, 0, 0, 0);
  }
  *(ushort4*)(Xe + (size_t)row * 1024 + c4) = o;
}

__global__ __launch_bounds__(256) void k_rownorm(const float* __restrict__ X, int rows,
                                                 float mult, float* __restrict__ acc) {
  int row = blockIdx.x * 4 + (threadIdx.x >> 6);
  int l = threadIdx.x & 63;
  if (row >= rows) return;
  const float* xr = X + (size_t)row * 1024;
  float s = 0.f;
  for (int i = 0; i < 4; ++i) {
    float4 v = *(const float4*)(xr + i * 256 + l * 4);
    s += v.x * v.x + v.y * v.y + v.z * v.z + v.w * v.w;
  }
  s = wave_sum(s);
  if (l == 0) atomicAdd(acc, mult * sqrtf(s));
}

__global__ __launch_bounds__(64) void k_ratio(float* sc) {
  if (threadIdx.x == 0) sc[2] = (sc[0] / 4100.0f) / (sc[1] / 4096.0f);
}

__global__ __launch_bounds__(256) void k_scalecast(const float* __restrict__ Hs,
    const float* __restrict__ sc, unsigned short* __restrict__ Hb) {
  int i = blockIdx.x * 256 + threadIdx.x;
  float ratio = sc[2];
  float4 v = *(const float4*)(Hs + (size_t)i * 4);
  ushort4 o = make_ushort4(f2bf(v.x * ratio), f2bf(v.y * ratio),
                           f2bf(v.z * ratio), f2bf(v.w * ratio));
  *(ushort4*)(Hb + (size_t)i * 4) = o;
}

// ---------------- GEMM 128x128 (2-phase, for the small output GEMM) ----------------
__global__ __launch_bounds__(256) void k_gemm(const unsigned short* __restrict__ A,
                                              const unsigned short* __restrict__ B,
                                              float* __restrict__ C, int M, int N, int K) {
  __shared__ __align__(16) short Al[128 * 64];
  __shared__ __align__(16) short Bl[128 * 64];
  const int t = threadIdx.x, l = t & 63, w = t >> 6;
  const int r = l & 15, g = l >> 4;
  const int wm = w >> 1, wn = w & 1;
  const size_t tm = (size_t)blockIdx.y * 128, tn = (size_t)blockIdx.x * 128;
  f32x4 acc[4][4] = {};
  for (int kt = 0; kt < K; kt += 64) {
    __syncthreads();
    for (int i = 0; i < 4; ++i) {
      int c = i * 256 + t;
      int row = c >> 3, k8 = (c & 7) * 8;
      async16(A + (tm + row) * K + kt + k8, Al + (i * 256 + w * 64) * 8);
    }
    for (int i = 0; i < 4; ++i) {
      int c = i * 256 + t;
      int row = c >> 3, k8 = (c & 7) * 8;
      async16(B + (tn + row) * K + kt + k8, Bl + (i * 256 + w * 64) * 8);
    }
    __syncthreads();
    for (int ks = 0; ks < 2; ++ks) {
      short8 af[4], bfr[4];
      for (int mi = 0; mi < 4; ++mi)
        af[mi] = *(const short8*)(Al + (wm * 64 + mi * 16 + r) * 64 + ks * 32 + g * 8);
      for (int ni = 0; ni < 4; ++ni)
        bfr[ni] = *(const short8*)(Bl + (wn * 64 + ni * 16 + r) * 64 + ks * 32 + g * 8);
      for (int mi = 0; mi < 4; ++mi)
        for (int ni = 0; ni < 4; ++ni)
          acc[mi][ni] = __builtin_amdgcn_mfma_f32_16x16x32_bf16(af[mi], bfr[ni], acc[mi][ni], 0, 0, 0);
    }
  }
  for (int mi = 0; mi < 4; ++mi)
    for (int ni = 0; ni < 4; ++ni)
      for (int j = 0; j < 4; ++j) {
        size_t row = tm + wm * 64 + mi * 16 + g * 4 + j;
        size_t col = tn + wn * 64 + ni * 16 + r;
        C[row * (size_t)N + col] = acc[mi][ni][j];
      }
}

// ---------------- GEMM 256x256, 8-wave, 4-phase/K-tile, counted vmcnt (T1+T2+T3+T4+T5) ----
// C[M][N] = A[M][K] * B[N][K]^T; M = gridDim-derived (tm*256), requires M%256==0, N%256==0, K%64==0.
__global__ __launch_bounds__(512) void k_gemm256(const unsigned short* __restrict__ A,
    const unsigned short* __restrict__ B, float* __restrict__ C, int N, int K, int ntn) {
  __shared__ __align__(16) short As[2][256 * 64];
  __shared__ __align__(16) short Bs[2][256 * 64];
  const int t = threadIdx.x, l = t & 63;
  const int w = t >> 6, r = l & 15, g = l >> 4;
  const int wm = w >> 2, wn = w & 3;
  // bijective XCD swizzle (m204)
  const int nwg = gridDim.x;
  const int q = nwg >> 3, rr = nwg & 7;
  const int xcd = blockIdx.x & 7, loc = blockIdx.x >> 3;
  const int wgid = (xcd < rr ? xcd * (q + 1) : rr * (q + 1) + (xcd - rr) * q) + loc;
  const int tm = wgid / ntn, tn = wgid % ntn;
  const size_t am0 = (size_t)tm * 256, bn0 = (size_t)tn * 256;
  const int NT = K >> 6;
  const int srow = t >> 3, sch = t & 7;

  auto stA = [&](int buf, int half, int kt) {
    const unsigned short* src = A + (am0 + half * 128) * (size_t)K + kt * 64;
    short* dst = As[buf] + half * 8192;
    async16(src + (size_t)srow * K + ((sch ^ (srow & 7)) << 3), dst + t * 8);
    async16(src + (size_t)(srow + 64) * K + ((sch ^ (srow & 7)) << 3), dst + (512 + t) * 8);
  };
  auto stB = [&](int buf, int half, int kt) {
    const unsigned short* src = B + (bn0 + half * 128) * (size_t)K + kt * 64;
    short* dst = Bs[buf] + half * 8192;
    async16(src + (size_t)srow * K + ((sch ^ (srow & 7)) << 3), dst + t * 8);
    async16(src + (size_t)(srow + 64) * K + ((sch ^ (srow & 7)) << 3), dst + (512 + t) * 8);
  };

  f32x4 acc[8][4] = {};
  short8 aL[4][2], aH[4][2], bL[2][2], bH[2][2];
  const int arow_base = wm * 128 + r;
  const int brow_base = wn * 64 + r;

  // prologue: tile 0 fully, tile 1 A-halves; vmcnt leaves tile-1 A in flight
  stA(0, 0, 0); stA(0, 1, 0); stB(0, 0, 0); stB(0, 1, 0);
  if (NT > 1) {
    stA(1, 0, 1); stA(1, 1, 1);
    asm volatile("s_waitcnt vmcnt(4)" ::: "memory"); SBAR;
  } else {
    asm volatile("s_waitcnt vmcnt(0)" ::: "memory"); SBAR;
  }
  __builtin_amdgcn_s_barrier();

  for (int tt = 0; tt < NT; ++tt) {
    const int buf = tt & 1;
    // ---- phase 1: read A[0-3], B[0-1]; stage (t+1).B half0; MFMA Q11
    #pragma unroll
    for (int mi = 0; mi < 4; ++mi)
      #pragma unroll
      for (int ks = 0; ks < 2; ++ks) {
        const int arow = arow_base + mi * 16;
        aL[mi][ks] = *(const short8*)(As[buf] + arow * 64 + (((ks * 4 + g) ^ (arow & 7)) << 3));
      }
    #pragma unroll
    for (int ni = 0; ni < 2; ++ni)
      #pragma unroll
      for (int ks = 0; ks < 2; ++ks) {
        const int brow = brow_base + ni * 16;
        bL[ni][ks] = *(const short8*)(Bs[buf] + brow * 64 + (((ks * 4 + g) ^ (brow & 7)) << 3));
      }
    if (tt + 1 < NT) stB(buf ^ 1, 0, tt + 1);
    PRE_MFMA;
    #pragma unroll
    for (int mi = 0; mi < 4; ++mi)
      #pragma unroll
      for (int ni = 0; ni < 2; ++ni)
        #pragma unroll
        for (int ks = 0; ks < 2; ++ks)
          acc[mi][ni] = __builtin_amdgcn_mfma_f32_16x16x32_bf16(aL[mi][ks], bL[ni][ks], acc[mi][ni], 0, 0, 0);
    POST_MFMA;
    // ---- phase 2: read B[2-3]; stage (t+1).B half1; MFMA Q12
    #pragma unroll
    for (int ni = 0; ni < 2; ++ni)
      #pragma unroll
      for (int ks = 0; ks < 2; ++ks) {
        const int brow = brow_base + (ni + 2) * 16;
        bH[ni][ks] = *(const short8*)(Bs[buf] + brow * 64 + (((ks * 4 + g) ^ (brow & 7)) << 3));
      }
    if (tt + 1 < NT) stB(buf ^ 1, 1, tt + 1);
    PRE_MFMA;
    #pragma unroll
    for (int mi = 0; mi < 4; ++mi)
      #pragma unroll
      for (int ni = 0; ni < 2; ++ni)
        #pragma unroll
        for (int ks = 0; ks < 2; ++ks)
          acc[mi][ni + 2] = __builtin_amdgcn_mfma_f32_16x16x32_bf16(aL[mi][ks], bH[ni][ks], acc[mi][ni + 2], 0, 0, 0);
    POST_MFMA;
    // ---- phase 3: read A[4-7]; MFMA Q22  (after this barrier, all tile-t ds_reads done)
    #pragma unroll
    for (int mi = 0; mi < 4; ++mi)
      #pragma unroll
      for (int ks = 0; ks < 2; ++ks) {
        const int arow = arow_base + (mi + 4) * 16;
        aH[mi][ks] = *(const short8*)(As[buf] + arow * 64 + (((ks * 4 + g) ^ (arow & 7)) << 3));
      }
    PRE_MFMA;
    #pragma unroll
    for (int mi = 0; mi < 4; ++mi)
      #pragma unroll
      for (int ni = 0; ni < 2; ++ni)
        #pragma unroll
        for (int ks = 0; ks < 2; ++ks)
          acc[mi + 4][ni + 2] = __builtin_amdgcn_mfma_f32_16x16x32_bf16(aH[mi][ks], bH[ni][ks], acc[mi + 4][ni + 2], 0, 0, 0);
    POST_MFMA;
    // ---- phase 4: stage (t+2).A both halves into buf (safe now); MFMA Q21
    if (tt + 2 < NT) { stA(buf, 0, tt + 2); stA(buf, 1, tt + 2); }
    PRE_MFMA;
    #pragma unroll
    for (int mi = 0; mi < 4; ++mi)
      #pragma unroll
      for (int ni = 0; ni < 2; ++ni)
        #pragma unroll
        for (int ks = 0; ks < 2; ++ks)
          acc[mi + 4][ni] = __builtin_amdgcn_mfma_f32_16x16x32_bf16(aH[mi][ks], bL[ni][ks], acc[mi + 4][ni], 0, 0, 0);
    __builtin_amdgcn_s_setprio(0); SBAR;
    // end-of-tile: counted wait for tile t+1 to be fully resident, never 0 mid-loop
    if (tt + 1 < NT) {
      if (tt + 2 < NT) { asm volatile("s_waitcnt vmcnt(4)" ::: "memory"); }
      else             { asm volatile("s_waitcnt vmcnt(0)" ::: "memory"); }
      SBAR;
      __builtin_amdgcn_s_barrier();
    }
  }

  #pragma unroll
  for (int mi = 0; mi < 8; ++mi)
    #pragma unroll
    for (int ni = 0; ni < 4; ++ni)
      #pragma unroll
      for (int j = 0; j < 4; ++j) {
        size_t row = am0 + wm * 128 + mi * 16 + g * 4 + j;
        size_t col = bn0 + wn * 64 + ni * 16 + r;
        C[row * (size_t)N + col] = acc[mi][ni][j];
      }
}

// ---------------- qkv postprocess: rope + head L2-normalize, coalesced scatter ----------------
__global__ __launch_bounds__(256) void k_postproc(const float* __restrict__ qkv,
    const float* __restrict__ re,
    unsigned short* __restrict__ Qh, unsigned short* __restrict__ Kh,
    unsigned short* __restrict__ Vt) {
  __shared__ short Vs[64][66];
  const int st = blockIdx.x, bh = blockIdx.y;
  const int b = bh >> 4, h = bh & 15;
  const int w = threadIdx.x >> 6, l = threadIdx.x & 63;
  for (int i = 0; i < 16; ++i) {
    const int ss = st * 64 + w * 16 + i;         // wave-uniform
    float q = 0.f, k = 0.f, v = 0.f;
    if (ss <= 1024) {
      const float* rowp = qkv + ((size_t)(b * 1025 + ss)) * 3072 + h * 64;
      q = rowp[l]; k = rowp[1024 + l]; v = rowp[2048 + l];
    }
    float cs = 1.f, sn = 0.f, sgn = 1.f;
    if (ss < 1024 && l < 32) {
      float f = re[ss * 32 + l];
      cs = cosf(f); sn = sinf(f);
      sgn = (l < 16) ? -1.f : 1.f;
    }
    float qp = __shfl_xor(q, 16), kp = __shfl_xor(k, 16);
    float q2 = q * cs + sgn * qp * sn;
    float k2 = k * cs + sgn * kp * sn;
    float nq = wave_sum(q2 * q2);
    float nk = wave_sum(k2 * k2);
    float iq = (ss <= 1024) ? 1.0f / sqrtf(nq) : 0.f;
    float ik = (ss <= 1024) ? 1.0f / sqrtf(nk) : 0.f;
    Qh[((size_t)bh * 1088 + ss) * 64 + l] = f2bf(q2 * iq);
    Kh[((size_t)bh * 1088 + ss) * 64 + l] = f2bf(k2 * ik);
    Vs[w * 16 + i][l] = (short)f2bf(v);
  }
  __syncthreads();
  for (int i = 0; i < 16; ++i) {
    const int d = w * 16 + i;
    Vt[((size_t)bh * 64 + d) * 1088 + st * 64 + l] = (unsigned short)Vs[l][d];
  }
}

// ---------------- attention: causal + sink, balanced strip pairs, swizzled LDS ----------------
__global__ __launch_bounds__(128) void k_attn(const unsigned short* __restrict__ Qh,
    const unsigned short* __restrict__ Kh, const unsigned short* __restrict__ Vt,
    float* __restrict__ H) {
  __shared__ __align__(16) short Kl[2][64 * 64];
  __shared__ __align__(16) short Vl[2][64 * 64];
  __shared__ __align__(16) short Pl[2 * 16 * 64];
  const int wid = blockIdx.x;
  const int xcd = wid & 7, jj = wid >> 3;
  const int bh = xcd + 8 * (jj >> 4), pp = jj & 15;
  const int b = bh >> 4, hh = bh & 15;
  const int t = threadIdx.x, l = t & 63, w = t >> 6;
  const int r = l & 15, g = l >> 4;

  auto stage = [&](int buf, int kt) {
    for (int i = 0; i < 4; ++i) {
      int c = i * 128 + t;
      int row = c >> 3, ch = c & 7;
      int sch = ch ^ (row & 7);
      async16(Kh + ((size_t)bh * 1088 + kt * 64 + row) * 64 + sch * 8,
              Kl[buf] + (i * 128 + w * 64) * 8);
      async16(Vt + ((size_t)bh * 64 + row) * 1088 + kt * 64 + sch * 8,
              Vl[buf] + (i * 128 + w * 64) * 8);
    }
  };

  for (int sidx = 0; sidx < 2; ++sidx) {
    const int strip = sidx == 0 ? pp : 31 - pp;
    const int qrow0 = strip * 32 + w * 16;
    short8 qf[2];
    for (int ks = 0; ks < 2; ++ks)
      qf[ks] = *(const short8*)(Qh + ((size_t)bh * 1088 + qrow0 + r) * 64 + ks * 32 + g * 8);
    const int nt = strip / 2 + 2;     // causal tiles 0..strip/2, then sink tile
    f32x4 oacc[4] = {};
    float lsum[4] = {0.f, 0.f, 0.f, 0.f};
    stage(0, 0);
    __syncthreads();
    int cur = 0;
    for (int i = 0; i < nt; ++i) {
      const int kt = (i < nt - 1) ? i : 16;
      if (i + 1 < nt) stage(cur ^ 1, (i + 1 < nt - 1) ? (i + 1) : 16);
      for (int nc = 0; nc < 4; ++nc) {
        f32x4 sc = {};
        for (int ks = 0; ks < 2; ++ks) {
          const int row = nc * 16 + r;
          const short8 kf = *(const short8*)(Kl[cur] + row * 64 + (((ks * 4 + g) ^ (row & 7)) << 3));
          sc = __builtin_amdgcn_mfma_f32_16x16x32_bf16(qf[ks], kf, sc, 0, 0, 0);
        }
        const int col = kt * 64 + nc * 16 + r;
        for (int j = 0; j < 4; ++j) {
          const int qrow = qrow0 + g * 4 + j;
          const bool valid = (col <= qrow) || (col == 1024);
          float p = valid ? __expf(sc[j]) : 0.0f;
          unsigned short pb = f2bf(p);
          lsum[j] += bf2f(pb);
          const int prow = w * 16 + g * 4 + j;
          const int bir = (nc * 16 + r) * 2;
          char* pd = (char*)Pl + prow * 128 + ((((unsigned)bir >> 4) ^ (prow & 7)) << 4) + (bir & 15);
          *(short*)pd = (short)pb;
        }
      }
      for (int ks = 0; ks < 2; ++ks) {
        const int prow = w * 16 + r;
        const short8 pf = *(const short8*)((char*)Pl + prow * 128 + (((ks * 4 + g) ^ (r & 7)) << 4));
        for (int nd = 0; nd < 4; ++nd) {
          const int vrow = nd * 16 + r;
          const short8 vf = *(const short8*)(Vl[cur] + vrow * 64 + (((ks * 4 + g) ^ (vrow & 7)) << 3));
          oacc[nd] = __builtin_amdgcn_mfma_f32_16x16x32_bf16(pf, vf, oacc[nd], 0, 0, 0);
        }
      }
      __syncthreads();
      cur ^= 1;
    }
    for (int j = 0; j < 4; ++j) {
      float v = lsum[j];
      v += __shfl_xor(v, 1); v += __shfl_xor(v, 2);
      v += __shfl_xor(v, 4); v += __shfl_xor(v, 8);
      lsum[j] = v;
    }
    for (int nd = 0; nd < 4; ++nd)
      for (int j = 0; j < 4; ++j) {
        const int srow = qrow0 + g * 4 + j;
        H[((size_t)(b * 1024 + srow)) * 1024 + hh * 64 + nd * 16 + r] = oacc[nd][j] / lsum[j];
      }
  }
}

// ---------------- launcher ----------------
extern "C" void kernel_launch(void* const* d_in, const int* in_sizes, int n_in,
                              void* d_out, int out_size, void* d_ws, size_t ws_size,
                              hipStream_t stream) {
  const float* x     = (const float*)d_in[0];
  const float* re    = (const float*)d_in[1];
  const float* w_qkv = (const float*)d_in[3];
  const float* w_out = (const float*)d_in[4];
  const float* sink  = (const float*)d_in[5];
  char* ws = (char*)d_ws;

  unsigned short* Wq = (unsigned short*)(ws + 0);          // 3072*1024 bf16
  unsigned short* Wo = (unsigned short*)(ws + 6291456);    // 1024*1024 bf16
  unsigned short* Xe = (unsigned short*)(ws + 8388608);    // 4352*1024 bf16
  float*          qkv = (float*)(ws + 17301504);           // 4352*3072 f32
  float*          Hs  = (float*)(ws + 17301504);           // reuse: 4096*1024 f32
  unsigned short* Hb  = (unsigned short*)(ws + 34078720);  // 4096*1024 bf16
  unsigned short* Qh = (unsigned short*)(ws + 70778880);   // 64*1088*64 bf16
  unsigned short* Kh = (unsigned short*)(ws + 79691776);   // 64*1088*64 bf16
  unsigned short* Vt = (unsigned short*)(ws + 88604672);   // 64*64*1088 bf16
  float*          sc = (float*)(ws + 97517568);            // scalars
  float*          out = (float*)d_out;

  k_init<<<1, 64, 0, stream>>>(sc);
  k_wnorm<<<768, 256, 0, stream>>>(w_qkv, Wq, 3072);
  k_wnorm<<<256, 256, 0, stream>>>(w_out, Wo, 1024);
  k_xext<<<4352, 256, 0, stream>>>(x, sink, Xe);
  k_rownorm<<<1024, 256, 0, stream>>>(x, 4096, 1.0f, sc + 0);
  k_rownorm<<<1, 256, 0, stream>>>(sink, 1, 4.0f, sc + 0);
  k_gemm256<<<17 * 12, 512, 0, stream>>>(Xe, Wq, qkv, 3072, 1024, 12);
  k_postproc<<<dim3(17, 64), 256, 0, stream>>>(qkv, re, Qh, Kh, Vt);
  k_attn<<<1024, 128, 0, stream>>>(Qh, Kh, Vt, Hs);
  k_rownorm<<<1024, 256, 0, stream>>>(Hs, 4096, 1.0f, sc + 1);
  k_ratio<<<1, 64, 0, stream>>>(sc);
  k_scalecast<<<4096, 256, 0, stream>>>(Hs, sc, Hb);
  k_gemm<<<dim3(8, 32), 256, 0, stream>>>(Hb, Wo, out, 4096, 1024, 1024);
}

// Round 4
// 166.073 us; speedup vs baseline: 1.8447x; 1.5792x over previous
//
#include <hip/hip_runtime.h>
#include <hip/hip_bf16.h>
#include <cstdint>

typedef __attribute__((ext_vector_type(8))) short short8;
typedef __attribute__((ext_vector_type(4))) float f32x4;

typedef const unsigned int __attribute__((address_space(1)))* gas_ptr;
typedef unsigned int __attribute__((address_space(3)))* las_ptr;

__device__ static inline void async16(const void* g, void* l) {
  __builtin_amdgcn_global_load_lds((gas_ptr)g, (las_ptr)l, 16, 0, 0);
}

__device__ static inline unsigned short f2bf(float f) {
  union { float f; uint32_t u; } v; v.f = f;
  uint32_t u = v.u;
  uint32_t r = (u + 0x7FFFu + ((u >> 16) & 1u)) >> 16;
  return (unsigned short)r;
}
__device__ static inline float bf2f(unsigned short s) {
  union { uint32_t u; float f; } v; v.u = ((uint32_t)s) << 16; return v.f;
}

__device__ static inline float wave_sum(float v) {
  v += __shfl_xor(v, 1);  v += __shfl_xor(v, 2);  v += __shfl_xor(v, 4);
  v += __shfl_xor(v, 8);  v += __shfl_xor(v, 16); v += __shfl_xor(v, 32);
  return v;
}

#define SBAR __builtin_amdgcn_sched_barrier(0)
#define PRE_MFMA do { SBAR; __builtin_amdgcn_s_barrier(); \
  asm volatile("s_waitcnt lgkmcnt(0)" ::: "memory"); SBAR; \
  __builtin_amdgcn_s_setprio(1); } while (0)
#define POST_MFMA do { __builtin_amdgcn_s_setprio(0); SBAR; \
  __builtin_amdgcn_s_barrier(); } while (0)

// ---------------- small utility kernels ----------------

__global__ __launch_bounds__(64) void k_init(float* sc) {
  if (threadIdx.x < 4) sc[threadIdx.x] = 0.0f;
}

__global__ __launch_bounds__(256) void k_wnorm(const float* __restrict__ W,
                                               unsigned short* __restrict__ E, int rows) {
  int row = blockIdx.x * 4 + (threadIdx.x >> 6);
  int l = threadIdx.x & 63;
  if (row >= rows) return;
  const float* wr = W + (size_t)row * 1024;
  float4 v[4];
  float s = 0.f;
  for (int i = 0; i < 4; ++i) {
    v[i] = *(const float4*)(wr + i * 256 + l * 4);
    s += v[i].x * v[i].x + v[i].y * v[i].y + v[i].z * v[i].z + v[i].w * v[i].w;
  }
  s = wave_sum(s);
  float inv = 1.0f / (0.0032f + sqrtf(s));
  unsigned short* er = E + (size_t)row * 1024;
  for (int i = 0; i < 4; ++i) {
    ushort4 o = make_ushort4(f2bf(v[i].x * inv), f2bf(v[i].y * inv),
                             f2bf(v[i].z * inv), f2bf(v[i].w * inv));
    *(ushort4*)(er + i * 256 + l * 4) = o;
  }
}

// build x_ext bf16 [4352][1024]: rows b*1025+s (s<1024 from x, s==1024 sink), rows>=4100 zero
__global__ __launch_bounds__(256) void k_xext(const float* __restrict__ x,
    const float* __restrict__ sink, unsigned short* __restrict__ Xe) {
  int i = blockIdx.x * 256 + threadIdx.x;
  int row = i >> 8;
  int c4 = (i & 255) * 4;
  ushort4 o;
  if (row < 4100) {
    int b = row / 1025, s = row % 1025;
    const float* src = (s < 1024) ? (x + ((size_t)(b * 1024 + s)) * 1024 + c4) : (sink + c4);
    float4 v = *(const float4*)src;
    o = make_ushort4(f2bf(v.x), f2bf(v.y), f2bf(v.z), f2bf(v.w));
  } else {
    o = make_ushort4(0, 0, 0, 0);
  }
  *(ushort4*)(Xe + (size_t)row * 1024 + c4) = o;
}

// grid-stride sum of row L2 norms (1024 cols) * mult; per-block LDS reduce, ONE atomic/block
__global__ __launch_bounds__(256) void k_rownorm(const float* __restrict__ X, int rows,
                                                 float mult, float* __restrict__ acc) {
  __shared__ float red[4];
  const int w = threadIdx.x >> 6, l = threadIdx.x & 63;
  float local = 0.f;
  for (int row = blockIdx.x * 4 + w; row < rows; row += gridDim.x * 4) {
    const float* xr = X + (size_t)row * 1024;
    float s = 0.f;
    for (int i = 0; i < 4; ++i) {
      float4 v = *(const float4*)(xr + i * 256 + l * 4);
      s += v.x * v.x + v.y * v.y + v.z * v.z + v.w * v.w;
    }
    s = wave_sum(s);
    local += sqrtf(s);
  }
  if (l == 0) red[w] = local;
  __syncthreads();
  if (threadIdx.x == 0)
    atomicAdd(acc, mult * (red[0] + red[1] + red[2] + red[3]));
}

__global__ __launch_bounds__(64) void k_ratio(float* sc) {
  if (threadIdx.x == 0) sc[2] = (sc[0] / 4100.0f) / (sc[1] / 4096.0f);
}

__global__ __launch_bounds__(256) void k_scalecast(const float* __restrict__ Hs,
    const float* __restrict__ sc, unsigned short* __restrict__ Hb) {
  int i = blockIdx.x * 256 + threadIdx.x;
  float ratio = sc[2];
  float4 v = *(const float4*)(Hs + (size_t)i * 4);
  ushort4 o = make_ushort4(f2bf(v.x * ratio), f2bf(v.y * ratio),
                           f2bf(v.z * ratio), f2bf(v.w * ratio));
  *(ushort4*)(Hb + (size_t)i * 4) = o;
}

// ---------------- GEMM 128x128 (2-phase, for the small output GEMM) ----------------
__global__ __launch_bounds__(256) void k_gemm(const unsigned short* __restrict__ A,
                                              const unsigned short* __restrict__ B,
                                              float* __restrict__ C, int M, int N, int K) {
  __shared__ __align__(16) short Al[128 * 64];
  __shared__ __align__(16) short Bl[128 * 64];
  const int t = threadIdx.x, l = t & 63, w = t >> 6;
  const int r = l & 15, g = l >> 4;
  const int wm = w >> 1, wn = w & 1;
  const size_t tm = (size_t)blockIdx.y * 128, tn = (size_t)blockIdx.x * 128;
  f32x4 acc[4][4] = {};
  for (int kt = 0; kt < K; kt += 64) {
    __syncthreads();
    for (int i = 0; i < 4; ++i) {
      int c = i * 256 + t;
      int row = c >> 3, k8 = (c & 7) * 8;
      async16(A + (tm + row) * K + kt + k8, Al + (i * 256 + w * 64) * 8);
    }
    for (int i = 0; i < 4; ++i) {
      int c = i * 256 + t;
      int row = c >> 3, k8 = (c & 7) * 8;
      async16(B + (tn + row) * K + kt + k8, Bl + (i * 256 + w * 64) * 8);
    }
    __syncthreads();
    for (int ks = 0; ks < 2; ++ks) {
      short8 af[4], bfr[4];
      for (int mi = 0; mi < 4; ++mi)
        af[mi] = *(const short8*)(Al + (wm * 64 + mi * 16 + r) * 64 + ks * 32 + g * 8);
      for (int ni = 0; ni < 4; ++ni)
        bfr[ni] = *(const short8*)(Bl + (wn * 64 + ni * 16 + r) * 64 + ks * 32 + g * 8);
      for (int mi = 0; mi < 4; ++mi)
        for (int ni = 0; ni < 4; ++ni)
          acc[mi][ni] = __builtin_amdgcn_mfma_f32_16x16x32_bf16(af[mi], bfr[ni], acc[mi][ni], 0, 0, 0);
    }
  }
  for (int mi = 0; mi < 4; ++mi)
    for (int ni = 0; ni < 4; ++ni)
      for (int j = 0; j < 4; ++j) {
        size_t row = tm + wm * 64 + mi * 16 + g * 4 + j;
        size_t col = tn + wn * 64 + ni * 16 + r;
        C[row * (size_t)N + col] = acc[mi][ni][j];
      }
}

// ---------------- GEMM 256x256, 8-wave, 4-phase/K-tile, counted vmcnt (T1+T2+T3+T4+T5) ----
__global__ __launch_bounds__(512) void k_gemm256(const unsigned short* __restrict__ A,
    const unsigned short* __restrict__ B, float* __restrict__ C, int N, int K, int ntn) {
  __shared__ __align__(16) short As[2][256 * 64];
  __shared__ __align__(16) short Bs[2][256 * 64];
  const int t = threadIdx.x, l = t & 63;
  const int w = t >> 6, r = l & 15, g = l >> 4;
  const int wm = w >> 2, wn = w & 3;
  // bijective XCD swizzle (m204)
  const int nwg = gridDim.x;
  const int q = nwg >> 3, rr = nwg & 7;
  const int xcd = blockIdx.x & 7, loc = blockIdx.x >> 3;
  const int wgid = (xcd < rr ? xcd * (q + 1) : rr * (q + 1) + (xcd - rr) * q) + loc;
  const int tm = wgid / ntn, tn = wgid % ntn;
  const size_t am0 = (size_t)tm * 256, bn0 = (size_t)tn * 256;
  const int NT = K >> 6;
  const int srow = t >> 3, sch = t & 7;

  auto stA = [&](int buf, int half, int kt) {
    const unsigned short* src = A + (am0 + half * 128) * (size_t)K + kt * 64;
    short* dst = As[buf] + half * 8192;
    async16(src + (size_t)srow * K + ((sch ^ (srow & 7)) << 3), dst + t * 8);
    async16(src + (size_t)(srow + 64) * K + ((sch ^ (srow & 7)) << 3), dst + (512 + t) * 8);
  };
  auto stB = [&](int buf, int half, int kt) {
    const unsigned short* src = B + (bn0 + half * 128) * (size_t)K + kt * 64;
    short* dst = Bs[buf] + half * 8192;
    async16(src + (size_t)srow * K + ((sch ^ (srow & 7)) << 3), dst + t * 8);
    async16(src + (size_t)(srow + 64) * K + ((sch ^ (srow & 7)) << 3), dst + (512 + t) * 8);
  };

  f32x4 acc[8][4] = {};
  short8 aL[4][2], aH[4][2], bL[2][2], bH[2][2];
  const int arow_base = wm * 128 + r;
  const int brow_base = wn * 64 + r;

  stA(0, 0, 0); stA(0, 1, 0); stB(0, 0, 0); stB(0, 1, 0);
  if (NT > 1) {
    stA(1, 0, 1); stA(1, 1, 1);
    asm volatile("s_waitcnt vmcnt(4)" ::: "memory"); SBAR;
  } else {
    asm volatile("s_waitcnt vmcnt(0)" ::: "memory"); SBAR;
  }
  __builtin_amdgcn_s_barrier();

  for (int tt = 0; tt < NT; ++tt) {
    const int buf = tt & 1;
    // ---- phase 1: read A[0-3], B[0-1]; stage (t+1).B half0; MFMA Q11
    #pragma unroll
    for (int mi = 0; mi < 4; ++mi)
      #pragma unroll
      for (int ks = 0; ks < 2; ++ks) {
        const int arow = arow_base + mi * 16;
        aL[mi][ks] = *(const short8*)(As[buf] + arow * 64 + (((ks * 4 + g) ^ (arow & 7)) << 3));
      }
    #pragma unroll
    for (int ni = 0; ni < 2; ++ni)
      #pragma unroll
      for (int ks = 0; ks < 2; ++ks) {
        const int brow = brow_base + ni * 16;
        bL[ni][ks] = *(const short8*)(Bs[buf] + brow * 64 + (((ks * 4 + g) ^ (brow & 7)) << 3));
      }
    if (tt + 1 < NT) stB(buf ^ 1, 0, tt + 1);
    PRE_MFMA;
    #pragma unroll
    for (int mi = 0; mi < 4; ++mi)
      #pragma unroll
      for (int ni = 0; ni < 2; ++ni)
        #pragma unroll
        for (int ks = 0; ks < 2; ++ks)
          acc[mi][ni] = __builtin_amdgcn_mfma_f32_16x16x32_bf16(aL[mi][ks], bL[ni][ks], acc[mi][ni], 0, 0, 0);
    POST_MFMA;
    // ---- phase 2: read B[2-3]; stage (t+1).B half1; MFMA Q12
    #pragma unroll
    for (int ni = 0; ni < 2; ++ni)
      #pragma unroll
      for (int ks = 0; ks < 2; ++ks) {
        const int brow = brow_base + (ni + 2) * 16;
        bH[ni][ks] = *(const short8*)(Bs[buf] + brow * 64 + (((ks * 4 + g) ^ (brow & 7)) << 3));
      }
    if (tt + 1 < NT) stB(buf ^ 1, 1, tt + 1);
    PRE_MFMA;
    #pragma unroll
    for (int mi = 0; mi < 4; ++mi)
      #pragma unroll
      for (int ni = 0; ni < 2; ++ni)
        #pragma unroll
        for (int ks = 0; ks < 2; ++ks)
          acc[mi][ni + 2] = __builtin_amdgcn_mfma_f32_16x16x32_bf16(aL[mi][ks], bH[ni][ks], acc[mi][ni + 2], 0, 0, 0);
    POST_MFMA;
    // ---- phase 3: read A[4-7]; MFMA Q22
    #pragma unroll
    for (int mi = 0; mi < 4; ++mi)
      #pragma unroll
      for (int ks = 0; ks < 2; ++ks) {
        const int arow = arow_base + (mi + 4) * 16;
        aH[mi][ks] = *(const short8*)(As[buf] + arow * 64 + (((ks * 4 + g) ^ (arow & 7)) << 3));
      }
    PRE_MFMA;
    #pragma unroll
    for (int mi = 0; mi < 4; ++mi)
      #pragma unroll
      for (int ni = 0; ni < 2; ++ni)
        #pragma unroll
        for (int ks = 0; ks < 2; ++ks)
          acc[mi + 4][ni + 2] = __builtin_amdgcn_mfma_f32_16x16x32_bf16(aH[mi][ks], bH[ni][ks], acc[mi + 4][ni + 2], 0, 0, 0);
    POST_MFMA;
    // ---- phase 4: stage (t+2).A both halves into buf; MFMA Q21
    if (tt + 2 < NT) { stA(buf, 0, tt + 2); stA(buf, 1, tt + 2); }
    PRE_MFMA;
    #pragma unroll
    for (int mi = 0; mi < 4; ++mi)
      #pragma unroll
      for (int ni = 0; ni < 2; ++ni)
        #pragma unroll
        for (int ks = 0; ks < 2; ++ks)
          acc[mi + 4][ni] = __builtin_amdgcn_mfma_f32_16x16x32_bf16(aH[mi][ks], bL[ni][ks], acc[mi + 4][ni], 0, 0, 0);
    __builtin_amdgcn_s_setprio(0); SBAR;
    if (tt + 1 < NT) {
      if (tt + 2 < NT) { asm volatile("s_waitcnt vmcnt(4)" ::: "memory"); }
      else             { asm volatile("s_waitcnt vmcnt(0)" ::: "memory"); }
      SBAR;
      __builtin_amdgcn_s_barrier();
    }
  }

  #pragma unroll
  for (int mi = 0; mi < 8; ++mi)
    #pragma unroll
    for (int ni = 0; ni < 4; ++ni)
      #pragma unroll
      for (int j = 0; j < 4; ++j) {
        size_t row = am0 + wm * 128 + mi * 16 + g * 4 + j;
        size_t col = bn0 + wn * 64 + ni * 16 + r;
        C[row * (size_t)N + col] = acc[mi][ni][j];
      }
}

// ---------------- qkv postprocess: rope + head L2-normalize, coalesced scatter ----------------
__global__ __launch_bounds__(256) void k_postproc(const float* __restrict__ qkv,
    const float* __restrict__ re,
    unsigned short* __restrict__ Qh, unsigned short* __restrict__ Kh,
    unsigned short* __restrict__ Vt) {
  __shared__ short Vs[64][66];
  const int st = blockIdx.x, bh = blockIdx.y;
  const int b = bh >> 4, h = bh & 15;
  const int w = threadIdx.x >> 6, l = threadIdx.x & 63;
  for (int i = 0; i < 16; ++i) {
    const int ss = st * 64 + w * 16 + i;         // wave-uniform
    float q = 0.f, k = 0.f, v = 0.f;
    if (ss <= 1024) {
      const float* rowp = qkv + ((size_t)(b * 1025 + ss)) * 3072 + h * 64;
      q = rowp[l]; k = rowp[1024 + l]; v = rowp[2048 + l];
    }
    float cs = 1.f, sn = 0.f, sgn = 1.f;
    if (ss < 1024 && l < 32) {
      float f = re[ss * 32 + l];
      cs = cosf(f); sn = sinf(f);
      sgn = (l < 16) ? -1.f : 1.f;
    }
    float qp = __shfl_xor(q, 16), kp = __shfl_xor(k, 16);
    float q2 = q * cs + sgn * qp * sn;
    float k2 = k * cs + sgn * kp * sn;
    float nq = wave_sum(q2 * q2);
    float nk = wave_sum(k2 * k2);
    float iq = (ss <= 1024) ? 1.0f / sqrtf(nq) : 0.f;
    float ik = (ss <= 1024) ? 1.0f / sqrtf(nk) : 0.f;
    Qh[((size_t)bh * 1088 + ss) * 64 + l] = f2bf(q2 * iq);
    Kh[((size_t)bh * 1088 + ss) * 64 + l] = f2bf(k2 * ik);
    Vs[w * 16 + i][l] = (short)f2bf(v);
  }
  __syncthreads();
  for (int i = 0; i < 16; ++i) {
    const int d = w * 16 + i;
    Vt[((size_t)bh * 64 + d) * 1088 + st * 64 + l] = (unsigned short)Vs[l][d];
  }
}

// ---------------- attention: causal + sink, balanced strip pairs, swizzled LDS ----------------
__global__ __launch_bounds__(128) void k_attn(const unsigned short* __restrict__ Qh,
    const unsigned short* __restrict__ Kh, const unsigned short* __restrict__ Vt,
    float* __restrict__ H) {
  __shared__ __align__(16) short Kl[2][64 * 64];
  __shared__ __align__(16) short Vl[2][64 * 64];
  __shared__ __align__(16) short Pl[2 * 16 * 64];
  const int wid = blockIdx.x;
  const int xcd = wid & 7, jj = wid >> 3;
  const int bh = xcd + 8 * (jj >> 4), pp = jj & 15;
  const int b = bh >> 4, hh = bh & 15;
  const int t = threadIdx.x, l = t & 63, w = t >> 6;
  const int r = l & 15, g = l >> 4;

  auto stage = [&](int buf, int kt) {
    for (int i = 0; i < 4; ++i) {
      int c = i * 128 + t;
      int row = c >> 3, ch = c & 7;
      int sch = ch ^ (row & 7);
      async16(Kh + ((size_t)bh * 1088 + kt * 64 + row) * 64 + sch * 8,
              Kl[buf] + (i * 128 + w * 64) * 8);
      async16(Vt + ((size_t)bh * 64 + row) * 1088 + kt * 64 + sch * 8,
              Vl[buf] + (i * 128 + w * 64) * 8);
    }
  };

  for (int sidx = 0; sidx < 2; ++sidx) {
    const int strip = sidx == 0 ? pp : 31 - pp;
    const int qrow0 = strip * 32 + w * 16;
    short8 qf[2];
    for (int ks = 0; ks < 2; ++ks)
      qf[ks] = *(const short8*)(Qh + ((size_t)bh * 1088 + qrow0 + r) * 64 + ks * 32 + g * 8);
    const int nt = strip / 2 + 2;     // causal tiles 0..strip/2, then sink tile
    f32x4 oacc[4] = {};
    float lsum[4] = {0.f, 0.f, 0.f, 0.f};
    stage(0, 0);
    __syncthreads();
    int cur = 0;
    for (int i = 0; i < nt; ++i) {
      const int kt = (i < nt - 1) ? i : 16;
      if (i + 1 < nt) stage(cur ^ 1, (i + 1 < nt - 1) ? (i + 1) : 16);
      for (int nc = 0; nc < 4; ++nc) {
        f32x4 sc = {};
        for (int ks = 0; ks < 2; ++ks) {
          const int row = nc * 16 + r;
          const short8 kf = *(const short8*)(Kl[cur] + row * 64 + (((ks * 4 + g) ^ (row & 7)) << 3));
          sc = __builtin_amdgcn_mfma_f32_16x16x32_bf16(qf[ks], kf, sc, 0, 0, 0);
        }
        const int col = kt * 64 + nc * 16 + r;
        for (int j = 0; j < 4; ++j) {
          const int qrow = qrow0 + g * 4 + j;
          const bool valid = (col <= qrow) || (col == 1024);
          float p = valid ? __expf(sc[j]) : 0.0f;
          unsigned short pb = f2bf(p);
          lsum[j] += bf2f(pb);
          const int prow = w * 16 + g * 4 + j;
          const int bir = (nc * 16 + r) * 2;
          char* pd = (char*)Pl + prow * 128 + ((((unsigned)bir >> 4) ^ (prow & 7)) << 4) + (bir & 15);
          *(short*)pd = (short)pb;
        }
      }
      for (int ks = 0; ks < 2; ++ks) {
        const int prow = w * 16 + r;
        const short8 pf = *(const short8*)((char*)Pl + prow * 128 + (((ks * 4 + g) ^ (r & 7)) << 4));
        for (int nd = 0; nd < 4; ++nd) {
          const int vrow = nd * 16 + r;
          const short8 vf = *(const short8*)(Vl[cur] + vrow * 64 + (((ks * 4 + g) ^ (vrow & 7)) << 3));
          oacc[nd] = __builtin_amdgcn_mfma_f32_16x16x32_bf16(pf, vf, oacc[nd], 0, 0, 0);
        }
      }
      __syncthreads();
      cur ^= 1;
    }
    for (int j = 0; j < 4; ++j) {
      float v = lsum[j];
      v += __shfl_xor(v, 1); v += __shfl_xor(v, 2);
      v += __shfl_xor(v, 4); v += __shfl_xor(v, 8);
      lsum[j] = v;
    }
    for (int nd = 0; nd < 4; ++nd)
      for (int j = 0; j < 4; ++j) {
        const int srow = qrow0 + g * 4 + j;
        H[((size_t)(b * 1024 + srow)) * 1024 + hh * 64 + nd * 16 + r] = oacc[nd][j] / lsum[j];
      }
  }
}

// ---------------- launcher ----------------
extern "C" void kernel_launch(void* const* d_in, const int* in_sizes, int n_in,
                              void* d_out, int out_size, void* d_ws, size_t ws_size,
                              hipStream_t stream) {
  const float* x     = (const float*)d_in[0];
  const float* re    = (const float*)d_in[1];
  const float* w_qkv = (const float*)d_in[3];
  const float* w_out = (const float*)d_in[4];
  const float* sink  = (const float*)d_in[5];
  char* ws = (char*)d_ws;

  unsigned short* Wq = (unsigned short*)(ws + 0);          // 3072*1024 bf16
  unsigned short* Wo = (unsigned short*)(ws + 6291456);    // 1024*1024 bf16
  unsigned short* Xe = (unsigned short*)(ws + 8388608);    // 4352*1024 bf16
  float*          qkv = (float*)(ws + 17301504);           // 4352*3072 f32
  float*          Hs  = (float*)(ws + 17301504);           // reuse: 4096*1024 f32
  unsigned short* Hb  = (unsigned short*)(ws + 34078720);  // 4096*1024 bf16
  unsigned short* Qh = (unsigned short*)(ws + 70778880);   // 64*1088*64 bf16
  unsigned short* Kh = (unsigned short*)(ws + 79691776);   // 64*1088*64 bf16
  unsigned short* Vt = (unsigned short*)(ws + 88604672);   // 64*64*1088 bf16
  float*          sc = (float*)(ws + 97517568);            // scalars
  float*          out = (float*)d_out;

  k_init<<<1, 64, 0, stream>>>(sc);
  k_wnorm<<<768, 256, 0, stream>>>(w_qkv, Wq, 3072);
  k_wnorm<<<256, 256, 0, stream>>>(w_out, Wo, 1024);
  k_xext<<<4352, 256, 0, stream>>>(x, sink, Xe);
  k_rownorm<<<256, 256, 0, stream>>>(x, 4096, 1.0f, sc + 0);
  k_rownorm<<<1, 256, 0, stream>>>(sink, 1, 4.0f, sc + 0);
  k_gemm256<<<17 * 12, 512, 0, stream>>>(Xe, Wq, qkv, 3072, 1024, 12);
  k_postproc<<<dim3(17, 64), 256, 0, stream>>>(qkv, re, Qh, Kh, Vt);
  k_attn<<<1024, 128, 0, stream>>>(Qh, Kh, Vt, Hs);
  k_rownorm<<<256, 256, 0, stream>>>(Hs, 4096, 1.0f, sc + 1);
  k_ratio<<<1, 64, 0, stream>>>(sc);
  k_scalecast<<<4096, 256, 0, stream>>>(Hs, sc, Hb);
  k_gemm<<<dim3(8, 32), 256, 0, stream>>>(Hb, Wo, out, 4096, 1024, 1024);
}

// Round 5
// 156.899 us; speedup vs baseline: 1.9525x; 1.0585x over previous
//
#include <hip/hip_runtime.h>
#include <hip/hip_bf16.h>
#include <cstdint>

typedef __attribute__((ext_vector_type(8))) short short8;
typedef __attribute__((ext_vector_type(4))) float f32x4;

typedef const unsigned int __attribute__((address_space(1)))* gas_ptr;
typedef unsigned int __attribute__((address_space(3)))* las_ptr;

__device__ static inline void async16(const void* g, void* l) {
  __builtin_amdgcn_global_load_lds((gas_ptr)g, (las_ptr)l, 16, 0, 0);
}

__device__ static inline unsigned short f2bf(float f) {
  union { float f; uint32_t u; } v; v.f = f;
  uint32_t u = v.u;
  uint32_t r = (u + 0x7FFFu + ((u >> 16) & 1u)) >> 16;
  return (unsigned short)r;
}
__device__ static inline float bf2f(unsigned short s) {
  union { uint32_t u; float f; } v; v.u = ((uint32_t)s) << 16; return v.f;
}

__device__ static inline float wave_sum(float v) {
  v += __shfl_xor(v, 1);  v += __shfl_xor(v, 2);  v += __shfl_xor(v, 4);
  v += __shfl_xor(v, 8);  v += __shfl_xor(v, 16); v += __shfl_xor(v, 32);
  return v;
}

#define SBAR __builtin_amdgcn_sched_barrier(0)
#define PRE_MFMA do { SBAR; __builtin_amdgcn_s_barrier(); \
  asm volatile("s_waitcnt lgkmcnt(0)" ::: "memory"); SBAR; \
  __builtin_amdgcn_s_setprio(1); } while (0)
#define POST_MFMA do { __builtin_amdgcn_s_setprio(0); SBAR; \
  __builtin_amdgcn_s_barrier(); } while (0)

// ---------------- small utility kernels ----------------

// scalars init + cos/sin tables ct/st[1024][16]
__global__ __launch_bounds__(256) void k_init_trig(const float* __restrict__ re,
    float* __restrict__ ct, float* __restrict__ st, float* __restrict__ sc) {
  int i = blockIdx.x * 256 + threadIdx.x;
  if (i < 4) sc[i] = 0.0f;
  int s = i >> 4, r = i & 15;
  float f = re[s * 32 + r];
  ct[i] = cosf(f);
  st[i] = sinf(f);
}

__global__ __launch_bounds__(256) void k_wnorm(const float* __restrict__ W,
                                               unsigned short* __restrict__ E, int rows) {
  int row = blockIdx.x * 4 + (threadIdx.x >> 6);
  int l = threadIdx.x & 63;
  if (row >= rows) return;
  const float* wr = W + (size_t)row * 1024;
  float4 v[4];
  float s = 0.f;
  for (int i = 0; i < 4; ++i) {
    v[i] = *(const float4*)(wr + i * 256 + l * 4);
    s += v[i].x * v[i].x + v[i].y * v[i].y + v[i].z * v[i].z + v[i].w * v[i].w;
  }
  s = wave_sum(s);
  float inv = 1.0f / (0.0032f + sqrtf(s));
  unsigned short* er = E + (size_t)row * 1024;
  for (int i = 0; i < 4; ++i) {
    ushort4 o = make_ushort4(f2bf(v[i].x * inv), f2bf(v[i].y * inv),
                             f2bf(v[i].z * inv), f2bf(v[i].w * inv));
    *(ushort4*)(er + i * 256 + l * 4) = o;
  }
}

// build x_ext bf16 [4352][1024]
__global__ __launch_bounds__(256) void k_xext(const float* __restrict__ x,
    const float* __restrict__ sink, unsigned short* __restrict__ Xe) {
  int i = blockIdx.x * 256 + threadIdx.x;
  int row = i >> 8;
  int c4 = (i & 255) * 4;
  ushort4 o;
  if (row < 4100) {
    int b = row / 1025, s = row % 1025;
    const float* src = (s < 1024) ? (x + ((size_t)(b * 1024 + s)) * 1024 + c4) : (sink + c4);
    float4 v = *(const float4*)src;
    o = make_ushort4(f2bf(v.x), f2bf(v.y), f2bf(v.z), f2bf(v.w));
  } else {
    o = make_ushort4(0, 0, 0, 0);
  }
  *(ushort4*)(Xe + (size_t)row * 1024 + c4) = o;
}

// grid-stride sum of row L2 norms * mult; one atomic per block
__global__ __launch_bounds__(256) void k_rownorm(const float* __restrict__ X, int rows,
                                                 float mult, float* __restrict__ acc) {
  __shared__ float red[4];
  const int w = threadIdx.x >> 6, l = threadIdx.x & 63;
  float local = 0.f;
  for (int row = blockIdx.x * 4 + w; row < rows; row += gridDim.x * 4) {
    const float* xr = X + (size_t)row * 1024;
    float s = 0.f;
    for (int i = 0; i < 4; ++i) {
      float4 v = *(const float4*)(xr + i * 256 + l * 4);
      s += v.x * v.x + v.y * v.y + v.z * v.z + v.w * v.w;
    }
    s = wave_sum(s);
    local += sqrtf(s);
  }
  if (l == 0) red[w] = local;
  __syncthreads();
  if (threadIdx.x == 0)
    atomicAdd(acc, mult * (red[0] + red[1] + red[2] + red[3]));
}

__global__ __launch_bounds__(64) void k_ratio(float* sc) {
  if (threadIdx.x == 0) sc[2] = (sc[0] / 4100.0f) / (sc[1] / 4096.0f);
}

__global__ __launch_bounds__(256) void k_scalecast(const float* __restrict__ Hs,
    const float* __restrict__ sc, unsigned short* __restrict__ Hb) {
  int i = blockIdx.x * 256 + threadIdx.x;
  float ratio = sc[2];
  float4 v = *(const float4*)(Hs + (size_t)i * 4);
  ushort4 o = make_ushort4(f2bf(v.x * ratio), f2bf(v.y * ratio),
                           f2bf(v.z * ratio), f2bf(v.w * ratio));
  *(ushort4*)(Hb + (size_t)i * 4) = o;
}

// zero K pad rows 1025..1087 and Vt pad cols 1025..1087
__global__ __launch_bounds__(256) void k_zeropad(unsigned short* __restrict__ Kh,
                                                 unsigned short* __restrict__ Vt) {
  int i = blockIdx.x * 256 + threadIdx.x;
  const int total = 64 * 63 * 64;
  if (i >= total) return;
  int bh = i / (63 * 64);
  int rest = i % (63 * 64);
  int row = rest / 64, d = rest % 64;
  Kh[((size_t)bh * 1088 + 1025 + row) * 64 + d] = 0;
  Vt[((size_t)bh * 64 + d) * 1088 + 1025 + row] = 0;
}

// ---------------- GEMM 128x128 (2-phase, for the small output GEMM) ----------------
__global__ __launch_bounds__(256) void k_gemm(const unsigned short* __restrict__ A,
                                              const unsigned short* __restrict__ B,
                                              float* __restrict__ C, int M, int N, int K) {
  __shared__ __align__(16) short Al[128 * 64];
  __shared__ __align__(16) short Bl[128 * 64];
  const int t = threadIdx.x, l = t & 63, w = t >> 6;
  const int r = l & 15, g = l >> 4;
  const int wm = w >> 1, wn = w & 1;
  const size_t tm = (size_t)blockIdx.y * 128, tn = (size_t)blockIdx.x * 128;
  f32x4 acc[4][4] = {};
  for (int kt = 0; kt < K; kt += 64) {
    __syncthreads();
    for (int i = 0; i < 4; ++i) {
      int c = i * 256 + t;
      int row = c >> 3, k8 = (c & 7) * 8;
      async16(A + (tm + row) * K + kt + k8, Al + (i * 256 + w * 64) * 8);
    }
    for (int i = 0; i < 4; ++i) {
      int c = i * 256 + t;
      int row = c >> 3, k8 = (c & 7) * 8;
      async16(B + (tn + row) * K + kt + k8, Bl + (i * 256 + w * 64) * 8);
    }
    __syncthreads();
    for (int ks = 0; ks < 2; ++ks) {
      short8 af[4], bfr[4];
      for (int mi = 0; mi < 4; ++mi)
        af[mi] = *(const short8*)(Al + (wm * 64 + mi * 16 + r) * 64 + ks * 32 + g * 8);
      for (int ni = 0; ni < 4; ++ni)
        bfr[ni] = *(const short8*)(Bl + (wn * 64 + ni * 16 + r) * 64 + ks * 32 + g * 8);
      for (int mi = 0; mi < 4; ++mi)
        for (int ni = 0; ni < 4; ++ni)
          acc[mi][ni] = __builtin_amdgcn_mfma_f32_16x16x32_bf16(af[mi], bfr[ni], acc[mi][ni], 0, 0, 0);
    }
  }
  for (int mi = 0; mi < 4; ++mi)
    for (int ni = 0; ni < 4; ++ni)
      for (int j = 0; j < 4; ++j) {
        size_t row = tm + wm * 64 + mi * 16 + g * 4 + j;
        size_t col = tn + wn * 64 + ni * 16 + r;
        C[row * (size_t)N + col] = acc[mi][ni][j];
      }
}

// ---------------- fused QKV GEMM 256x256 + RoPE + head-normalize + V-transpose ----------
// A=Xe[4352][1024], B=Wq[3072][1024]; grid 17*12; each wave's 64 output cols = one head.
__global__ __launch_bounds__(512) void k_gemm256qkv(const unsigned short* __restrict__ A,
    const unsigned short* __restrict__ B,
    unsigned short* __restrict__ Qh, unsigned short* __restrict__ Kh,
    unsigned short* __restrict__ Vt,
    const float* __restrict__ ct, const float* __restrict__ st) {
  const int N = 3072, K = 1024, ntn = 12;
  __shared__ __align__(16) short SMEM[65536];   // 128 KiB: As[2]|Bs[2], reused for V-transpose
  const int t = threadIdx.x, l = t & 63;
  const int w = t >> 6, r = l & 15, g = l >> 4;
  const int wm = w >> 2, wn = w & 3;
  // bijective XCD swizzle (m204)
  const int nwg = gridDim.x;
  const int q = nwg >> 3, rr = nwg & 7;
  const int xcd = blockIdx.x & 7, loc = blockIdx.x >> 3;
  const int wgid = (xcd < rr ? xcd * (q + 1) : rr * (q + 1) + (xcd - rr) * q) + loc;
  const int tm = wgid / ntn, tn = wgid % ntn;
  const size_t am0 = (size_t)tm * 256, bn0 = (size_t)tn * 256;
  const int NT = K >> 6;
  const int srow = t >> 3, sch = t & 7;

  auto stA = [&](int buf, int half, int kt) {
    const unsigned short* src = A + (am0 + half * 128) * (size_t)K + kt * 64;
    short* dst = SMEM + buf * 16384 + half * 8192;
    async16(src + (size_t)srow * K + ((sch ^ (srow & 7)) << 3), dst + t * 8);
    async16(src + (size_t)(srow + 64) * K + ((sch ^ (srow & 7)) << 3), dst + (512 + t) * 8);
  };
  auto stB = [&](int buf, int half, int kt) {
    const unsigned short* src = B + (bn0 + half * 128) * (size_t)K + kt * 64;
    short* dst = SMEM + 32768 + buf * 16384 + half * 8192;
    async16(src + (size_t)srow * K + ((sch ^ (srow & 7)) << 3), dst + t * 8);
    async16(src + (size_t)(srow + 64) * K + ((sch ^ (srow & 7)) << 3), dst + (512 + t) * 8);
  };

  f32x4 acc[8][4] = {};
  short8 aL[4][2], aH[4][2], bL[2][2], bH[2][2];
  const int arow_base = wm * 128 + r;
  const int brow_base = wn * 64 + r;

  stA(0, 0, 0); stA(0, 1, 0); stB(0, 0, 0); stB(0, 1, 0);
  stA(1, 0, 1); stA(1, 1, 1);
  asm volatile("s_waitcnt vmcnt(4)" ::: "memory"); SBAR;
  __builtin_amdgcn_s_barrier();

  for (int tt = 0; tt < NT; ++tt) {
    const int buf = tt & 1;
    const short* Asb = SMEM + buf * 16384;
    const short* Bsb = SMEM + 32768 + buf * 16384;
    // ---- phase 1
    #pragma unroll
    for (int mi = 0; mi < 4; ++mi)
      #pragma unroll
      for (int ks = 0; ks < 2; ++ks) {
        const int arow = arow_base + mi * 16;
        aL[mi][ks] = *(const short8*)(Asb + arow * 64 + (((ks * 4 + g) ^ (arow & 7)) << 3));
      }
    #pragma unroll
    for (int ni = 0; ni < 2; ++ni)
      #pragma unroll
      for (int ks = 0; ks < 2; ++ks) {
        const int brow = brow_base + ni * 16;
        bL[ni][ks] = *(const short8*)(Bsb + brow * 64 + (((ks * 4 + g) ^ (brow & 7)) << 3));
      }
    if (tt + 1 < NT) stB(buf ^ 1, 0, tt + 1);
    PRE_MFMA;
    #pragma unroll
    for (int mi = 0; mi < 4; ++mi)
      #pragma unroll
      for (int ni = 0; ni < 2; ++ni)
        #pragma unroll
        for (int ks = 0; ks < 2; ++ks)
          acc[mi][ni] = __builtin_amdgcn_mfma_f32_16x16x32_bf16(aL[mi][ks], bL[ni][ks], acc[mi][ni], 0, 0, 0);
    POST_MFMA;
    // ---- phase 2
    #pragma unroll
    for (int ni = 0; ni < 2; ++ni)
      #pragma unroll
      for (int ks = 0; ks < 2; ++ks) {
        const int brow = brow_base + (ni + 2) * 16;
        bH[ni][ks] = *(const short8*)(Bsb + brow * 64 + (((ks * 4 + g) ^ (brow & 7)) << 3));
      }
    if (tt + 1 < NT) stB(buf ^ 1, 1, tt + 1);
    PRE_MFMA;
    #pragma unroll
    for (int mi = 0; mi < 4; ++mi)
      #pragma unroll
      for (int ni = 0; ni < 2; ++ni)
        #pragma unroll
        for (int ks = 0; ks < 2; ++ks)
          acc[mi][ni + 2] = __builtin_amdgcn_mfma_f32_16x16x32_bf16(aL[mi][ks], bH[ni][ks], acc[mi][ni + 2], 0, 0, 0);
    POST_MFMA;
    // ---- phase 3
    #pragma unroll
    for (int mi = 0; mi < 4; ++mi)
      #pragma unroll
      for (int ks = 0; ks < 2; ++ks) {
        const int arow = arow_base + (mi + 4) * 16;
        aH[mi][ks] = *(const short8*)(Asb + arow * 64 + (((ks * 4 + g) ^ (arow & 7)) << 3));
      }
    PRE_MFMA;
    #pragma unroll
    for (int mi = 0; mi < 4; ++mi)
      #pragma unroll
      for (int ni = 0; ni < 2; ++ni)
        #pragma unroll
        for (int ks = 0; ks < 2; ++ks)
          acc[mi + 4][ni + 2] = __builtin_amdgcn_mfma_f32_16x16x32_bf16(aH[mi][ks], bH[ni][ks], acc[mi + 4][ni + 2], 0, 0, 0);
    POST_MFMA;
    // ---- phase 4
    if (tt + 2 < NT) { stA(buf, 0, tt + 2); stA(buf, 1, tt + 2); }
    PRE_MFMA;
    #pragma unroll
    for (int mi = 0; mi < 4; ++mi)
      #pragma unroll
      for (int ni = 0; ni < 2; ++ni)
        #pragma unroll
        for (int ks = 0; ks < 2; ++ks)
          acc[mi + 4][ni] = __builtin_amdgcn_mfma_f32_16x16x32_bf16(aH[mi][ks], bL[ni][ks], acc[mi + 4][ni], 0, 0, 0);
    __builtin_amdgcn_s_setprio(0); SBAR;
    if (tt + 1 < NT) {
      if (tt + 2 < NT) { asm volatile("s_waitcnt vmcnt(4)" ::: "memory"); }
      else             { asm volatile("s_waitcnt vmcnt(0)" ::: "memory"); }
      SBAR;
      __builtin_amdgcn_s_barrier();
    }
  }

  __syncthreads();   // drain all waves' LDS reads before SMEM reuse

  // ---- fused epilogue ----
  const int head_global = tn * 4 + wn;   // 0..47; sel block-uniform
  const int sel = head_global >> 4;      // 0=q, 1=k, 2=v
  const int h = head_global & 15;
  const int row0 = (int)am0 + wm * 128;

  if (sel < 2) {
    unsigned short* dst = (sel == 0) ? Qh : Kh;
    #pragma unroll
    for (int mi = 0; mi < 8; ++mi)
      #pragma unroll
      for (int j = 0; j < 4; ++j) {
        const int row = row0 + mi * 16 + g * 4 + j;
        const int b = row / 1025, s = row - b * 1025;
        float cs = 1.f, sn = 0.f;
        if (s < 1024) { cs = ct[s * 16 + r]; sn = st[s * 16 + r]; }
        const float a0 = acc[mi][0][j], a1 = acc[mi][1][j];
        const float a2 = acc[mi][2][j], a3 = acc[mi][3][j];
        const float r0 = a0 * cs - a1 * sn;
        const float r1 = a1 * cs + a0 * sn;
        float nrm = r0 * r0 + r1 * r1 + a2 * a2 + a3 * a3;
        nrm += __shfl_xor(nrm, 1); nrm += __shfl_xor(nrm, 2);
        nrm += __shfl_xor(nrm, 4); nrm += __shfl_xor(nrm, 8);
        const float inv = 1.0f / sqrtf(nrm);
        if (row < 4100) {
          const size_t base = ((size_t)(b * 16 + h) * 1088 + s) * 64 + r;
          dst[base]      = f2bf(r0 * inv);
          dst[base + 16] = f2bf(r1 * inv);
          dst[base + 32] = f2bf(a2 * inv);
          dst[base + 48] = f2bf(a3 * inv);
        }
      }
  } else {
    // V: per-wave LDS transpose (XOR-swizzled), then coalesced Vt writes
    short* vs = SMEM + w * 8192;   // 16 KB per wave
    #pragma unroll
    for (int mi = 0; mi < 8; ++mi)
      #pragma unroll
      for (int j = 0; j < 4; ++j) {
        const int sloc = mi * 16 + g * 4 + j;
        #pragma unroll
        for (int ni = 0; ni < 4; ++ni) {
          const int d = ni * 16 + r;
          vs[d * 128 + (sloc ^ ((d & 15) << 3))] = (short)f2bf(acc[mi][ni][j]);
        }
      }
    asm volatile("s_waitcnt lgkmcnt(0)" ::: "memory"); SBAR;
    #pragma unroll
    for (int ii = 0; ii < 16; ++ii) {
      const int d = ii * 4 + g;          // 0..63
      const int s0 = r * 8;              // chunk of 8 seq positions
      short8 vv = *(const short8*)(vs + d * 128 + (s0 ^ ((d & 15) << 3)));
      const int grow = row0 + s0;
      const int b0 = grow / 1025, b7 = (grow + 7) / 1025;
      if (b0 == b7 && grow + 7 < 4100) {
        const int s = grow - b0 * 1025;
        *(short8*)(Vt + ((size_t)(b0 * 16 + h) * 64 + d) * 1088 + s) = vv;
      } else {
        for (int k2 = 0; k2 < 8; ++k2) {
          const int gr = grow + k2;
          if (gr >= 4100) break;
          const int bb = gr / 1025, ss = gr - bb * 1025;
          Vt[((size_t)(bb * 16 + h) * 64 + d) * 1088 + ss] = (unsigned short)vv[k2];
        }
      }
    }
  }
}

// ---------------- attention: causal + sink, balanced strip pairs, swizzled LDS ----------------
__global__ __launch_bounds__(128) void k_attn(const unsigned short* __restrict__ Qh,
    const unsigned short* __restrict__ Kh, const unsigned short* __restrict__ Vt,
    float* __restrict__ H) {
  __shared__ __align__(16) short Kl[2][64 * 64];
  __shared__ __align__(16) short Vl[2][64 * 64];
  __shared__ __align__(16) short Pl[2 * 16 * 64];
  const int wid = blockIdx.x;
  const int xcd = wid & 7, jj = wid >> 3;
  const int bh = xcd + 8 * (jj >> 4), pp = jj & 15;
  const int b = bh >> 4, hh = bh & 15;
  const int t = threadIdx.x, l = t & 63, w = t >> 6;
  const int r = l & 15, g = l >> 4;

  auto stage = [&](int buf, int kt) {
    for (int i = 0; i < 4; ++i) {
      int c = i * 128 + t;
      int row = c >> 3, ch = c & 7;
      int sch = ch ^ (row & 7);
      async16(Kh + ((size_t)bh * 1088 + kt * 64 + row) * 64 + sch * 8,
              Kl[buf] + (i * 128 + w * 64) * 8);
      async16(Vt + ((size_t)bh * 64 + row) * 1088 + kt * 64 + sch * 8,
              Vl[buf] + (i * 128 + w * 64) * 8);
    }
  };

  for (int sidx = 0; sidx < 2; ++sidx) {
    const int strip = sidx == 0 ? pp : 31 - pp;
    const int qrow0 = strip * 32 + w * 16;
    short8 qf[2];
    for (int ks = 0; ks < 2; ++ks)
      qf[ks] = *(const short8*)(Qh + ((size_t)bh * 1088 + qrow0 + r) * 64 + ks * 32 + g * 8);
    const int nt = strip / 2 + 2;
    f32x4 oacc[4] = {};
    float lsum[4] = {0.f, 0.f, 0.f, 0.f};
    stage(0, 0);
    __syncthreads();
    int cur = 0;
    for (int i = 0; i < nt; ++i) {
      const int kt = (i < nt - 1) ? i : 16;
      if (i + 1 < nt) stage(cur ^ 1, (i + 1 < nt - 1) ? (i + 1) : 16);
      for (int nc = 0; nc < 4; ++nc) {
        f32x4 sc = {};
        for (int ks = 0; ks < 2; ++ks) {
          const int row = nc * 16 + r;
          const short8 kf = *(const short8*)(Kl[cur] + row * 64 + (((ks * 4 + g) ^ (row & 7)) << 3));
          sc = __builtin_amdgcn_mfma_f32_16x16x32_bf16(qf[ks], kf, sc, 0, 0, 0);
        }
        const int col = kt * 64 + nc * 16 + r;
        for (int j = 0; j < 4; ++j) {
          const int qrow = qrow0 + g * 4 + j;
          const bool valid = (col <= qrow) || (col == 1024);
          float p = valid ? __expf(sc[j]) : 0.0f;
          unsigned short pb = f2bf(p);
          lsum[j] += bf2f(pb);
          const int prow = w * 16 + g * 4 + j;
          const int bir = (nc * 16 + r) * 2;
          char* pd = (char*)Pl + prow * 128 + ((((unsigned)bir >> 4) ^ (prow & 7)) << 4) + (bir & 15);
          *(short*)pd = (short)pb;
        }
      }
      for (int ks = 0; ks < 2; ++ks) {
        const int prow = w * 16 + r;
        const short8 pf = *(const short8*)((char*)Pl + prow * 128 + (((ks * 4 + g) ^ (r & 7)) << 4));
        for (int nd = 0; nd < 4; ++nd) {
          const int vrow = nd * 16 + r;
          const short8 vf = *(const short8*)(Vl[cur] + vrow * 64 + (((ks * 4 + g) ^ (vrow & 7)) << 3));
          oacc[nd] = __builtin_amdgcn_mfma_f32_16x16x32_bf16(pf, vf, oacc[nd], 0, 0, 0);
        }
      }
      __syncthreads();
      cur ^= 1;
    }
    for (int j = 0; j < 4; ++j) {
      float v = lsum[j];
      v += __shfl_xor(v, 1); v += __shfl_xor(v, 2);
      v += __shfl_xor(v, 4); v += __shfl_xor(v, 8);
      lsum[j] = v;
    }
    for (int nd = 0; nd < 4; ++nd)
      for (int j = 0; j < 4; ++j) {
        const int srow = qrow0 + g * 4 + j;
        H[((size_t)(b * 1024 + srow)) * 1024 + hh * 64 + nd * 16 + r] = oacc[nd][j] / lsum[j];
      }
  }
}

// ---------------- launcher ----------------
extern "C" void kernel_launch(void* const* d_in, const int* in_sizes, int n_in,
                              void* d_out, int out_size, void* d_ws, size_t ws_size,
                              hipStream_t stream) {
  const float* x     = (const float*)d_in[0];
  const float* re    = (const float*)d_in[1];
  const float* w_qkv = (const float*)d_in[3];
  const float* w_out = (const float*)d_in[4];
  const float* sink  = (const float*)d_in[5];
  char* ws = (char*)d_ws;

  unsigned short* Wq = (unsigned short*)(ws + 0);          // 3072*1024 bf16
  unsigned short* Wo = (unsigned short*)(ws + 6291456);    // 1024*1024 bf16
  unsigned short* Xe = (unsigned short*)(ws + 8388608);    // 4352*1024 bf16
  float*          Hs = (float*)(ws + 17301504);            // 4096*1024 f32
  unsigned short* Hb = (unsigned short*)(ws + 34078720);   // 4096*1024 bf16
  unsigned short* Qh = (unsigned short*)(ws + 42467328);   // 64*1088*64 bf16
  unsigned short* Kh = (unsigned short*)(ws + 51380224);   // 64*1088*64 bf16
  unsigned short* Vt = (unsigned short*)(ws + 60293120);   // 64*64*1088 bf16
  float*          ct = (float*)(ws + 69206016);            // 1024*16 f32
  float*          st = (float*)(ws + 69271552);            // 1024*16 f32
  float*          sc = (float*)(ws + 69337088);            // scalars
  float*          out = (float*)d_out;

  k_init_trig<<<64, 256, 0, stream>>>(re, ct, st, sc);
  k_wnorm<<<768, 256, 0, stream>>>(w_qkv, Wq, 3072);
  k_wnorm<<<256, 256, 0, stream>>>(w_out, Wo, 1024);
  k_xext<<<4352, 256, 0, stream>>>(x, sink, Xe);
  k_rownorm<<<256, 256, 0, stream>>>(x, 4096, 1.0f, sc + 0);
  k_rownorm<<<1, 256, 0, stream>>>(sink, 1, 4.0f, sc + 0);
  k_zeropad<<<1008, 256, 0, stream>>>(Kh, Vt);
  k_gemm256qkv<<<17 * 12, 512, 0, stream>>>(Xe, Wq, Qh, Kh, Vt, ct, st);
  k_attn<<<1024, 128, 0, stream>>>(Qh, Kh, Vt, Hs);
  k_rownorm<<<256, 256, 0, stream>>>(Hs, 4096, 1.0f, sc + 1);
  k_ratio<<<1, 64, 0, stream>>>(sc);
  k_scalecast<<<4096, 256, 0, stream>>>(Hs, sc, Hb);
  k_gemm<<<dim3(8, 32), 256, 0, stream>>>(Hb, Wo, out, 4096, 1024, 1024);
}

// Round 6
// 142.992 us; speedup vs baseline: 2.1424x; 1.0973x over previous
//
#include <hip/hip_runtime.h>
#include <hip/hip_bf16.h>
#include <cstdint>

typedef __attribute__((ext_vector_type(8))) short short8;
typedef __attribute__((ext_vector_type(4))) float f32x4;

typedef const unsigned int __attribute__((address_space(1)))* gas_ptr;
typedef unsigned int __attribute__((address_space(3)))* las_ptr;

__device__ static inline void async16(const void* g, void* l) {
  __builtin_amdgcn_global_load_lds((gas_ptr)g, (las_ptr)l, 16, 0, 0);
}

__device__ static inline unsigned short f2bf(float f) {
  union { float f; uint32_t u; } v; v.f = f;
  uint32_t u = v.u;
  uint32_t r = (u + 0x7FFFu + ((u >> 16) & 1u)) >> 16;
  return (unsigned short)r;
}
__device__ static inline float bf2f(unsigned short s) {
  union { uint32_t u; float f; } v; v.u = ((uint32_t)s) << 16; return v.f;
}

__device__ static inline float wave_sum(float v) {
  v += __shfl_xor(v, 1);  v += __shfl_xor(v, 2);  v += __shfl_xor(v, 4);
  v += __shfl_xor(v, 8);  v += __shfl_xor(v, 16); v += __shfl_xor(v, 32);
  return v;
}

#define SBAR __builtin_amdgcn_sched_barrier(0)
#define PRE_MFMA do { SBAR; __builtin_amdgcn_s_barrier(); \
  asm volatile("s_waitcnt lgkmcnt(0)" ::: "memory"); SBAR; \
  __builtin_amdgcn_s_setprio(1); } while (0)
#define POST_MFMA do { __builtin_amdgcn_s_setprio(0); SBAR; \
  __builtin_amdgcn_s_barrier(); } while (0)

// ---------------- small utility kernels ----------------

// zero scalars+cells, build transposed trig tables ctT/stT[16][1024]
__global__ __launch_bounds__(256) void k_init_trig(const float* __restrict__ re,
    float* __restrict__ ctT, float* __restrict__ stT, float* __restrict__ sc) {
  int i = blockIdx.x * 256 + threadIdx.x;   // 16384 threads
  if (i < 1040) sc[i] = 0.0f;
  int s = i >> 4, r = i & 15;
  float f = re[s * 32 + r];
  ctT[r * 1024 + s] = cosf(f);
  stT[r * 1024 + s] = sinf(f);
}

__global__ __launch_bounds__(256) void k_wnorm(const float* __restrict__ W,
                                               unsigned short* __restrict__ E, int rows) {
  int row = blockIdx.x * 4 + (threadIdx.x >> 6);
  int l = threadIdx.x & 63;
  if (row >= rows) return;
  const float* wr = W + (size_t)row * 1024;
  float4 v[4];
  float s = 0.f;
  for (int i = 0; i < 4; ++i) {
    v[i] = *(const float4*)(wr + i * 256 + l * 4);
    s += v[i].x * v[i].x + v[i].y * v[i].y + v[i].z * v[i].z + v[i].w * v[i].w;
  }
  s = wave_sum(s);
  float inv = 1.0f / (0.0032f + sqrtf(s));
  unsigned short* er = E + (size_t)row * 1024;
  for (int i = 0; i < 4; ++i) {
    ushort4 o = make_ushort4(f2bf(v[i].x * inv), f2bf(v[i].y * inv),
                             f2bf(v[i].z * inv), f2bf(v[i].w * inv));
    *(ushort4*)(er + i * 256 + l * 4) = o;
  }
}

// build x_ext bf16 [4352][1024] AND accumulate sum of row L2 norms into spread cells
__global__ __launch_bounds__(256) void k_xext(const float* __restrict__ x,
    const float* __restrict__ sink, unsigned short* __restrict__ Xe,
    float* __restrict__ sc) {
  __shared__ float red[4];
  const int row = blockIdx.x;
  const int tid = threadIdx.x, w = tid >> 6, l = tid & 63;
  const int c4 = tid * 4;
  float4 v = make_float4(0.f, 0.f, 0.f, 0.f);
  if (row < 4100) {
    int b = row / 1025, s = row - b * 1025;
    const float* src = (s < 1024) ? (x + ((size_t)(b * 1024 + s)) * 1024 + c4) : (sink + c4);
    v = *(const float4*)src;
  }
  *(ushort4*)(Xe + (size_t)row * 1024 + c4) =
      make_ushort4(f2bf(v.x), f2bf(v.y), f2bf(v.z), f2bf(v.w));
  float ss = v.x * v.x + v.y * v.y + v.z * v.z + v.w * v.w;
  ss = wave_sum(ss);
  if (l == 0) red[w] = ss;
  __syncthreads();
  if (tid == 0 && row < 4100)
    atomicAdd(sc + 16 + (row & 63) * 16, sqrtf(red[0] + red[1] + red[2] + red[3]));
}

// sum of row L2 norms of Hb (bf16 [4096][1024]) -> sc[1]
__global__ __launch_bounds__(256) void k_rownormB(const unsigned short* __restrict__ Hb,
                                                  float* __restrict__ acc) {
  __shared__ float red[4];
  const int w = threadIdx.x >> 6, l = threadIdx.x & 63;
  float local = 0.f;
  for (int row = blockIdx.x * 4 + w; row < 4096; row += gridDim.x * 4) {
    const unsigned short* hr = Hb + (size_t)row * 1024;
    float s = 0.f;
    for (int i = 0; i < 2; ++i) {
      short8 v = *(const short8*)(hr + i * 512 + l * 8);
      #pragma unroll
      for (int k = 0; k < 8; ++k) { float f = bf2f((unsigned short)v[k]); s += f * f; }
    }
    s = wave_sum(s);
    local += sqrtf(s);
  }
  if (l == 0) red[w] = local;
  __syncthreads();
  if (threadIdx.x == 0)
    atomicAdd(acc, red[0] + red[1] + red[2] + red[3]);
}

// ---------------- GEMM 128x128 (2-phase) with ratio epilogue: out = (A*B^T) * ratio ----
__global__ __launch_bounds__(256) void k_gemm(const unsigned short* __restrict__ A,
                                              const unsigned short* __restrict__ B,
                                              float* __restrict__ C, int M, int N, int K,
                                              const float* __restrict__ sc) {
  __shared__ __align__(16) short Al[128 * 64];
  __shared__ __align__(16) short Bl[128 * 64];
  const int t = threadIdx.x, l = t & 63, w = t >> 6;
  const int r = l & 15, g = l >> 4;
  const int wm = w >> 1, wn = w & 1;
  const size_t tm = (size_t)blockIdx.y * 128, tn = (size_t)blockIdx.x * 128;
  f32x4 acc[4][4] = {};
  for (int kt = 0; kt < K; kt += 64) {
    __syncthreads();
    for (int i = 0; i < 4; ++i) {
      int c = i * 256 + t;
      int row = c >> 3, k8 = (c & 7) * 8;
      async16(A + (tm + row) * K + kt + k8, Al + (i * 256 + w * 64) * 8);
    }
    for (int i = 0; i < 4; ++i) {
      int c = i * 256 + t;
      int row = c >> 3, k8 = (c & 7) * 8;
      async16(B + (tn + row) * K + kt + k8, Bl + (i * 256 + w * 64) * 8);
    }
    __syncthreads();
    for (int ks = 0; ks < 2; ++ks) {
      short8 af[4], bfr[4];
      for (int mi = 0; mi < 4; ++mi)
        af[mi] = *(const short8*)(Al + (wm * 64 + mi * 16 + r) * 64 + ks * 32 + g * 8);
      for (int ni = 0; ni < 4; ++ni)
        bfr[ni] = *(const short8*)(Bl + (wn * 64 + ni * 16 + r) * 64 + ks * 32 + g * 8);
      for (int mi = 0; mi < 4; ++mi)
        for (int ni = 0; ni < 4; ++ni)
          acc[mi][ni] = __builtin_amdgcn_mfma_f32_16x16x32_bf16(af[mi], bfr[ni], acc[mi][ni], 0, 0, 0);
    }
  }
  // ratio = (mean x_ext row norm) / (mean h row norm)
  float num = 0.f;
  #pragma unroll
  for (int i = 0; i < 64; ++i) num += sc[16 + i * 16];
  const float ratio = (num * (1.0f / 4100.0f)) * (4096.0f / sc[1]);
  for (int mi = 0; mi < 4; ++mi)
    for (int ni = 0; ni < 4; ++ni)
      for (int j = 0; j < 4; ++j) {
        size_t row = tm + wm * 64 + mi * 16 + g * 4 + j;
        size_t col = tn + wn * 64 + ni * 16 + r;
        C[row * (size_t)N + col] = acc[mi][ni][j] * ratio;
      }
}

// ---------------- fused QKV GEMM 256x256 + RoPE + head-normalize + V-transpose ----------
__global__ __launch_bounds__(512) void k_gemm256qkv(const unsigned short* __restrict__ A,
    const unsigned short* __restrict__ B,
    unsigned short* __restrict__ Qh, unsigned short* __restrict__ Kh,
    unsigned short* __restrict__ Vt,
    const float* __restrict__ ctT, const float* __restrict__ stT) {
  const int K = 1024, ntn = 12;
  __shared__ __align__(16) short SMEM[65536];   // 128 KiB
  const int t = threadIdx.x, l = t & 63;
  const int w = t >> 6, r = l & 15, g = l >> 4;
  const int wm = w >> 2, wn = w & 3;
  const int nwg = gridDim.x;
  const int q = nwg >> 3, rr = nwg & 7;
  const int xcd = blockIdx.x & 7, loc = blockIdx.x >> 3;
  const int wgid = (xcd < rr ? xcd * (q + 1) : rr * (q + 1) + (xcd - rr) * q) + loc;
  const int tm = wgid / ntn, tn = wgid % ntn;
  const size_t am0 = (size_t)tm * 256, bn0 = (size_t)tn * 256;
  const int NT = K >> 6;
  const int srow = t >> 3, sch = t & 7;

  auto stA = [&](int buf, int half, int kt) {
    const unsigned short* src = A + (am0 + half * 128) * (size_t)K + kt * 64;
    short* dst = SMEM + buf * 16384 + half * 8192;
    async16(src + (size_t)srow * K + ((sch ^ (srow & 7)) << 3), dst + t * 8);
    async16(src + (size_t)(srow + 64) * K + ((sch ^ (srow & 7)) << 3), dst + (512 + t) * 8);
  };
  auto stB = [&](int buf, int half, int kt) {
    const unsigned short* src = B + (bn0 + half * 128) * (size_t)K + kt * 64;
    short* dst = SMEM + 32768 + buf * 16384 + half * 8192;
    async16(src + (size_t)srow * K + ((sch ^ (srow & 7)) << 3), dst + t * 8);
    async16(src + (size_t)(srow + 64) * K + ((sch ^ (srow & 7)) << 3), dst + (512 + t) * 8);
  };

  f32x4 acc[8][4] = {};
  short8 aL[4][2], aH[4][2], bL[2][2], bH[2][2];
  const int arow_base = wm * 128 + r;
  const int brow_base = wn * 64 + r;

  stA(0, 0, 0); stA(0, 1, 0); stB(0, 0, 0); stB(0, 1, 0);
  stA(1, 0, 1); stA(1, 1, 1);
  asm volatile("s_waitcnt vmcnt(4)" ::: "memory"); SBAR;
  __builtin_amdgcn_s_barrier();

  for (int tt = 0; tt < NT; ++tt) {
    const int buf = tt & 1;
    const short* Asb = SMEM + buf * 16384;
    const short* Bsb = SMEM + 32768 + buf * 16384;
    // ---- phase 1
    #pragma unroll
    for (int mi = 0; mi < 4; ++mi)
      #pragma unroll
      for (int ks = 0; ks < 2; ++ks) {
        const int arow = arow_base + mi * 16;
        aL[mi][ks] = *(const short8*)(Asb + arow * 64 + (((ks * 4 + g) ^ (arow & 7)) << 3));
      }
    #pragma unroll
    for (int ni = 0; ni < 2; ++ni)
      #pragma unroll
      for (int ks = 0; ks < 2; ++ks) {
        const int brow = brow_base + ni * 16;
        bL[ni][ks] = *(const short8*)(Bsb + brow * 64 + (((ks * 4 + g) ^ (brow & 7)) << 3));
      }
    if (tt + 1 < NT) stB(buf ^ 1, 0, tt + 1);
    PRE_MFMA;
    #pragma unroll
    for (int mi = 0; mi < 4; ++mi)
      #pragma unroll
      for (int ni = 0; ni < 2; ++ni)
        #pragma unroll
        for (int ks = 0; ks < 2; ++ks)
          acc[mi][ni] = __builtin_amdgcn_mfma_f32_16x16x32_bf16(aL[mi][ks], bL[ni][ks], acc[mi][ni], 0, 0, 0);
    POST_MFMA;
    // ---- phase 2
    #pragma unroll
    for (int ni = 0; ni < 2; ++ni)
      #pragma unroll
      for (int ks = 0; ks < 2; ++ks) {
        const int brow = brow_base + (ni + 2) * 16;
        bH[ni][ks] = *(const short8*)(Bsb + brow * 64 + (((ks * 4 + g) ^ (brow & 7)) << 3));
      }
    if (tt + 1 < NT) stB(buf ^ 1, 1, tt + 1);
    PRE_MFMA;
    #pragma unroll
    for (int mi = 0; mi < 4; ++mi)
      #pragma unroll
      for (int ni = 0; ni < 2; ++ni)
        #pragma unroll
        for (int ks = 0; ks < 2; ++ks)
          acc[mi][ni + 2] = __builtin_amdgcn_mfma_f32_16x16x32_bf16(aL[mi][ks], bH[ni][ks], acc[mi][ni + 2], 0, 0, 0);
    POST_MFMA;
    // ---- phase 3
    #pragma unroll
    for (int mi = 0; mi < 4; ++mi)
      #pragma unroll
      for (int ks = 0; ks < 2; ++ks) {
        const int arow = arow_base + (mi + 4) * 16;
        aH[mi][ks] = *(const short8*)(Asb + arow * 64 + (((ks * 4 + g) ^ (arow & 7)) << 3));
      }
    PRE_MFMA;
    #pragma unroll
    for (int mi = 0; mi < 4; ++mi)
      #pragma unroll
      for (int ni = 0; ni < 2; ++ni)
        #pragma unroll
        for (int ks = 0; ks < 2; ++ks)
          acc[mi + 4][ni + 2] = __builtin_amdgcn_mfma_f32_16x16x32_bf16(aH[mi][ks], bH[ni][ks], acc[mi + 4][ni + 2], 0, 0, 0);
    POST_MFMA;
    // ---- phase 4
    if (tt + 2 < NT) { stA(buf, 0, tt + 2); stA(buf, 1, tt + 2); }
    PRE_MFMA;
    #pragma unroll
    for (int mi = 0; mi < 4; ++mi)
      #pragma unroll
      for (int ni = 0; ni < 2; ++ni)
        #pragma unroll
        for (int ks = 0; ks < 2; ++ks)
          acc[mi + 4][ni] = __builtin_amdgcn_mfma_f32_16x16x32_bf16(aH[mi][ks], bL[ni][ks], acc[mi + 4][ni], 0, 0, 0);
    __builtin_amdgcn_s_setprio(0); SBAR;
    if (tt + 1 < NT) {
      if (tt + 2 < NT) { asm volatile("s_waitcnt vmcnt(4)" ::: "memory"); }
      else             { asm volatile("s_waitcnt vmcnt(0)" ::: "memory"); }
      SBAR;
      __builtin_amdgcn_s_barrier();
    }
  }

  __syncthreads();   // drain all waves' LDS reads before SMEM reuse

  // ---- fused epilogue ----
  const int head_global = tn * 4 + wn;   // block-uniform sel
  const int sel = head_global >> 4;      // 0=q, 1=k, 2=v
  const int h = head_global & 15;
  const int row0 = (int)am0 + wm * 128;

  if (sel < 2) {
    unsigned short* dst = (sel == 0) ? Qh : Kh;
    #pragma unroll
    for (int mi = 0; mi < 8; ++mi) {
      const int rowb = row0 + mi * 16 + g * 4;
      const int b = rowb / 1025;
      const int s0 = rowb - b * 1025;
      float cs[4], sn[4];
      if (s0 + 3 < 1024) {
        float4 c4 = *(const float4*)(ctT + r * 1024 + s0);
        float4 s4 = *(const float4*)(stT + r * 1024 + s0);
        cs[0] = c4.x; cs[1] = c4.y; cs[2] = c4.z; cs[3] = c4.w;
        sn[0] = s4.x; sn[1] = s4.y; sn[2] = s4.z; sn[3] = s4.w;
      } else {
        #pragma unroll
        for (int j = 0; j < 4; ++j) {
          const int rj = rowb + j;
          const int bj = rj / 1025, sj = rj - bj * 1025;
          cs[j] = (sj < 1024) ? ctT[r * 1024 + sj] : 1.f;
          sn[j] = (sj < 1024) ? stT[r * 1024 + sj] : 0.f;
        }
      }
      #pragma unroll
      for (int j = 0; j < 4; ++j) {
        const int row = rowb + j;
        const int b2 = row / 1025, s = row - b2 * 1025;
        const float a0 = acc[mi][0][j], a1 = acc[mi][1][j];
        const float a2 = acc[mi][2][j], a3 = acc[mi][3][j];
        const float r0 = a0 * cs[j] - a1 * sn[j];
        const float r1 = a1 * cs[j] + a0 * sn[j];
        float nrm = r0 * r0 + r1 * r1 + a2 * a2 + a3 * a3;
        nrm += __shfl_xor(nrm, 1); nrm += __shfl_xor(nrm, 2);
        nrm += __shfl_xor(nrm, 4); nrm += __shfl_xor(nrm, 8);
        const float inv = rsqrtf(nrm);
        if (row < 4100) {
          const size_t base = ((size_t)(b2 * 16 + h) * 1088 + s) * 64 + r;
          dst[base]      = f2bf(r0 * inv);
          dst[base + 16] = f2bf(r1 * inv);
          dst[base + 32] = f2bf(a2 * inv);
          dst[base + 48] = f2bf(a3 * inv);
        }
      }
    }
  } else {
    // V: per-wave LDS transpose, packed b64 writes (conflict-free), coalesced Vt writes
    short* vs = SMEM + w * 8192;   // 16 KB per wave
    #pragma unroll
    for (int mi = 0; mi < 8; ++mi) {
      const int s0 = mi * 16 + g * 4;
      #pragma unroll
      for (int ni = 0; ni < 4; ++ni) {
        const int d = ni * 16 + r;
        ushort4 pk = make_ushort4(f2bf(acc[mi][ni][0]), f2bf(acc[mi][ni][1]),
                                  f2bf(acc[mi][ni][2]), f2bf(acc[mi][ni][3]));
        *(ushort4*)(vs + d * 128 + (s0 ^ ((d & 15) << 3))) = pk;
      }
    }
    asm volatile("s_waitcnt lgkmcnt(0)" ::: "memory"); SBAR;
    #pragma unroll
    for (int ii = 0; ii < 16; ++ii) {
      const int d = ii * 4 + g;
      const int s0 = r * 8;
      short8 vv = *(const short8*)(vs + d * 128 + (s0 ^ ((d & 15) << 3)));
      const int grow = row0 + s0;
      const int b0 = grow / 1025, b7 = (grow + 7) / 1025;
      if (b0 == b7 && grow + 7 < 4100) {
        const int s = grow - b0 * 1025;
        *(short8*)(Vt + ((size_t)(b0 * 16 + h) * 64 + d) * 1088 + s) = vv;
      } else {
        for (int k2 = 0; k2 < 8; ++k2) {
          const int gr = grow + k2;
          if (gr >= 4100) break;
          const int bb = gr / 1025, ss = gr - bb * 1025;
          Vt[((size_t)(bb * 16 + h) * 64 + d) * 1088 + ss] = (unsigned short)vv[k2];
        }
      }
    }
  }
}

// ---------------- attention: causal + sink, balanced strip pairs, swizzled LDS ----------------
__global__ __launch_bounds__(128) void k_attn(const unsigned short* __restrict__ Qh,
    const unsigned short* __restrict__ Kh, const unsigned short* __restrict__ Vt,
    unsigned short* __restrict__ Hb) {
  __shared__ __align__(16) short Kl[2][64 * 64];
  __shared__ __align__(16) short Vl[2][64 * 64];
  __shared__ __align__(16) short Pl[2 * 16 * 64];
  const int wid = blockIdx.x;
  const int xcd = wid & 7, jj = wid >> 3;
  const int bh = xcd + 8 * (jj >> 4), pp = jj & 15;
  const int b = bh >> 4, hh = bh & 15;
  const int t = threadIdx.x, l = t & 63, w = t >> 6;
  const int r = l & 15, g = l >> 4;

  auto stage = [&](int buf, int kt) {
    for (int i = 0; i < 4; ++i) {
      int c = i * 128 + t;
      int row = c >> 3, ch = c & 7;
      int sch = ch ^ (row & 7);
      async16(Kh + ((size_t)bh * 1088 + kt * 64 + row) * 64 + sch * 8,
              Kl[buf] + (i * 128 + w * 64) * 8);
      async16(Vt + ((size_t)bh * 64 + row) * 1088 + kt * 64 + sch * 8,
              Vl[buf] + (i * 128 + w * 64) * 8);
    }
  };

  for (int sidx = 0; sidx < 2; ++sidx) {
    const int strip = sidx == 0 ? pp : 31 - pp;
    const int qrow0 = strip * 32 + w * 16;
    short8 qf[2];
    for (int ks = 0; ks < 2; ++ks)
      qf[ks] = *(const short8*)(Qh + ((size_t)bh * 1088 + qrow0 + r) * 64 + ks * 32 + g * 8);
    const int nt = strip / 2 + 2;
    f32x4 oacc[4] = {};
    float lsum[4] = {0.f, 0.f, 0.f, 0.f};
    stage(0, 0);
    __syncthreads();
    int cur = 0;
    for (int i = 0; i < nt; ++i) {
      const int kt = (i < nt - 1) ? i : 16;
      if (i + 1 < nt) stage(cur ^ 1, (i + 1 < nt - 1) ? (i + 1) : 16);
      for (int nc = 0; nc < 4; ++nc) {
        f32x4 sc = {};
        for (int ks = 0; ks < 2; ++ks) {
          const int row = nc * 16 + r;
          const short8 kf = *(const short8*)(Kl[cur] + row * 64 + (((ks * 4 + g) ^ (row & 7)) << 3));
          sc = __builtin_amdgcn_mfma_f32_16x16x32_bf16(qf[ks], kf, sc, 0, 0, 0);
        }
        const int col = kt * 64 + nc * 16 + r;
        for (int j = 0; j < 4; ++j) {
          const int qrow = qrow0 + g * 4 + j;
          const bool valid = (col <= qrow) || (col == 1024);
          float p = valid ? __expf(sc[j]) : 0.0f;
          unsigned short pb = f2bf(p);
          lsum[j] += bf2f(pb);
          const int prow = w * 16 + g * 4 + j;
          const int bir = (nc * 16 + r) * 2;
          char* pd = (char*)Pl + prow * 128 + ((((unsigned)bir >> 4) ^ (prow & 7)) << 4) + (bir & 15);
          *(short*)pd = (short)pb;
        }
      }
      for (int ks = 0; ks < 2; ++ks) {
        const int prow = w * 16 + r;
        const short8 pf = *(const short8*)((char*)Pl + prow * 128 + (((ks * 4 + g) ^ (r & 7)) << 4));
        for (int nd = 0; nd < 4; ++nd) {
          const int vrow = nd * 16 + r;
          const short8 vf = *(const short8*)(Vl[cur] + vrow * 64 + (((ks * 4 + g) ^ (vrow & 7)) << 3));
          oacc[nd] = __builtin_amdgcn_mfma_f32_16x16x32_bf16(pf, vf, oacc[nd], 0, 0, 0);
        }
      }
      __syncthreads();
      cur ^= 1;
    }
    float inv[4];
    for (int j = 0; j < 4; ++j) {
      float v = lsum[j];
      v += __shfl_xor(v, 1); v += __shfl_xor(v, 2);
      v += __shfl_xor(v, 4); v += __shfl_xor(v, 8);
      inv[j] = 1.0f / v;
    }
    for (int nd = 0; nd < 4; ++nd)
      for (int j = 0; j < 4; ++j) {
        const int srow = qrow0 + g * 4 + j;
        Hb[((size_t)(b * 1024 + srow)) * 1024 + hh * 64 + nd * 16 + r] = f2bf(oacc[nd][j] * inv[j]);
      }
  }
}

// ---------------- launcher ----------------
extern "C" void kernel_launch(void* const* d_in, const int* in_sizes, int n_in,
                              void* d_out, int out_size, void* d_ws, size_t ws_size,
                              hipStream_t stream) {
  const float* x     = (const float*)d_in[0];
  const float* re    = (const float*)d_in[1];
  const float* w_qkv = (const float*)d_in[3];
  const float* w_out = (const float*)d_in[4];
  const float* sink  = (const float*)d_in[5];
  char* ws = (char*)d_ws;

  unsigned short* Wq  = (unsigned short*)(ws + 0);          // 3072*1024 bf16
  unsigned short* Wo  = (unsigned short*)(ws + 6291456);    // 1024*1024 bf16
  unsigned short* Xe  = (unsigned short*)(ws + 8388608);    // 4352*1024 bf16
  unsigned short* Hb  = (unsigned short*)(ws + 17301504);   // 4096*1024 bf16
  unsigned short* Qh  = (unsigned short*)(ws + 25690112);   // 64*1088*64 bf16
  unsigned short* Kh  = (unsigned short*)(ws + 34603008);   // 64*1088*64 bf16
  unsigned short* Vt  = (unsigned short*)(ws + 43515904);   // 64*64*1088 bf16
  float*          ctT = (float*)(ws + 52428800);            // 16*1024 f32
  float*          stT = (float*)(ws + 52494336);            // 16*1024 f32
  float*          sc  = (float*)(ws + 52559872);            // scalars + 64 spread cells
  float*          out = (float*)d_out;

  k_init_trig<<<64, 256, 0, stream>>>(re, ctT, stT, sc);
  k_wnorm<<<768, 256, 0, stream>>>(w_qkv, Wq, 3072);
  k_wnorm<<<256, 256, 0, stream>>>(w_out, Wo, 1024);
  k_xext<<<4352, 256, 0, stream>>>(x, sink, Xe, sc);
  k_gemm256qkv<<<17 * 12, 512, 0, stream>>>(Xe, Wq, Qh, Kh, Vt, ctT, stT);
  k_attn<<<1024, 128, 0, stream>>>(Qh, Kh, Vt, Hb);
  k_rownormB<<<256, 256, 0, stream>>>(Hb, sc + 1);
  k_gemm<<<dim3(8, 32), 256, 0, stream>>>(Hb, Wo, out, 4096, 1024, 1024, sc);
}

// Round 7
// 139.602 us; speedup vs baseline: 2.1945x; 1.0243x over previous
//
#include <hip/hip_runtime.h>
#include <hip/hip_bf16.h>
#include <cstdint>

typedef __attribute__((ext_vector_type(8))) short short8;
typedef __attribute__((ext_vector_type(4))) float f32x4;

typedef const unsigned int __attribute__((address_space(1)))* gas_ptr;
typedef unsigned int __attribute__((address_space(3)))* las_ptr;

__device__ static inline void async16(const void* g, void* l) {
  __builtin_amdgcn_global_load_lds((gas_ptr)g, (las_ptr)l, 16, 0, 0);
}

__device__ static inline unsigned short f2bf(float f) {
  union { float f; uint32_t u; } v; v.f = f;
  uint32_t u = v.u;
  uint32_t r = (u + 0x7FFFu + ((u >> 16) & 1u)) >> 16;
  return (unsigned short)r;
}
__device__ static inline float bf2f(unsigned short s) {
  union { uint32_t u; float f; } v; v.u = ((uint32_t)s) << 16; return v.f;
}

__device__ static inline float wave_sum(float v) {
  v += __shfl_xor(v, 1);  v += __shfl_xor(v, 2);  v += __shfl_xor(v, 4);
  v += __shfl_xor(v, 8);  v += __shfl_xor(v, 16); v += __shfl_xor(v, 32);
  return v;
}

#define SBAR __builtin_amdgcn_sched_barrier(0)

// ---------------- small utility kernels ----------------

// zero scalars+cells, build transposed trig tables ctT/stT[16][1024]
__global__ __launch_bounds__(256) void k_init_trig(const float* __restrict__ re,
    float* __restrict__ ctT, float* __restrict__ stT, float* __restrict__ sc) {
  int i = blockIdx.x * 256 + threadIdx.x;   // 16384 threads
  if (i < 1040) sc[i] = 0.0f;
  int s = i >> 4, r = i & 15;
  float f = re[s * 32 + r];
  ctT[r * 1024 + s] = cosf(f);
  stT[r * 1024 + s] = sinf(f);
}

__global__ __launch_bounds__(256) void k_wnorm(const float* __restrict__ W,
                                               unsigned short* __restrict__ E, int rows) {
  int row = blockIdx.x * 4 + (threadIdx.x >> 6);
  int l = threadIdx.x & 63;
  if (row >= rows) return;
  const float* wr = W + (size_t)row * 1024;
  float4 v[4];
  float s = 0.f;
  for (int i = 0; i < 4; ++i) {
    v[i] = *(const float4*)(wr + i * 256 + l * 4);
    s += v[i].x * v[i].x + v[i].y * v[i].y + v[i].z * v[i].z + v[i].w * v[i].w;
  }
  s = wave_sum(s);
  float inv = 1.0f / (0.0032f + sqrtf(s));
  unsigned short* er = E + (size_t)row * 1024;
  for (int i = 0; i < 4; ++i) {
    ushort4 o = make_ushort4(f2bf(v[i].x * inv), f2bf(v[i].y * inv),
                             f2bf(v[i].z * inv), f2bf(v[i].w * inv));
    *(ushort4*)(er + i * 256 + l * 4) = o;
  }
}

// build x_ext bf16 [4352][1024] AND accumulate sum of row L2 norms into spread cells
__global__ __launch_bounds__(256) void k_xext(const float* __restrict__ x,
    const float* __restrict__ sink, unsigned short* __restrict__ Xe,
    float* __restrict__ sc) {
  __shared__ float red[4];
  const int row = blockIdx.x;
  const int tid = threadIdx.x, w = tid >> 6, l = tid & 63;
  const int c4 = tid * 4;
  float4 v = make_float4(0.f, 0.f, 0.f, 0.f);
  if (row < 4100) {
    int b = row / 1025, s = row - b * 1025;
    const float* src = (s < 1024) ? (x + ((size_t)(b * 1024 + s)) * 1024 + c4) : (sink + c4);
    v = *(const float4*)src;
  }
  *(ushort4*)(Xe + (size_t)row * 1024 + c4) =
      make_ushort4(f2bf(v.x), f2bf(v.y), f2bf(v.z), f2bf(v.w));
  float ss = v.x * v.x + v.y * v.y + v.z * v.z + v.w * v.w;
  ss = wave_sum(ss);
  if (l == 0) red[w] = ss;
  __syncthreads();
  if (tid == 0 && row < 4100)
    atomicAdd(sc + 16 + (row & 63) * 16, sqrtf(red[0] + red[1] + red[2] + red[3]));
}

// sum of row L2 norms of Hb (bf16 [4096][1024]) -> sc[1]
__global__ __launch_bounds__(256) void k_rownormB(const unsigned short* __restrict__ Hb,
                                                  float* __restrict__ acc) {
  __shared__ float red[4];
  const int w = threadIdx.x >> 6, l = threadIdx.x & 63;
  float local = 0.f;
  for (int row = blockIdx.x * 4 + w; row < 4096; row += gridDim.x * 4) {
    const unsigned short* hr = Hb + (size_t)row * 1024;
    float s = 0.f;
    for (int i = 0; i < 2; ++i) {
      short8 v = *(const short8*)(hr + i * 512 + l * 8);
      #pragma unroll
      for (int k = 0; k < 8; ++k) { float f = bf2f((unsigned short)v[k]); s += f * f; }
    }
    s = wave_sum(s);
    local += sqrtf(s);
  }
  if (l == 0) red[w] = local;
  __syncthreads();
  if (threadIdx.x == 0)
    atomicAdd(acc, red[0] + red[1] + red[2] + red[3]);
}

// ---------------- GEMM 128x128 (2-phase) with ratio epilogue: out = (A*B^T) * ratio ----
__global__ __launch_bounds__(256) void k_gemm(const unsigned short* __restrict__ A,
                                              const unsigned short* __restrict__ B,
                                              float* __restrict__ C, int M, int N, int K,
                                              const float* __restrict__ sc) {
  __shared__ __align__(16) short Al[128 * 64];
  __shared__ __align__(16) short Bl[128 * 64];
  const int t = threadIdx.x, l = t & 63, w = t >> 6;
  const int r = l & 15, g = l >> 4;
  const int wm = w >> 1, wn = w & 1;
  const size_t tm = (size_t)blockIdx.y * 128, tn = (size_t)blockIdx.x * 128;
  f32x4 acc[4][4] = {};
  for (int kt = 0; kt < K; kt += 64) {
    __syncthreads();
    for (int i = 0; i < 4; ++i) {
      int c = i * 256 + t;
      int row = c >> 3, k8 = (c & 7) * 8;
      async16(A + (tm + row) * K + kt + k8, Al + (i * 256 + w * 64) * 8);
    }
    for (int i = 0; i < 4; ++i) {
      int c = i * 256 + t;
      int row = c >> 3, k8 = (c & 7) * 8;
      async16(B + (tn + row) * K + kt + k8, Bl + (i * 256 + w * 64) * 8);
    }
    __syncthreads();
    for (int ks = 0; ks < 2; ++ks) {
      short8 af[4], bfr[4];
      for (int mi = 0; mi < 4; ++mi)
        af[mi] = *(const short8*)(Al + (wm * 64 + mi * 16 + r) * 64 + ks * 32 + g * 8);
      for (int ni = 0; ni < 4; ++ni)
        bfr[ni] = *(const short8*)(Bl + (wn * 64 + ni * 16 + r) * 64 + ks * 32 + g * 8);
      for (int mi = 0; mi < 4; ++mi)
        for (int ni = 0; ni < 4; ++ni)
          acc[mi][ni] = __builtin_amdgcn_mfma_f32_16x16x32_bf16(af[mi], bfr[ni], acc[mi][ni], 0, 0, 0);
    }
  }
  // ratio = (mean x_ext row norm) / (mean h row norm)
  float num = 0.f;
  #pragma unroll
  for (int i = 0; i < 64; ++i) num += sc[16 + i * 16];
  const float ratio = (num * (1.0f / 4100.0f)) * (4096.0f / sc[1]);
  for (int mi = 0; mi < 4; ++mi)
    for (int ni = 0; ni < 4; ++ni)
      for (int j = 0; j < 4; ++j) {
        size_t row = tm + wm * 64 + mi * 16 + g * 4 + j;
        size_t col = tn + wn * 64 + ni * 16 + r;
        C[row * (size_t)N + col] = acc[mi][ni][j] * ratio;
      }
}

// ---------------- fused QKV GEMM 256x256 + RoPE + head-normalize + V-transpose ----------
// Single barrier per K-tile; intra-tile MFMA/ds_read pipelining via compiler-counted lgkmcnt.
__global__ __launch_bounds__(512) void k_gemm256qkv(const unsigned short* __restrict__ A,
    const unsigned short* __restrict__ B,
    unsigned short* __restrict__ Qh, unsigned short* __restrict__ Kh,
    unsigned short* __restrict__ Vt,
    const float* __restrict__ ctT, const float* __restrict__ stT) {
  const int K = 1024, ntn = 12;
  __shared__ __align__(16) short SMEM[65536];   // 128 KiB
  const int t = threadIdx.x, l = t & 63;
  const int w = t >> 6, r = l & 15, g = l >> 4;
  const int wm = w >> 2, wn = w & 3;
  const int nwg = gridDim.x;
  const int q = nwg >> 3, rr = nwg & 7;
  const int xcd = blockIdx.x & 7, loc = blockIdx.x >> 3;
  const int wgid = (xcd < rr ? xcd * (q + 1) : rr * (q + 1) + (xcd - rr) * q) + loc;
  const int tm = wgid / ntn, tn = wgid % ntn;
  const size_t am0 = (size_t)tm * 256, bn0 = (size_t)tn * 256;
  const int NT = K >> 6;
  const int srow = t >> 3, sch = t & 7;

  auto stA = [&](int buf, int half, int kt) {
    const unsigned short* src = A + (am0 + half * 128) * (size_t)K + kt * 64;
    short* dst = SMEM + buf * 16384 + half * 8192;
    async16(src + (size_t)srow * K + ((sch ^ (srow & 7)) << 3), dst + t * 8);
    async16(src + (size_t)(srow + 64) * K + ((sch ^ (srow & 7)) << 3), dst + (512 + t) * 8);
  };
  auto stB = [&](int buf, int half, int kt) {
    const unsigned short* src = B + (bn0 + half * 128) * (size_t)K + kt * 64;
    short* dst = SMEM + 32768 + buf * 16384 + half * 8192;
    async16(src + (size_t)srow * K + ((sch ^ (srow & 7)) << 3), dst + t * 8);
    async16(src + (size_t)(srow + 64) * K + ((sch ^ (srow & 7)) << 3), dst + (512 + t) * 8);
  };

  f32x4 acc[8][4] = {};
  short8 aL[4][2], aH[4][2], bL[2][2], bH[2][2];
  const int arow_base = wm * 128 + r;
  const int brow_base = wn * 64 + r;

  // prologue: stage tile 0 into buf 0
  stA(0, 0, 0); stA(0, 1, 0); stB(0, 0, 0); stB(0, 1, 0);
  asm volatile("s_waitcnt vmcnt(0)" ::: "memory"); SBAR;
  __builtin_amdgcn_s_barrier();

  for (int tt = 0; tt < NT; ++tt) {
    const int buf = tt & 1;
    const short* Asb = SMEM + buf * 16384;
    const short* Bsb = SMEM + 32768 + buf * 16384;
    // stage t+1 into the other buffer (safe: all reads of it finished last tile)
    if (tt + 1 < NT) {
      stA(buf ^ 1, 0, tt + 1); stA(buf ^ 1, 1, tt + 1);
      stB(buf ^ 1, 0, tt + 1); stB(buf ^ 1, 1, tt + 1);
    }
    SBAR;
    // G1 reads: aL (8), bL (4)
    #pragma unroll
    for (int mi = 0; mi < 4; ++mi)
      #pragma unroll
      for (int ks = 0; ks < 2; ++ks) {
        const int arow = arow_base + mi * 16;
        aL[mi][ks] = *(const short8*)(Asb + arow * 64 + (((ks * 4 + g) ^ (arow & 7)) << 3));
      }
    #pragma unroll
    for (int ni = 0; ni < 2; ++ni)
      #pragma unroll
      for (int ks = 0; ks < 2; ++ks) {
        const int brow = brow_base + ni * 16;
        bL[ni][ks] = *(const short8*)(Bsb + brow * 64 + (((ks * 4 + g) ^ (brow & 7)) << 3));
      }
    SBAR;
    // G2 reads: bH (4) — in flight during MFMA G1
    #pragma unroll
    for (int ni = 0; ni < 2; ++ni)
      #pragma unroll
      for (int ks = 0; ks < 2; ++ks) {
        const int brow = brow_base + (ni + 2) * 16;
        bH[ni][ks] = *(const short8*)(Bsb + brow * 64 + (((ks * 4 + g) ^ (brow & 7)) << 3));
      }
    SBAR;
    // MFMA G1: aL x bL
    __builtin_amdgcn_s_setprio(1);
    #pragma unroll
    for (int mi = 0; mi < 4; ++mi)
      #pragma unroll
      for (int ni = 0; ni < 2; ++ni)
        #pragma unroll
        for (int ks = 0; ks < 2; ++ks)
          acc[mi][ni] = __builtin_amdgcn_mfma_f32_16x16x32_bf16(aL[mi][ks], bL[ni][ks], acc[mi][ni], 0, 0, 0);
    __builtin_amdgcn_s_setprio(0);
    SBAR;
    // G3 reads: aH (8) — in flight during MFMA G2
    #pragma unroll
    for (int mi = 0; mi < 4; ++mi)
      #pragma unroll
      for (int ks = 0; ks < 2; ++ks) {
        const int arow = arow_base + (mi + 4) * 16;
        aH[mi][ks] = *(const short8*)(Asb + arow * 64 + (((ks * 4 + g) ^ (arow & 7)) << 3));
      }
    SBAR;
    // MFMA G2: aL x bH
    __builtin_amdgcn_s_setprio(1);
    #pragma unroll
    for (int mi = 0; mi < 4; ++mi)
      #pragma unroll
      for (int ni = 0; ni < 2; ++ni)
        #pragma unroll
        for (int ks = 0; ks < 2; ++ks)
          acc[mi][ni + 2] = __builtin_amdgcn_mfma_f32_16x16x32_bf16(aL[mi][ks], bH[ni][ks], acc[mi][ni + 2], 0, 0, 0);
    __builtin_amdgcn_s_setprio(0);
    SBAR;
    // MFMA G3+G4: aH x bH, aH x bL
    __builtin_amdgcn_s_setprio(1);
    #pragma unroll
    for (int mi = 0; mi < 4; ++mi)
      #pragma unroll
      for (int ni = 0; ni < 2; ++ni)
        #pragma unroll
        for (int ks = 0; ks < 2; ++ks)
          acc[mi + 4][ni + 2] = __builtin_amdgcn_mfma_f32_16x16x32_bf16(aH[mi][ks], bH[ni][ks], acc[mi + 4][ni + 2], 0, 0, 0);
    #pragma unroll
    for (int mi = 0; mi < 4; ++mi)
      #pragma unroll
      for (int ni = 0; ni < 2; ++ni)
        #pragma unroll
        for (int ks = 0; ks < 2; ++ks)
          acc[mi + 4][ni] = __builtin_amdgcn_mfma_f32_16x16x32_bf16(aH[mi][ks], bL[ni][ks], acc[mi + 4][ni], 0, 0, 0);
    __builtin_amdgcn_s_setprio(0);
    SBAR;
    // end of tile: next tile's staging resident; all waves' reads of this buf done
    asm volatile("s_waitcnt vmcnt(0)" ::: "memory"); SBAR;
    __builtin_amdgcn_s_barrier();
  }

  __syncthreads();   // drain before SMEM reuse

  // ---- fused epilogue ----
  const int head_global = tn * 4 + wn;   // block-uniform sel
  const int sel = head_global >> 4;      // 0=q, 1=k, 2=v
  const int h = head_global & 15;
  const int row0 = (int)am0 + wm * 128;

  if (sel < 2) {
    unsigned short* dst = (sel == 0) ? Qh : Kh;
    #pragma unroll
    for (int mi = 0; mi < 8; ++mi) {
      const int rowb = row0 + mi * 16 + g * 4;
      const int b = rowb / 1025;
      const int s0 = rowb - b * 1025;
      float cs[4], sn[4];
      if (s0 + 3 < 1024) {
        float4 c4 = *(const float4*)(ctT + r * 1024 + s0);
        float4 s4 = *(const float4*)(stT + r * 1024 + s0);
        cs[0] = c4.x; cs[1] = c4.y; cs[2] = c4.z; cs[3] = c4.w;
        sn[0] = s4.x; sn[1] = s4.y; sn[2] = s4.z; sn[3] = s4.w;
      } else {
        #pragma unroll
        for (int j = 0; j < 4; ++j) {
          const int rj = rowb + j;
          const int bj = rj / 1025, sj = rj - bj * 1025;
          cs[j] = (sj < 1024) ? ctT[r * 1024 + sj] : 1.f;
          sn[j] = (sj < 1024) ? stT[r * 1024 + sj] : 0.f;
        }
      }
      #pragma unroll
      for (int j = 0; j < 4; ++j) {
        const int row = rowb + j;
        const int b2 = row / 1025, s = row - b2 * 1025;
        const float a0 = acc[mi][0][j], a1 = acc[mi][1][j];
        const float a2 = acc[mi][2][j], a3 = acc[mi][3][j];
        const float r0 = a0 * cs[j] - a1 * sn[j];
        const float r1 = a1 * cs[j] + a0 * sn[j];
        float nrm = r0 * r0 + r1 * r1 + a2 * a2 + a3 * a3;
        nrm += __shfl_xor(nrm, 1); nrm += __shfl_xor(nrm, 2);
        nrm += __shfl_xor(nrm, 4); nrm += __shfl_xor(nrm, 8);
        const float inv = rsqrtf(nrm);
        if (row < 4100) {
          const size_t base = ((size_t)(b2 * 16 + h) * 1088 + s) * 64 + r;
          dst[base]      = f2bf(r0 * inv);
          dst[base + 16] = f2bf(r1 * inv);
          dst[base + 32] = f2bf(a2 * inv);
          dst[base + 48] = f2bf(a3 * inv);
        }
      }
    }
  } else {
    // V: per-wave LDS transpose, packed b64 writes, coalesced Vt writes
    short* vs = SMEM + w * 8192;   // 16 KB per wave
    #pragma unroll
    for (int mi = 0; mi < 8; ++mi) {
      const int s0 = mi * 16 + g * 4;
      #pragma unroll
      for (int ni = 0; ni < 4; ++ni) {
        const int d = ni * 16 + r;
        ushort4 pk = make_ushort4(f2bf(acc[mi][ni][0]), f2bf(acc[mi][ni][1]),
                                  f2bf(acc[mi][ni][2]), f2bf(acc[mi][ni][3]));
        *(ushort4*)(vs + d * 128 + (s0 ^ ((d & 15) << 3))) = pk;
      }
    }
    asm volatile("s_waitcnt lgkmcnt(0)" ::: "memory"); SBAR;
    #pragma unroll
    for (int ii = 0; ii < 16; ++ii) {
      const int d = ii * 4 + g;
      const int s0 = r * 8;
      short8 vv = *(const short8*)(vs + d * 128 + (s0 ^ ((d & 15) << 3)));
      const int grow = row0 + s0;
      const int b0 = grow / 1025, b7 = (grow + 7) / 1025;
      if (b0 == b7 && grow + 7 < 4100) {
        const int s = grow - b0 * 1025;
        *(short8*)(Vt + ((size_t)(b0 * 16 + h) * 64 + d) * 1088 + s) = vv;
      } else {
        for (int k2 = 0; k2 < 8; ++k2) {
          const int gr = grow + k2;
          if (gr >= 4100) break;
          const int bb = gr / 1025, ss = gr - bb * 1025;
          Vt[((size_t)(bb * 16 + h) * 64 + d) * 1088 + ss] = (unsigned short)vv[k2];
        }
      }
    }
  }
}

// ---------------- attention: causal + sink, balanced strip pairs, swizzled LDS ----------------
__global__ __launch_bounds__(128) void k_attn(const unsigned short* __restrict__ Qh,
    const unsigned short* __restrict__ Kh, const unsigned short* __restrict__ Vt,
    unsigned short* __restrict__ Hb) {
  __shared__ __align__(16) short Kl[2][64 * 64];
  __shared__ __align__(16) short Vl[2][64 * 64];
  __shared__ __align__(16) short Pl[2 * 16 * 64];
  const int wid = blockIdx.x;
  const int xcd = wid & 7, jj = wid >> 3;
  const int bh = xcd + 8 * (jj >> 4), pp = jj & 15;
  const int b = bh >> 4, hh = bh & 15;
  const int t = threadIdx.x, l = t & 63, w = t >> 6;
  const int r = l & 15, g = l >> 4;

  auto stage = [&](int buf, int kt) {
    for (int i = 0; i < 4; ++i) {
      int c = i * 128 + t;
      int row = c >> 3, ch = c & 7;
      int sch = ch ^ (row & 7);
      async16(Kh + ((size_t)bh * 1088 + kt * 64 + row) * 64 + sch * 8,
              Kl[buf] + (i * 128 + w * 64) * 8);
      async16(Vt + ((size_t)bh * 64 + row) * 1088 + kt * 64 + sch * 8,
              Vl[buf] + (i * 128 + w * 64) * 8);
    }
  };

  for (int sidx = 0; sidx < 2; ++sidx) {
    const int strip = sidx == 0 ? pp : 31 - pp;
    const int qrow0 = strip * 32 + w * 16;
    short8 qf[2];
    for (int ks = 0; ks < 2; ++ks)
      qf[ks] = *(const short8*)(Qh + ((size_t)bh * 1088 + qrow0 + r) * 64 + ks * 32 + g * 8);
    const int nt = strip / 2 + 2;
    f32x4 oacc[4] = {};
    float lsum[4] = {0.f, 0.f, 0.f, 0.f};
    stage(0, 0);
    __syncthreads();
    int cur = 0;
    for (int i = 0; i < nt; ++i) {
      const int kt = (i < nt - 1) ? i : 16;
      if (i + 1 < nt) stage(cur ^ 1, (i + 1 < nt - 1) ? (i + 1) : 16);
      for (int nc = 0; nc < 4; ++nc) {
        f32x4 sc = {};
        for (int ks = 0; ks < 2; ++ks) {
          const int row = nc * 16 + r;
          const short8 kf = *(const short8*)(Kl[cur] + row * 64 + (((ks * 4 + g) ^ (row & 7)) << 3));
          sc = __builtin_amdgcn_mfma_f32_16x16x32_bf16(qf[ks], kf, sc, 0, 0, 0);
        }
        const int col = kt * 64 + nc * 16 + r;
        for (int j = 0; j < 4; ++j) {
          const int qrow = qrow0 + g * 4 + j;
          const bool valid = (col <= qrow) || (col == 1024);
          float p = valid ? __expf(sc[j]) : 0.0f;
          unsigned short pb = f2bf(p);
          lsum[j] += bf2f(pb);
          const int prow = w * 16 + g * 4 + j;
          const int bir = (nc * 16 + r) * 2;
          char* pd = (char*)Pl + prow * 128 + ((((unsigned)bir >> 4) ^ (prow & 7)) << 4) + (bir & 15);
          *(short*)pd = (short)pb;
        }
      }
      for (int ks = 0; ks < 2; ++ks) {
        const int prow = w * 16 + r;
        const short8 pf = *(const short8*)((char*)Pl + prow * 128 + (((ks * 4 + g) ^ (r & 7)) << 4));
        for (int nd = 0; nd < 4; ++nd) {
          const int vrow = nd * 16 + r;
          const short8 vf = *(const short8*)(Vl[cur] + vrow * 64 + (((ks * 4 + g) ^ (vrow & 7)) << 3));
          oacc[nd] = __builtin_amdgcn_mfma_f32_16x16x32_bf16(pf, vf, oacc[nd], 0, 0, 0);
        }
      }
      __syncthreads();
      cur ^= 1;
    }
    float inv[4];
    for (int j = 0; j < 4; ++j) {
      float v = lsum[j];
      v += __shfl_xor(v, 1); v += __shfl_xor(v, 2);
      v += __shfl_xor(v, 4); v += __shfl_xor(v, 8);
      inv[j] = 1.0f / v;
    }
    for (int nd = 0; nd < 4; ++nd)
      for (int j = 0; j < 4; ++j) {
        const int srow = qrow0 + g * 4 + j;
        Hb[((size_t)(b * 1024 + srow)) * 1024 + hh * 64 + nd * 16 + r] = f2bf(oacc[nd][j] * inv[j]);
      }
  }
}

// ---------------- launcher ----------------
extern "C" void kernel_launch(void* const* d_in, const int* in_sizes, int n_in,
                              void* d_out, int out_size, void* d_ws, size_t ws_size,
                              hipStream_t stream) {
  const float* x     = (const float*)d_in[0];
  const float* re    = (const float*)d_in[1];
  const float* w_qkv = (const float*)d_in[3];
  const float* w_out = (const float*)d_in[4];
  const float* sink  = (const float*)d_in[5];
  char* ws = (char*)d_ws;

  unsigned short* Wq  = (unsigned short*)(ws + 0);          // 3072*1024 bf16
  unsigned short* Wo  = (unsigned short*)(ws + 6291456);    // 1024*1024 bf16
  unsigned short* Xe  = (unsigned short*)(ws + 8388608);    // 4352*1024 bf16
  unsigned short* Hb  = (unsigned short*)(ws + 17301504);   // 4096*1024 bf16
  unsigned short* Qh  = (unsigned short*)(ws + 25690112);   // 64*1088*64 bf16
  unsigned short* Kh  = (unsigned short*)(ws + 34603008);   // 64*1088*64 bf16
  unsigned short* Vt  = (unsigned short*)(ws + 43515904);   // 64*64*1088 bf16
  float*          ctT = (float*)(ws + 52428800);            // 16*1024 f32
  float*          stT = (float*)(ws + 52494336);            // 16*1024 f32
  float*          sc  = (float*)(ws + 52559872);            // scalars + 64 spread cells
  float*          out = (float*)d_out;

  k_init_trig<<<64, 256, 0, stream>>>(re, ctT, stT, sc);
  k_wnorm<<<768, 256, 0, stream>>>(w_qkv, Wq, 3072);
  k_wnorm<<<256, 256, 0, stream>>>(w_out, Wo, 1024);
  k_xext<<<4352, 256, 0, stream>>>(x, sink, Xe, sc);
  k_gemm256qkv<<<17 * 12, 512, 0, stream>>>(Xe, Wq, Qh, Kh, Vt, ctT, stT);
  k_attn<<<1024, 128, 0, stream>>>(Qh, Kh, Vt, Hb);
  k_rownormB<<<256, 256, 0, stream>>>(Hb, sc + 1);
  k_gemm<<<dim3(8, 32), 256, 0, stream>>>(Hb, Wo, out, 4096, 1024, 1024, sc);
}

// Round 8
// 122.680 us; speedup vs baseline: 2.4972x; 1.1379x over previous
//
#include <hip/hip_runtime.h>
#include <hip/hip_bf16.h>
#include <cstdint>

typedef __attribute__((ext_vector_type(8))) short short8;
typedef __attribute__((ext_vector_type(4))) float f32x4;

typedef const unsigned int __attribute__((address_space(1)))* gas_ptr;
typedef unsigned int __attribute__((address_space(3)))* las_ptr;

__device__ static inline void async16(const void* g, void* l) {
  __builtin_amdgcn_global_load_lds((gas_ptr)g, (las_ptr)l, 16, 0, 0);
}

__device__ static inline unsigned short f2bf(float f) {
  union { float f; uint32_t u; } v; v.f = f;
  uint32_t u = v.u;
  uint32_t r = (u + 0x7FFFu + ((u >> 16) & 1u)) >> 16;
  return (unsigned short)r;
}
__device__ static inline float bf2f(unsigned short s) {
  union { uint32_t u; float f; } v; v.u = ((uint32_t)s) << 16; return v.f;
}

__device__ static inline float wave_sum(float v) {
  v += __shfl_xor(v, 1);  v += __shfl_xor(v, 2);  v += __shfl_xor(v, 4);
  v += __shfl_xor(v, 8);  v += __shfl_xor(v, 16); v += __shfl_xor(v, 32);
  return v;
}

#define SBAR __builtin_amdgcn_sched_barrier(0)

// ---------------- small utility kernels ----------------

// zero scalars+cells, build transposed trig tables ctT/stT[16][1024]
__global__ __launch_bounds__(256) void k_init_trig(const float* __restrict__ re,
    float* __restrict__ ctT, float* __restrict__ stT, float* __restrict__ sc) {
  int i = blockIdx.x * 256 + threadIdx.x;   // 16384 threads
  if (i < 1040) sc[i] = 0.0f;
  int s = i >> 4, r = i & 15;
  float f = re[s * 32 + r];
  ctT[r * 1024 + s] = cosf(f);
  stT[r * 1024 + s] = sinf(f);
}

__global__ __launch_bounds__(256) void k_wnorm(const float* __restrict__ W,
                                               unsigned short* __restrict__ E, int rows) {
  int row = blockIdx.x * 4 + (threadIdx.x >> 6);
  int l = threadIdx.x & 63;
  if (row >= rows) return;
  const float* wr = W + (size_t)row * 1024;
  float4 v[4];
  float s = 0.f;
  for (int i = 0; i < 4; ++i) {
    v[i] = *(const float4*)(wr + i * 256 + l * 4);
    s += v[i].x * v[i].x + v[i].y * v[i].y + v[i].z * v[i].z + v[i].w * v[i].w;
  }
  s = wave_sum(s);
  float inv = 1.0f / (0.0032f + sqrtf(s));
  unsigned short* er = E + (size_t)row * 1024;
  for (int i = 0; i < 4; ++i) {
    ushort4 o = make_ushort4(f2bf(v[i].x * inv), f2bf(v[i].y * inv),
                             f2bf(v[i].z * inv), f2bf(v[i].w * inv));
    *(ushort4*)(er + i * 256 + l * 4) = o;
  }
}

// build x_ext bf16 [4352][1024] AND accumulate sum of row L2 norms into spread cells
__global__ __launch_bounds__(256) void k_xext(const float* __restrict__ x,
    const float* __restrict__ sink, unsigned short* __restrict__ Xe,
    float* __restrict__ sc) {
  __shared__ float red[4];
  const int row = blockIdx.x;
  const int tid = threadIdx.x, w = tid >> 6, l = tid & 63;
  const int c4 = tid * 4;
  float4 v = make_float4(0.f, 0.f, 0.f, 0.f);
  if (row < 4100) {
    int b = row / 1025, s = row - b * 1025;
    const float* src = (s < 1024) ? (x + ((size_t)(b * 1024 + s)) * 1024 + c4) : (sink + c4);
    v = *(const float4*)src;
  }
  *(ushort4*)(Xe + (size_t)row * 1024 + c4) =
      make_ushort4(f2bf(v.x), f2bf(v.y), f2bf(v.z), f2bf(v.w));
  float ss = v.x * v.x + v.y * v.y + v.z * v.z + v.w * v.w;
  ss = wave_sum(ss);
  if (l == 0) red[w] = ss;
  __syncthreads();
  if (tid == 0 && row < 4100)
    atomicAdd(sc + 16 + (row & 63) * 16, sqrtf(red[0] + red[1] + red[2] + red[3]));
}

// sum of row L2 norms of Hb (bf16 [4096][1024]) -> sc[1]
__global__ __launch_bounds__(256) void k_rownormB(const unsigned short* __restrict__ Hb,
                                                  float* __restrict__ acc) {
  __shared__ float red[4];
  const int w = threadIdx.x >> 6, l = threadIdx.x & 63;
  float local = 0.f;
  for (int row = blockIdx.x * 4 + w; row < 4096; row += gridDim.x * 4) {
    const unsigned short* hr = Hb + (size_t)row * 1024;
    float s = 0.f;
    for (int i = 0; i < 2; ++i) {
      short8 v = *(const short8*)(hr + i * 512 + l * 8);
      #pragma unroll
      for (int k = 0; k < 8; ++k) { float f = bf2f((unsigned short)v[k]); s += f * f; }
    }
    s = wave_sum(s);
    local += sqrtf(s);
  }
  if (l == 0) red[w] = local;
  __syncthreads();
  if (threadIdx.x == 0)
    atomicAdd(acc, red[0] + red[1] + red[2] + red[3]);
}

// ---------------- unified 128x128 GEMM (m97 structure, swizzled, XCD-remapped) ----------
// C[M][N] = A[M][K] * B[N][K]^T.
// EPI=0: write C f32 scaled by ratio (from sc). EPI=1: fused QKV epilogue (RoPE+norm+Vt).
template<int EPI>
__global__ __launch_bounds__(256, 3) void k_gemm128(
    const unsigned short* __restrict__ A, const unsigned short* __restrict__ B,
    float* __restrict__ C, int N, int K, int ntn,
    unsigned short* __restrict__ Qh, unsigned short* __restrict__ Kh,
    unsigned short* __restrict__ Vt,
    const float* __restrict__ ctT, const float* __restrict__ stT,
    const float* __restrict__ sc) {
  __shared__ __align__(16) short SMEM[16384];   // 32 KiB: Al | Bl (reused for V-transpose)
  short* Al = SMEM;
  short* Bl = SMEM + 8192;
  const int t = threadIdx.x, l = t & 63, w = t >> 6;
  const int r = l & 15, g = l >> 4;
  const int wm = w >> 1, wn = w & 1;
  // bijective XCD swizzle (m204)
  const int nwg = gridDim.x;
  const int q = nwg >> 3, rr = nwg & 7;
  const int xcd = blockIdx.x & 7, loc = blockIdx.x >> 3;
  const int wgid = (xcd < rr ? xcd * (q + 1) : rr * (q + 1) + (xcd - rr) * q) + loc;
  const int tm = wgid / ntn, tn = wgid % ntn;
  const size_t am0 = (size_t)tm * 128, bn0 = (size_t)tn * 128;

  f32x4 acc[4][4] = {};
  for (int kt = 0; kt < K; kt += 64) {
    __syncthreads();
    // stage: LDS[row][ch] = global[row][ch ^ (row&7)]  (linear dest, pre-swizzled src)
    #pragma unroll
    for (int i = 0; i < 4; ++i) {
      int c = i * 256 + t;
      int row = c >> 3, sch = (c & 7) ^ (row & 7);
      async16(A + (am0 + row) * (size_t)K + kt + sch * 8, Al + (i * 256 + w * 64) * 8);
    }
    #pragma unroll
    for (int i = 0; i < 4; ++i) {
      int c = i * 256 + t;
      int row = c >> 3, sch = (c & 7) ^ (row & 7);
      async16(B + (bn0 + row) * (size_t)K + kt + sch * 8, Bl + (i * 256 + w * 64) * 8);
    }
    __syncthreads();
    #pragma unroll
    for (int ks = 0; ks < 2; ++ks) {
      short8 af[4], bfr[4];
      #pragma unroll
      for (int mi = 0; mi < 4; ++mi) {
        const int arow = wm * 64 + mi * 16 + r;
        af[mi] = *(const short8*)(Al + arow * 64 + (((ks * 4 + g) ^ (arow & 7)) << 3));
      }
      #pragma unroll
      for (int ni = 0; ni < 4; ++ni) {
        const int brow = wn * 64 + ni * 16 + r;
        bfr[ni] = *(const short8*)(Bl + brow * 64 + (((ks * 4 + g) ^ (brow & 7)) << 3));
      }
      #pragma unroll
      for (int mi = 0; mi < 4; ++mi)
        #pragma unroll
        for (int ni = 0; ni < 4; ++ni)
          acc[mi][ni] = __builtin_amdgcn_mfma_f32_16x16x32_bf16(af[mi], bfr[ni], acc[mi][ni], 0, 0, 0);
    }
  }

  if constexpr (EPI == 0) {
    // ratio = (mean x_ext row norm) / (mean h row norm)
    float num = 0.f;
    #pragma unroll
    for (int i = 0; i < 64; ++i) num += sc[16 + i * 16];
    const float ratio = (num * (1.0f / 4100.0f)) * (4096.0f / sc[1]);
    #pragma unroll
    for (int mi = 0; mi < 4; ++mi)
      #pragma unroll
      for (int ni = 0; ni < 4; ++ni)
        #pragma unroll
        for (int j = 0; j < 4; ++j) {
          size_t row = am0 + wm * 64 + mi * 16 + g * 4 + j;
          size_t col = bn0 + wn * 64 + ni * 16 + r;
          C[row * (size_t)N + col] = acc[mi][ni][j] * ratio;
        }
  } else {
    __syncthreads();   // drain all waves' LDS reads before SMEM reuse
    const int head_global = tn * 2 + wn;   // 0..47, wave-uniform
    const int sel = head_global >> 4;      // 0=q, 1=k, 2=v
    const int h = head_global & 15;
    const int row0 = (int)am0 + wm * 64;

    if (sel < 2) {
      unsigned short* dst = (sel == 0) ? Qh : Kh;
      #pragma unroll
      for (int mi = 0; mi < 4; ++mi) {
        const int rowb = row0 + mi * 16 + g * 4;
        const int b = rowb / 1025;
        const int s0 = rowb - b * 1025;
        float cs[4], sn[4];
        if (s0 + 3 < 1024) {
          float4 c4 = *(const float4*)(ctT + r * 1024 + s0);
          float4 s4 = *(const float4*)(stT + r * 1024 + s0);
          cs[0] = c4.x; cs[1] = c4.y; cs[2] = c4.z; cs[3] = c4.w;
          sn[0] = s4.x; sn[1] = s4.y; sn[2] = s4.z; sn[3] = s4.w;
        } else {
          #pragma unroll
          for (int j = 0; j < 4; ++j) {
            const int rj = rowb + j;
            const int bj = rj / 1025, sj = rj - bj * 1025;
            cs[j] = (sj < 1024) ? ctT[r * 1024 + sj] : 1.f;
            sn[j] = (sj < 1024) ? stT[r * 1024 + sj] : 0.f;
          }
        }
        #pragma unroll
        for (int j = 0; j < 4; ++j) {
          const int row = rowb + j;
          const int b2 = row / 1025, s = row - b2 * 1025;
          const float a0 = acc[mi][0][j], a1 = acc[mi][1][j];
          const float a2 = acc[mi][2][j], a3 = acc[mi][3][j];
          const float r0 = a0 * cs[j] - a1 * sn[j];
          const float r1 = a1 * cs[j] + a0 * sn[j];
          float nrm = r0 * r0 + r1 * r1 + a2 * a2 + a3 * a3;
          nrm += __shfl_xor(nrm, 1); nrm += __shfl_xor(nrm, 2);
          nrm += __shfl_xor(nrm, 4); nrm += __shfl_xor(nrm, 8);
          const float inv = rsqrtf(nrm);
          if (row < 4100) {
            const size_t base = ((size_t)(b2 * 16 + h) * 1088 + s) * 64 + r;
            dst[base]      = f2bf(r0 * inv);
            dst[base + 16] = f2bf(r1 * inv);
            dst[base + 32] = f2bf(a2 * inv);
            dst[base + 48] = f2bf(a3 * inv);
          }
        }
      }
    } else {
      // V: per-wave LDS transpose. vs[d][slot] as ushort4 slots, slot' = slot ^ (d&15).
      short* vs = SMEM + w * 4096;   // 8 KiB per wave: 64 d-rows x 64 shorts
      #pragma unroll
      for (int mi = 0; mi < 4; ++mi) {
        const int slot = mi * 4 + g;       // seq chunk (mi*16+g*4)/4
        #pragma unroll
        for (int ni = 0; ni < 4; ++ni) {
          const int d = ni * 16 + r;
          ushort4 pk = make_ushort4(f2bf(acc[mi][ni][0]), f2bf(acc[mi][ni][1]),
                                    f2bf(acc[mi][ni][2]), f2bf(acc[mi][ni][3]));
          *(ushort4*)(vs + d * 64 + ((slot ^ (d & 15)) << 2)) = pk;
        }
      }
      asm volatile("s_waitcnt lgkmcnt(0)" ::: "memory"); SBAR;
      #pragma unroll
      for (int ii = 0; ii < 16; ++ii) {
        const int d = ii * 4 + g;          // 0..63
        ushort4 vv = *(const ushort4*)(vs + d * 64 + (((r ^ (d & 15)) & 15) << 2));
        const int grow = row0 + r * 4;
        const int b0 = grow / 1025, b3 = (grow + 3) / 1025;
        if (b0 == b3 && grow + 3 < 4100) {
          const int s = grow - b0 * 1025;
          *(ushort4*)(Vt + ((size_t)(b0 * 16 + h) * 64 + d) * 1088 + s) = vv;
        } else {
          unsigned short tmp[4] = {vv.x, vv.y, vv.z, vv.w};
          for (int k2 = 0; k2 < 4; ++k2) {
            const int gr = grow + k2;
            if (gr >= 4100) break;
            const int bb = gr / 1025, ss = gr - bb * 1025;
            Vt[((size_t)(bb * 16 + h) * 64 + d) * 1088 + ss] = tmp[k2];
          }
        }
      }
    }
  }
}

// ---------------- attention: causal + sink, balanced strip pairs, swizzled LDS ----------------
__global__ __launch_bounds__(128) void k_attn(const unsigned short* __restrict__ Qh,
    const unsigned short* __restrict__ Kh, const unsigned short* __restrict__ Vt,
    unsigned short* __restrict__ Hb) {
  __shared__ __align__(16) short Kl[2][64 * 64];
  __shared__ __align__(16) short Vl[2][64 * 64];
  __shared__ __align__(16) short Pl[2 * 16 * 64];
  const int wid = blockIdx.x;
  const int xcd = wid & 7, jj = wid >> 3;
  const int bh = xcd + 8 * (jj >> 4), pp = jj & 15;
  const int b = bh >> 4, hh = bh & 15;
  const int t = threadIdx.x, l = t & 63, w = t >> 6;
  const int r = l & 15, g = l >> 4;

  auto stage = [&](int buf, int kt) {
    for (int i = 0; i < 4; ++i) {
      int c = i * 128 + t;
      int row = c >> 3, ch = c & 7;
      int sch = ch ^ (row & 7);
      async16(Kh + ((size_t)bh * 1088 + kt * 64 + row) * 64 + sch * 8,
              Kl[buf] + (i * 128 + w * 64) * 8);
      async16(Vt + ((size_t)bh * 64 + row) * 1088 + kt * 64 + sch * 8,
              Vl[buf] + (i * 128 + w * 64) * 8);
    }
  };

  for (int sidx = 0; sidx < 2; ++sidx) {
    const int strip = sidx == 0 ? pp : 31 - pp;
    const int qrow0 = strip * 32 + w * 16;
    short8 qf[2];
    for (int ks = 0; ks < 2; ++ks)
      qf[ks] = *(const short8*)(Qh + ((size_t)bh * 1088 + qrow0 + r) * 64 + ks * 32 + g * 8);
    const int nt = strip / 2 + 2;
    f32x4 oacc[4] = {};
    float lsum[4] = {0.f, 0.f, 0.f, 0.f};
    stage(0, 0);
    __syncthreads();
    int cur = 0;
    for (int i = 0; i < nt; ++i) {
      const int kt = (i < nt - 1) ? i : 16;
      if (i + 1 < nt) stage(cur ^ 1, (i + 1 < nt - 1) ? (i + 1) : 16);
      for (int nc = 0; nc < 4; ++nc) {
        f32x4 sc = {};
        for (int ks = 0; ks < 2; ++ks) {
          const int row = nc * 16 + r;
          const short8 kf = *(const short8*)(Kl[cur] + row * 64 + (((ks * 4 + g) ^ (row & 7)) << 3));
          sc = __builtin_amdgcn_mfma_f32_16x16x32_bf16(qf[ks], kf, sc, 0, 0, 0);
        }
        const int col = kt * 64 + nc * 16 + r;
        for (int j = 0; j < 4; ++j) {
          const int qrow = qrow0 + g * 4 + j;
          const bool valid = (col <= qrow) || (col == 1024);
          float p = valid ? __expf(sc[j]) : 0.0f;
          unsigned short pb = f2bf(p);
          lsum[j] += bf2f(pb);
          const int prow = w * 16 + g * 4 + j;
          const int bir = (nc * 16 + r) * 2;
          char* pd = (char*)Pl + prow * 128 + ((((unsigned)bir >> 4) ^ (prow & 7)) << 4) + (bir & 15);
          *(short*)pd = (short)pb;
        }
      }
      for (int ks = 0; ks < 2; ++ks) {
        const int prow = w * 16 + r;
        const short8 pf = *(const short8*)((char*)Pl + prow * 128 + (((ks * 4 + g) ^ (r & 7)) << 4));
        for (int nd = 0; nd < 4; ++nd) {
          const int vrow = nd * 16 + r;
          const short8 vf = *(const short8*)(Vl[cur] + vrow * 64 + (((ks * 4 + g) ^ (vrow & 7)) << 3));
          oacc[nd] = __builtin_amdgcn_mfma_f32_16x16x32_bf16(pf, vf, oacc[nd], 0, 0, 0);
        }
      }
      __syncthreads();
      cur ^= 1;
    }
    float inv[4];
    for (int j = 0; j < 4; ++j) {
      float v = lsum[j];
      v += __shfl_xor(v, 1); v += __shfl_xor(v, 2);
      v += __shfl_xor(v, 4); v += __shfl_xor(v, 8);
      inv[j] = 1.0f / v;
    }
    for (int nd = 0; nd < 4; ++nd)
      for (int j = 0; j < 4; ++j) {
        const int srow = qrow0 + g * 4 + j;
        Hb[((size_t)(b * 1024 + srow)) * 1024 + hh * 64 + nd * 16 + r] = f2bf(oacc[nd][j] * inv[j]);
      }
  }
}

// ---------------- launcher ----------------
extern "C" void kernel_launch(void* const* d_in, const int* in_sizes, int n_in,
                              void* d_out, int out_size, void* d_ws, size_t ws_size,
                              hipStream_t stream) {
  const float* x     = (const float*)d_in[0];
  const float* re    = (const float*)d_in[1];
  const float* w_qkv = (const float*)d_in[3];
  const float* w_out = (const float*)d_in[4];
  const float* sink  = (const float*)d_in[5];
  char* ws = (char*)d_ws;

  unsigned short* Wq  = (unsigned short*)(ws + 0);          // 3072*1024 bf16
  unsigned short* Wo  = (unsigned short*)(ws + 6291456);    // 1024*1024 bf16
  unsigned short* Xe  = (unsigned short*)(ws + 8388608);    // 4352*1024 bf16
  unsigned short* Hb  = (unsigned short*)(ws + 17301504);   // 4096*1024 bf16
  unsigned short* Qh  = (unsigned short*)(ws + 25690112);   // 64*1088*64 bf16
  unsigned short* Kh  = (unsigned short*)(ws + 34603008);   // 64*1088*64 bf16
  unsigned short* Vt  = (unsigned short*)(ws + 43515904);   // 64*64*1088 bf16
  float*          ctT = (float*)(ws + 52428800);            // 16*1024 f32
  float*          stT = (float*)(ws + 52494336);            // 16*1024 f32
  float*          sc  = (float*)(ws + 52559872);            // scalars + 64 spread cells
  float*          out = (float*)d_out;

  k_init_trig<<<64, 256, 0, stream>>>(re, ctT, stT, sc);
  k_wnorm<<<768, 256, 0, stream>>>(w_qkv, Wq, 3072);
  k_wnorm<<<256, 256, 0, stream>>>(w_out, Wo, 1024);
  k_xext<<<4352, 256, 0, stream>>>(x, sink, Xe, sc);
  k_gemm128<1><<<34 * 24, 256, 0, stream>>>(Xe, Wq, nullptr, 3072, 1024, 24,
                                            Qh, Kh, Vt, ctT, stT, sc);
  k_attn<<<1024, 128, 0, stream>>>(Qh, Kh, Vt, Hb);
  k_rownormB<<<256, 256, 0, stream>>>(Hb, sc + 1);
  k_gemm128<0><<<32 * 8, 256, 0, stream>>>(Hb, Wo, out, 1024, 1024, 8,
                                           nullptr, nullptr, nullptr, ctT, stT, sc);
}

// Round 9
// 121.260 us; speedup vs baseline: 2.5264x; 1.0117x over previous
//
#include <hip/hip_runtime.h>
#include <hip/hip_bf16.h>
#include <cstdint>

typedef __attribute__((ext_vector_type(8))) short short8;
typedef __attribute__((ext_vector_type(4))) float f32x4;

typedef const unsigned int __attribute__((address_space(1)))* gas_ptr;
typedef unsigned int __attribute__((address_space(3)))* las_ptr;

__device__ static inline void async16(const void* g, void* l) {
  __builtin_amdgcn_global_load_lds((gas_ptr)g, (las_ptr)l, 16, 0, 0);
}

__device__ static inline unsigned short f2bf(float f) {
  union { float f; uint32_t u; } v; v.f = f;
  uint32_t u = v.u;
  uint32_t r = (u + 0x7FFFu + ((u >> 16) & 1u)) >> 16;
  return (unsigned short)r;
}
__device__ static inline float bf2f(unsigned short s) {
  union { uint32_t u; float f; } v; v.u = ((uint32_t)s) << 16; return v.f;
}

__device__ static inline float wave_sum(float v) {
  v += __shfl_xor(v, 1);  v += __shfl_xor(v, 2);  v += __shfl_xor(v, 4);
  v += __shfl_xor(v, 8);  v += __shfl_xor(v, 16); v += __shfl_xor(v, 32);
  return v;
}

#define SBAR __builtin_amdgcn_sched_barrier(0)

// ---------------- small utility kernels ----------------

// zero scalars+cells, build transposed trig tables ctT/stT[16][1024]
__global__ __launch_bounds__(256) void k_init_trig(const float* __restrict__ re,
    float* __restrict__ ctT, float* __restrict__ stT, float* __restrict__ sc) {
  int i = blockIdx.x * 256 + threadIdx.x;   // 16384 threads
  if (i < 1040) sc[i] = 0.0f;
  int s = i >> 4, r = i & 15;
  float f = re[s * 32 + r];
  ctT[r * 1024 + s] = cosf(f);
  stT[r * 1024 + s] = sinf(f);
}

__global__ __launch_bounds__(256) void k_wnorm(const float* __restrict__ W,
                                               unsigned short* __restrict__ E, int rows) {
  int row = blockIdx.x * 4 + (threadIdx.x >> 6);
  int l = threadIdx.x & 63;
  if (row >= rows) return;
  const float* wr = W + (size_t)row * 1024;
  float4 v[4];
  float s = 0.f;
  for (int i = 0; i < 4; ++i) {
    v[i] = *(const float4*)(wr + i * 256 + l * 4);
    s += v[i].x * v[i].x + v[i].y * v[i].y + v[i].z * v[i].z + v[i].w * v[i].w;
  }
  s = wave_sum(s);
  float inv = 1.0f / (0.0032f + sqrtf(s));
  unsigned short* er = E + (size_t)row * 1024;
  for (int i = 0; i < 4; ++i) {
    ushort4 o = make_ushort4(f2bf(v[i].x * inv), f2bf(v[i].y * inv),
                             f2bf(v[i].z * inv), f2bf(v[i].w * inv));
    *(ushort4*)(er + i * 256 + l * 4) = o;
  }
}

// build x_ext bf16 [4352][1024] AND accumulate sum of row L2 norms into spread cells
__global__ __launch_bounds__(256) void k_xext(const float* __restrict__ x,
    const float* __restrict__ sink, unsigned short* __restrict__ Xe,
    float* __restrict__ sc) {
  __shared__ float red[4];
  const int row = blockIdx.x;
  const int tid = threadIdx.x, w = tid >> 6, l = tid & 63;
  const int c4 = tid * 4;
  float4 v = make_float4(0.f, 0.f, 0.f, 0.f);
  if (row < 4100) {
    int b = row / 1025, s = row - b * 1025;
    const float* src = (s < 1024) ? (x + ((size_t)(b * 1024 + s)) * 1024 + c4) : (sink + c4);
    v = *(const float4*)src;
  }
  *(ushort4*)(Xe + (size_t)row * 1024 + c4) =
      make_ushort4(f2bf(v.x), f2bf(v.y), f2bf(v.z), f2bf(v.w));
  float ss = v.x * v.x + v.y * v.y + v.z * v.z + v.w * v.w;
  ss = wave_sum(ss);
  if (l == 0) red[w] = ss;
  __syncthreads();
  if (tid == 0 && row < 4100)
    atomicAdd(sc + 16 + (row & 63) * 16, sqrtf(red[0] + red[1] + red[2] + red[3]));
}

// sum of row L2 norms of Hb (bf16 [4096][1024]) -> sc[1]
__global__ __launch_bounds__(256) void k_rownormB(const unsigned short* __restrict__ Hb,
                                                  float* __restrict__ acc) {
  __shared__ float red[4];
  const int w = threadIdx.x >> 6, l = threadIdx.x & 63;
  float local = 0.f;
  for (int row = blockIdx.x * 4 + w; row < 4096; row += gridDim.x * 4) {
    const unsigned short* hr = Hb + (size_t)row * 1024;
    float s = 0.f;
    for (int i = 0; i < 2; ++i) {
      short8 v = *(const short8*)(hr + i * 512 + l * 8);
      #pragma unroll
      for (int k = 0; k < 8; ++k) { float f = bf2f((unsigned short)v[k]); s += f * f; }
    }
    s = wave_sum(s);
    local += sqrtf(s);
  }
  if (l == 0) red[w] = local;
  __syncthreads();
  if (threadIdx.x == 0)
    atomicAdd(acc, red[0] + red[1] + red[2] + red[3]);
}

// ---------------- unified 128x128 GEMM: dbuf LDS + counted vmcnt pipeline ----------
// C[M][N] = A[M][K] * B[N][K]^T.
// EPI=0: write C f32 scaled by ratio (from sc). EPI=1: fused QKV epilogue (RoPE+norm+Vt).
template<int EPI>
__global__ __launch_bounds__(256, 2) void k_gemm128(
    const unsigned short* __restrict__ A, const unsigned short* __restrict__ B,
    float* __restrict__ C, int N, int K, int ntn,
    unsigned short* __restrict__ Qh, unsigned short* __restrict__ Kh,
    unsigned short* __restrict__ Vt,
    const float* __restrict__ ctT, const float* __restrict__ stT,
    const float* __restrict__ sc) {
  __shared__ __align__(16) short SMEM[32768];   // 64 KiB: 2 x (Al | Bl)
  const int t = threadIdx.x, l = t & 63, w = t >> 6;
  const int r = l & 15, g = l >> 4;
  const int wm = w >> 1, wn = w & 1;
  // bijective XCD swizzle (m204)
  const int nwg = gridDim.x;
  const int q = nwg >> 3, rr = nwg & 7;
  const int xcd = blockIdx.x & 7, loc = blockIdx.x >> 3;
  const int wgid = (xcd < rr ? xcd * (q + 1) : rr * (q + 1) + (xcd - rr) * q) + loc;
  const int tm = wgid / ntn, tn = wgid % ntn;
  const size_t am0 = (size_t)tm * 128, bn0 = (size_t)tn * 128;
  const int NT = K >> 6;

  // stage: LDS[row][ch] = global[row][ch ^ (row&7)]  (linear dest, pre-swizzled src)
  auto stage = [&](int buf, int kt) {
    short* Al = SMEM + buf * 16384;
    short* Bl = Al + 8192;
    #pragma unroll
    for (int i = 0; i < 4; ++i) {
      int c = i * 256 + t;
      int row = c >> 3, sch = (c & 7) ^ (row & 7);
      async16(A + (am0 + row) * (size_t)K + kt + sch * 8, Al + (i * 256 + w * 64) * 8);
    }
    #pragma unroll
    for (int i = 0; i < 4; ++i) {
      int c = i * 256 + t;
      int row = c >> 3, sch = (c & 7) ^ (row & 7);
      async16(B + (bn0 + row) * (size_t)K + kt + sch * 8, Bl + (i * 256 + w * 64) * 8);
    }
  };

  f32x4 acc[4][4] = {};
  stage(0, 0);
  for (int tt = 0; tt < NT; ++tt) {
    const int buf = tt & 1;
    const short* Al = SMEM + buf * 16384;
    const short* Bl = Al + 8192;
    // issue next tile's stage into the other buffer; wait only for THIS tile's 8 loads
    if (tt + 1 < NT) {
      stage(buf ^ 1, (tt + 1) * 64);
      asm volatile("s_waitcnt vmcnt(8)" ::: "memory");
    } else {
      asm volatile("s_waitcnt vmcnt(0)" ::: "memory");
    }
    SBAR;
    __builtin_amdgcn_s_barrier();   // tile tt resident for all waves
    SBAR;
    #pragma unroll
    for (int ks = 0; ks < 2; ++ks) {
      short8 af[4], bfr[4];
      #pragma unroll
      for (int mi = 0; mi < 4; ++mi) {
        const int arow = wm * 64 + mi * 16 + r;
        af[mi] = *(const short8*)(Al + arow * 64 + (((ks * 4 + g) ^ (arow & 7)) << 3));
      }
      #pragma unroll
      for (int ni = 0; ni < 4; ++ni) {
        const int brow = wn * 64 + ni * 16 + r;
        bfr[ni] = *(const short8*)(Bl + brow * 64 + (((ks * 4 + g) ^ (brow & 7)) << 3));
      }
      #pragma unroll
      for (int mi = 0; mi < 4; ++mi)
        #pragma unroll
        for (int ni = 0; ni < 4; ++ni)
          acc[mi][ni] = __builtin_amdgcn_mfma_f32_16x16x32_bf16(af[mi], bfr[ni], acc[mi][ni], 0, 0, 0);
    }
    SBAR;
    __builtin_amdgcn_s_barrier();   // all waves done reading buf (reads consumed by MFMA)
    SBAR;
  }

  if constexpr (EPI == 0) {
    // ratio = (mean x_ext row norm) / (mean h row norm)
    float num = 0.f;
    #pragma unroll
    for (int i = 0; i < 64; ++i) num += sc[16 + i * 16];
    const float ratio = (num * (1.0f / 4100.0f)) * (4096.0f / sc[1]);
    #pragma unroll
    for (int mi = 0; mi < 4; ++mi)
      #pragma unroll
      for (int ni = 0; ni < 4; ++ni)
        #pragma unroll
        for (int j = 0; j < 4; ++j) {
          size_t row = am0 + wm * 64 + mi * 16 + g * 4 + j;
          size_t col = bn0 + wn * 64 + ni * 16 + r;
          C[row * (size_t)N + col] = acc[mi][ni][j] * ratio;
        }
  } else {
    __syncthreads();   // drain all waves' LDS reads before SMEM reuse
    const int head_global = tn * 2 + wn;   // 0..47, wave-uniform
    const int sel = head_global >> 4;      // 0=q, 1=k, 2=v
    const int h = head_global & 15;
    const int row0 = (int)am0 + wm * 64;

    if (sel < 2) {
      unsigned short* dst = (sel == 0) ? Qh : Kh;
      #pragma unroll
      for (int mi = 0; mi < 4; ++mi) {
        const int rowb = row0 + mi * 16 + g * 4;
        const int b = rowb / 1025;
        const int s0 = rowb - b * 1025;
        float cs[4], sn[4];
        if (s0 + 3 < 1024) {
          float4 c4 = *(const float4*)(ctT + r * 1024 + s0);
          float4 s4 = *(const float4*)(stT + r * 1024 + s0);
          cs[0] = c4.x; cs[1] = c4.y; cs[2] = c4.z; cs[3] = c4.w;
          sn[0] = s4.x; sn[1] = s4.y; sn[2] = s4.z; sn[3] = s4.w;
        } else {
          #pragma unroll
          for (int j = 0; j < 4; ++j) {
            const int rj = rowb + j;
            const int bj = rj / 1025, sj = rj - bj * 1025;
            cs[j] = (sj < 1024) ? ctT[r * 1024 + sj] : 1.f;
            sn[j] = (sj < 1024) ? stT[r * 1024 + sj] : 0.f;
          }
        }
        #pragma unroll
        for (int j = 0; j < 4; ++j) {
          const int row = rowb + j;
          const int b2 = row / 1025, s = row - b2 * 1025;
          const float a0 = acc[mi][0][j], a1 = acc[mi][1][j];
          const float a2 = acc[mi][2][j], a3 = acc[mi][3][j];
          const float r0 = a0 * cs[j] - a1 * sn[j];
          const float r1 = a1 * cs[j] + a0 * sn[j];
          float nrm = r0 * r0 + r1 * r1 + a2 * a2 + a3 * a3;
          nrm += __shfl_xor(nrm, 1); nrm += __shfl_xor(nrm, 2);
          nrm += __shfl_xor(nrm, 4); nrm += __shfl_xor(nrm, 8);
          const float inv = rsqrtf(nrm);
          if (row < 4100) {
            const size_t base = ((size_t)(b2 * 16 + h) * 1088 + s) * 64 + r;
            dst[base]      = f2bf(r0 * inv);
            dst[base + 16] = f2bf(r1 * inv);
            dst[base + 32] = f2bf(a2 * inv);
            dst[base + 48] = f2bf(a3 * inv);
          }
        }
      }
    } else {
      // V: per-wave LDS transpose. vs[d][slot] as ushort4 slots, slot' = slot ^ (d&15).
      short* vs = SMEM + w * 4096;   // 8 KiB per wave: 64 d-rows x 64 shorts
      #pragma unroll
      for (int mi = 0; mi < 4; ++mi) {
        const int slot = mi * 4 + g;       // seq chunk (mi*16+g*4)/4
        #pragma unroll
        for (int ni = 0; ni < 4; ++ni) {
          const int d = ni * 16 + r;
          ushort4 pk = make_ushort4(f2bf(acc[mi][ni][0]), f2bf(acc[mi][ni][1]),
                                    f2bf(acc[mi][ni][2]), f2bf(acc[mi][ni][3]));
          *(ushort4*)(vs + d * 64 + ((slot ^ (d & 15)) << 2)) = pk;
        }
      }
      asm volatile("s_waitcnt lgkmcnt(0)" ::: "memory"); SBAR;
      #pragma unroll
      for (int ii = 0; ii < 16; ++ii) {
        const int d = ii * 4 + g;          // 0..63
        ushort4 vv = *(const ushort4*)(vs + d * 64 + (((r ^ (d & 15)) & 15) << 2));
        const int grow = row0 + r * 4;
        const int b0 = grow / 1025, b3 = (grow + 3) / 1025;
        if (b0 == b3 && grow + 3 < 4100) {
          const int s = grow - b0 * 1025;
          *(ushort4*)(Vt + ((size_t)(b0 * 16 + h) * 64 + d) * 1088 + s) = vv;
        } else {
          unsigned short tmp[4] = {vv.x, vv.y, vv.z, vv.w};
          for (int k2 = 0; k2 < 4; ++k2) {
            const int gr = grow + k2;
            if (gr >= 4100) break;
            const int bb = gr / 1025, ss = gr - bb * 1025;
            Vt[((size_t)(bb * 16 + h) * 64 + d) * 1088 + ss] = tmp[k2];
          }
        }
      }
    }
  }
}

// ---------------- attention: causal + sink, balanced strip pairs, swizzled LDS ----------------
__global__ __launch_bounds__(128) void k_attn(const unsigned short* __restrict__ Qh,
    const unsigned short* __restrict__ Kh, const unsigned short* __restrict__ Vt,
    unsigned short* __restrict__ Hb) {
  __shared__ __align__(16) short Kl[2][64 * 64];
  __shared__ __align__(16) short Vl[2][64 * 64];
  __shared__ __align__(16) short Pl[2 * 16 * 64];
  const int wid = blockIdx.x;
  const int xcd = wid & 7, jj = wid >> 3;
  const int bh = xcd + 8 * (jj >> 4), pp = jj & 15;
  const int b = bh >> 4, hh = bh & 15;
  const int t = threadIdx.x, l = t & 63, w = t >> 6;
  const int r = l & 15, g = l >> 4;

  auto stage = [&](int buf, int kt) {
    for (int i = 0; i < 2; ++i) {
      int c = i * 128 + t;
      int row = c >> 3, ch = c & 7;
      int sch = ch ^ (row & 7);
      async16(Kh + ((size_t)bh * 1088 + kt * 64 + row) * 64 + sch * 8,
              Kl[buf] + (i * 128 + w * 64) * 8);
      async16(Vt + ((size_t)bh * 64 + row) * 1088 + kt * 64 + sch * 8,
              Vl[buf] + (i * 128 + w * 64) * 8);
    }
    for (int i = 2; i < 4; ++i) {
      int c = i * 128 + t;
      int row = c >> 3, ch = c & 7;
      int sch = ch ^ (row & 7);
      async16(Kh + ((size_t)bh * 1088 + kt * 64 + row) * 64 + sch * 8,
              Kl[buf] + (i * 128 + w * 64) * 8);
      async16(Vt + ((size_t)bh * 64 + row) * 1088 + kt * 64 + sch * 8,
              Vl[buf] + (i * 128 + w * 64) * 8);
    }
  };

  for (int sidx = 0; sidx < 2; ++sidx) {
    const int strip = sidx == 0 ? pp : 31 - pp;
    const int qrow0 = strip * 32 + w * 16;
    short8 qf[2];
    for (int ks = 0; ks < 2; ++ks)
      qf[ks] = *(const short8*)(Qh + ((size_t)bh * 1088 + qrow0 + r) * 64 + ks * 32 + g * 8);
    const int nt = strip / 2 + 2;
    f32x4 oacc[4] = {};
    float lsum[4] = {0.f, 0.f, 0.f, 0.f};
    stage(0, 0);
    __syncthreads();
    int cur = 0;
    for (int i = 0; i < nt; ++i) {
      const int kt = (i < nt - 1) ? i : 16;
      if (i + 1 < nt) stage(cur ^ 1, (i + 1 < nt - 1) ? (i + 1) : 16);
      for (int nc = 0; nc < 4; ++nc) {
        f32x4 sc = {};
        for (int ks = 0; ks < 2; ++ks) {
          const int row = nc * 16 + r;
          const short8 kf = *(const short8*)(Kl[cur] + row * 64 + (((ks * 4 + g) ^ (row & 7)) << 3));
          sc = __builtin_amdgcn_mfma_f32_16x16x32_bf16(qf[ks], kf, sc, 0, 0, 0);
        }
        const int col = kt * 64 + nc * 16 + r;
        for (int j = 0; j < 4; ++j) {
          const int qrow = qrow0 + g * 4 + j;
          const bool valid = (col <= qrow) || (col == 1024);
          float p = valid ? __expf(sc[j]) : 0.0f;
          unsigned short pb = f2bf(p);
          lsum[j] += bf2f(pb);
          const int prow = w * 16 + g * 4 + j;
          const int bir = (nc * 16 + r) * 2;
          char* pd = (char*)Pl + prow * 128 + ((((unsigned)bir >> 4) ^ (prow & 7)) << 4) + (bir & 15);
          *(short*)pd = (short)pb;
        }
      }
      for (int ks = 0; ks < 2; ++ks) {
        const int prow = w * 16 + r;
        const short8 pf = *(const short8*)((char*)Pl + prow * 128 + (((ks * 4 + g) ^ (r & 7)) << 4));
        for (int nd = 0; nd < 4; ++nd) {
          const int vrow = nd * 16 + r;
          const short8 vf = *(const short8*)(Vl[cur] + vrow * 64 + (((ks * 4 + g) ^ (vrow & 7)) << 3));
          oacc[nd] = __builtin_amdgcn_mfma_f32_16x16x32_bf16(pf, vf, oacc[nd], 0, 0, 0);
        }
      }
      __syncthreads();
      cur ^= 1;
    }
    float inv[4];
    for (int j = 0; j < 4; ++j) {
      float v = lsum[j];
      v += __shfl_xor(v, 1); v += __shfl_xor(v, 2);
      v += __shfl_xor(v, 4); v += __shfl_xor(v, 8);
      inv[j] = 1.0f / v;
    }
    for (int nd = 0; nd < 4; ++nd)
      for (int j = 0; j < 4; ++j) {
        const int srow = qrow0 + g * 4 + j;
        Hb[((size_t)(b * 1024 + srow)) * 1024 + hh * 64 + nd * 16 + r] = f2bf(oacc[nd][j] * inv[j]);
      }
  }
}

// ---------------- launcher ----------------
extern "C" void kernel_launch(void* const* d_in, const int* in_sizes, int n_in,
                              void* d_out, int out_size, void* d_ws, size_t ws_size,
                              hipStream_t stream) {
  const float* x     = (const float*)d_in[0];
  const float* re    = (const float*)d_in[1];
  const float* w_qkv = (const float*)d_in[3];
  const float* w_out = (const float*)d_in[4];
  const float* sink  = (const float*)d_in[5];
  char* ws = (char*)d_ws;

  unsigned short* Wq  = (unsigned short*)(ws + 0);          // 3072*1024 bf16
  unsigned short* Wo  = (unsigned short*)(ws + 6291456);    // 1024*1024 bf16
  unsigned short* Xe  = (unsigned short*)(ws + 8388608);    // 4352*1024 bf16
  unsigned short* Hb  = (unsigned short*)(ws + 17301504);   // 4096*1024 bf16
  unsigned short* Qh  = (unsigned short*)(ws + 25690112);   // 64*1088*64 bf16
  unsigned short* Kh  = (unsigned short*)(ws + 34603008);   // 64*1088*64 bf16
  unsigned short* Vt  = (unsigned short*)(ws + 43515904);   // 64*64*1088 bf16
  float*          ctT = (float*)(ws + 52428800);            // 16*1024 f32
  float*          stT = (float*)(ws + 52494336);            // 16*1024 f32
  float*          sc  = (float*)(ws + 52559872);            // scalars + 64 spread cells
  float*          out = (float*)d_out;

  k_init_trig<<<64, 256, 0, stream>>>(re, ctT, stT, sc);
  k_wnorm<<<768, 256, 0, stream>>>(w_qkv, Wq, 3072);
  k_wnorm<<<256, 256, 0, stream>>>(w_out, Wo, 1024);
  k_xext<<<4352, 256, 0, stream>>>(x, sink, Xe, sc);
  k_gemm128<1><<<34 * 24, 256, 0, stream>>>(Xe, Wq, nullptr, 3072, 1024, 24,
                                            Qh, Kh, Vt, ctT, stT, sc);
  k_attn<<<1024, 128, 0, stream>>>(Qh, Kh, Vt, Hb);
  k_rownormB<<<256, 256, 0, stream>>>(Hb, sc + 1);
  k_gemm128<0><<<32 * 8, 256, 0, stream>>>(Hb, Wo, out, 1024, 1024, 8,
                                           nullptr, nullptr, nullptr, ctT, stT, sc);
}

// Round 10
// 119.620 us; speedup vs baseline: 2.5611x; 1.0137x over previous
//
#include <hip/hip_runtime.h>
#include <hip/hip_bf16.h>
#include <cstdint>

typedef __attribute__((ext_vector_type(8))) short short8;
typedef __attribute__((ext_vector_type(4))) float f32x4;

typedef const unsigned int __attribute__((address_space(1)))* gas_ptr;
typedef unsigned int __attribute__((address_space(3)))* las_ptr;

__device__ static inline void async16(const void* g, void* l) {
  __builtin_amdgcn_global_load_lds((gas_ptr)g, (las_ptr)l, 16, 0, 0);
}

__device__ static inline unsigned short f2bf(float f) {
  union { float f; uint32_t u; } v; v.f = f;
  uint32_t u = v.u;
  uint32_t r = (u + 0x7FFFu + ((u >> 16) & 1u)) >> 16;
  return (unsigned short)r;
}
__device__ static inline float bf2f(unsigned short s) {
  union { uint32_t u; float f; } v; v.u = ((uint32_t)s) << 16; return v.f;
}

__device__ static inline float wave_sum(float v) {
  v += __shfl_xor(v, 1);  v += __shfl_xor(v, 2);  v += __shfl_xor(v, 4);
  v += __shfl_xor(v, 8);  v += __shfl_xor(v, 16); v += __shfl_xor(v, 32);
  return v;
}

#define SBAR __builtin_amdgcn_sched_barrier(0)

// ---------------- small utility kernels ----------------

// zero scalars+cells, build transposed trig tables ctT/stT[16][1024]
__global__ __launch_bounds__(256) void k_init_trig(const float* __restrict__ re,
    float* __restrict__ ctT, float* __restrict__ stT, float* __restrict__ sc) {
  int i = blockIdx.x * 256 + threadIdx.x;   // 16384 threads
  if (i < 1040) sc[i] = 0.0f;
  int s = i >> 4, r = i & 15;
  float f = re[s * 32 + r];
  ctT[r * 1024 + s] = cosf(f);
  stT[r * 1024 + s] = sinf(f);
}

__global__ __launch_bounds__(256) void k_wnorm(const float* __restrict__ W,
                                               unsigned short* __restrict__ E, int rows) {
  int row = blockIdx.x * 4 + (threadIdx.x >> 6);
  int l = threadIdx.x & 63;
  if (row >= rows) return;
  const float* wr = W + (size_t)row * 1024;
  float4 v[4];
  float s = 0.f;
  for (int i = 0; i < 4; ++i) {
    v[i] = *(const float4*)(wr + i * 256 + l * 4);
    s += v[i].x * v[i].x + v[i].y * v[i].y + v[i].z * v[i].z + v[i].w * v[i].w;
  }
  s = wave_sum(s);
  float inv = 1.0f / (0.0032f + sqrtf(s));
  unsigned short* er = E + (size_t)row * 1024;
  for (int i = 0; i < 4; ++i) {
    ushort4 o = make_ushort4(f2bf(v[i].x * inv), f2bf(v[i].y * inv),
                             f2bf(v[i].z * inv), f2bf(v[i].w * inv));
    *(ushort4*)(er + i * 256 + l * 4) = o;
  }
}

// build x_ext bf16 [4352][1024] AND accumulate sum of row L2 norms into spread cells
__global__ __launch_bounds__(256) void k_xext(const float* __restrict__ x,
    const float* __restrict__ sink, unsigned short* __restrict__ Xe,
    float* __restrict__ sc) {
  __shared__ float red[4];
  const int row = blockIdx.x;
  const int tid = threadIdx.x, w = tid >> 6, l = tid & 63;
  const int c4 = tid * 4;
  float4 v = make_float4(0.f, 0.f, 0.f, 0.f);
  if (row < 4100) {
    int b = row / 1025, s = row - b * 1025;
    const float* src = (s < 1024) ? (x + ((size_t)(b * 1024 + s)) * 1024 + c4) : (sink + c4);
    v = *(const float4*)src;
  }
  *(ushort4*)(Xe + (size_t)row * 1024 + c4) =
      make_ushort4(f2bf(v.x), f2bf(v.y), f2bf(v.z), f2bf(v.w));
  float ss = v.x * v.x + v.y * v.y + v.z * v.z + v.w * v.w;
  ss = wave_sum(ss);
  if (l == 0) red[w] = ss;
  __syncthreads();
  if (tid == 0 && row < 4100)
    atomicAdd(sc + 16 + (row & 63) * 16, sqrtf(red[0] + red[1] + red[2] + red[3]));
}

// sum of row L2 norms of Hb (bf16 [4096][1024]) -> sc[1]
__global__ __launch_bounds__(256) void k_rownormB(const unsigned short* __restrict__ Hb,
                                                  float* __restrict__ acc) {
  __shared__ float red[4];
  const int w = threadIdx.x >> 6, l = threadIdx.x & 63;
  float local = 0.f;
  for (int row = blockIdx.x * 4 + w; row < 4096; row += gridDim.x * 4) {
    const unsigned short* hr = Hb + (size_t)row * 1024;
    float s = 0.f;
    for (int i = 0; i < 2; ++i) {
      short8 v = *(const short8*)(hr + i * 512 + l * 8);
      #pragma unroll
      for (int k = 0; k < 8; ++k) { float f = bf2f((unsigned short)v[k]); s += f * f; }
    }
    s = wave_sum(s);
    local += sqrtf(s);
  }
  if (l == 0) red[w] = local;
  __syncthreads();
  if (threadIdx.x == 0)
    atomicAdd(acc, red[0] + red[1] + red[2] + red[3]);
}

// ---------------- unified GEMM (m97 structure, swizzled, XCD-remapped, 4 blocks/CU) ----
// C[M][N] = A[M][K] * B[N][K]^T.
// EPI=1: BM=128, fused QKV epilogue (RoPE+norm+Vt). EPI=0: BM=64, f32 C scaled by ratio.
template<int EPI>
__global__ __launch_bounds__(256, 4) void k_gemm128(
    const unsigned short* __restrict__ A, const unsigned short* __restrict__ B,
    float* __restrict__ C, int N, int K, int ntn,
    unsigned short* __restrict__ Qh, unsigned short* __restrict__ Kh,
    unsigned short* __restrict__ Vt,
    const float* __restrict__ ctT, const float* __restrict__ stT,
    const float* __restrict__ sc) {
  constexpr int BM = EPI ? 128 : 64;
  constexpr int MI = BM / 32;                 // acc m-fragments per wave
  __shared__ __align__(16) short SMEM[(BM + 128) * 64];
  short* Al = SMEM;                           // BM x 64
  short* Bl = SMEM + BM * 64;                 // 128 x 64
  const int t = threadIdx.x, l = t & 63, w = t >> 6;
  const int r = l & 15, g = l >> 4;
  const int wm = w >> 1, wn = w & 1;
  // bijective XCD swizzle (m204)
  const int nwg = gridDim.x;
  const int q = nwg >> 3, rr = nwg & 7;
  const int xcd = blockIdx.x & 7, loc = blockIdx.x >> 3;
  const int wgid = (xcd < rr ? xcd * (q + 1) : rr * (q + 1) + (xcd - rr) * q) + loc;
  const int tm = wgid / ntn, tn = wgid % ntn;
  const size_t am0 = (size_t)tm * BM, bn0 = (size_t)tn * 128;

  f32x4 acc[MI][4] = {};
  for (int kt = 0; kt < K; kt += 64) {
    __syncthreads();
    // stage: LDS[row][ch] = global[row][ch ^ (row&7)]  (linear dest, pre-swizzled src)
    #pragma unroll
    for (int i = 0; i < BM / 32; ++i) {
      int c = i * 256 + t;
      int row = c >> 3, sch = (c & 7) ^ (row & 7);
      async16(A + (am0 + row) * (size_t)K + kt + sch * 8, Al + (i * 256 + w * 64) * 8);
    }
    #pragma unroll
    for (int i = 0; i < 4; ++i) {
      int c = i * 256 + t;
      int row = c >> 3, sch = (c & 7) ^ (row & 7);
      async16(B + (bn0 + row) * (size_t)K + kt + sch * 8, Bl + (i * 256 + w * 64) * 8);
    }
    __syncthreads();
    #pragma unroll
    for (int ks = 0; ks < 2; ++ks) {
      short8 af[MI], bfr[4];
      #pragma unroll
      for (int mi = 0; mi < MI; ++mi) {
        const int arow = wm * (MI * 16) + mi * 16 + r;
        af[mi] = *(const short8*)(Al + arow * 64 + (((ks * 4 + g) ^ (arow & 7)) << 3));
      }
      #pragma unroll
      for (int ni = 0; ni < 4; ++ni) {
        const int brow = wn * 64 + ni * 16 + r;
        bfr[ni] = *(const short8*)(Bl + brow * 64 + (((ks * 4 + g) ^ (brow & 7)) << 3));
      }
      #pragma unroll
      for (int mi = 0; mi < MI; ++mi)
        #pragma unroll
        for (int ni = 0; ni < 4; ++ni)
          acc[mi][ni] = __builtin_amdgcn_mfma_f32_16x16x32_bf16(af[mi], bfr[ni], acc[mi][ni], 0, 0, 0);
    }
  }

  if constexpr (EPI == 0) {
    // ratio = (mean x_ext row norm) / (mean h row norm)
    float num = 0.f;
    #pragma unroll
    for (int i = 0; i < 64; ++i) num += sc[16 + i * 16];
    const float ratio = (num * (1.0f / 4100.0f)) * (4096.0f / sc[1]);
    #pragma unroll
    for (int mi = 0; mi < MI; ++mi)
      #pragma unroll
      for (int ni = 0; ni < 4; ++ni)
        #pragma unroll
        for (int j = 0; j < 4; ++j) {
          size_t row = am0 + wm * (MI * 16) + mi * 16 + g * 4 + j;
          size_t col = bn0 + wn * 64 + ni * 16 + r;
          C[row * (size_t)N + col] = acc[mi][ni][j] * ratio;
        }
  } else {
    __syncthreads();   // drain all waves' LDS reads before SMEM reuse
    const int head_global = tn * 2 + wn;   // 0..47, wave-uniform
    const int sel = head_global >> 4;      // 0=q, 1=k, 2=v
    const int h = head_global & 15;
    const int row0 = (int)am0 + wm * 64;

    if (sel < 2) {
      unsigned short* dst = (sel == 0) ? Qh : Kh;
      #pragma unroll
      for (int mi = 0; mi < 4; ++mi) {
        const int rowb = row0 + mi * 16 + g * 4;
        const int b = rowb / 1025;
        const int s0 = rowb - b * 1025;
        float cs[4], sn[4];
        if (s0 + 3 < 1024) {
          float4 c4 = *(const float4*)(ctT + r * 1024 + s0);
          float4 s4 = *(const float4*)(stT + r * 1024 + s0);
          cs[0] = c4.x; cs[1] = c4.y; cs[2] = c4.z; cs[3] = c4.w;
          sn[0] = s4.x; sn[1] = s4.y; sn[2] = s4.z; sn[3] = s4.w;
        } else {
          #pragma unroll
          for (int j = 0; j < 4; ++j) {
            const int rj = rowb + j;
            const int bj = rj / 1025, sj = rj - bj * 1025;
            cs[j] = (sj < 1024) ? ctT[r * 1024 + sj] : 1.f;
            sn[j] = (sj < 1024) ? stT[r * 1024 + sj] : 0.f;
          }
        }
        #pragma unroll
        for (int j = 0; j < 4; ++j) {
          const int row = rowb + j;
          const int b2 = row / 1025, s = row - b2 * 1025;
          const float a0 = acc[mi][0][j], a1 = acc[mi][1][j];
          const float a2 = acc[mi][2][j], a3 = acc[mi][3][j];
          const float r0 = a0 * cs[j] - a1 * sn[j];
          const float r1 = a1 * cs[j] + a0 * sn[j];
          float nrm = r0 * r0 + r1 * r1 + a2 * a2 + a3 * a3;
          nrm += __shfl_xor(nrm, 1); nrm += __shfl_xor(nrm, 2);
          nrm += __shfl_xor(nrm, 4); nrm += __shfl_xor(nrm, 8);
          const float inv = rsqrtf(nrm);
          if (row < 4100) {
            const size_t base = ((size_t)(b2 * 16 + h) * 1088 + s) * 64 + r;
            dst[base]      = f2bf(r0 * inv);
            dst[base + 16] = f2bf(r1 * inv);
            dst[base + 32] = f2bf(a2 * inv);
            dst[base + 48] = f2bf(a3 * inv);
          }
        }
      }
    } else {
      // V: per-wave LDS transpose. vs[d][slot] as ushort4 slots, slot' = slot ^ (d&15).
      short* vs = SMEM + w * 4096;   // 8 KiB per wave: 64 d-rows x 64 shorts
      #pragma unroll
      for (int mi = 0; mi < 4; ++mi) {
        const int slot = mi * 4 + g;       // seq chunk (mi*16+g*4)/4
        #pragma unroll
        for (int ni = 0; ni < 4; ++ni) {
          const int d = ni * 16 + r;
          ushort4 pk = make_ushort4(f2bf(acc[mi][ni][0]), f2bf(acc[mi][ni][1]),
                                    f2bf(acc[mi][ni][2]), f2bf(acc[mi][ni][3]));
          *(ushort4*)(vs + d * 64 + ((slot ^ (d & 15)) << 2)) = pk;
        }
      }
      asm volatile("s_waitcnt lgkmcnt(0)" ::: "memory"); SBAR;
      #pragma unroll
      for (int ii = 0; ii < 16; ++ii) {
        const int d = ii * 4 + g;          // 0..63
        ushort4 vv = *(const ushort4*)(vs + d * 64 + (((r ^ (d & 15)) & 15) << 2));
        const int grow = row0 + r * 4;
        const int b0 = grow / 1025, b3 = (grow + 3) / 1025;
        if (b0 == b3 && grow + 3 < 4100) {
          const int s = grow - b0 * 1025;
          *(ushort4*)(Vt + ((size_t)(b0 * 16 + h) * 64 + d) * 1088 + s) = vv;
        } else {
          unsigned short tmp[4] = {vv.x, vv.y, vv.z, vv.w};
          for (int k2 = 0; k2 < 4; ++k2) {
            const int gr = grow + k2;
            if (gr >= 4100) break;
            const int bb = gr / 1025, ss = gr - bb * 1025;
            Vt[((size_t)(bb * 16 + h) * 64 + d) * 1088 + ss] = tmp[k2];
          }
        }
      }
    }
  }
}

// ---------------- attention: causal + sink, balanced strip pairs, swizzled LDS ----------------
__global__ __launch_bounds__(128) void k_attn(const unsigned short* __restrict__ Qh,
    const unsigned short* __restrict__ Kh, const unsigned short* __restrict__ Vt,
    unsigned short* __restrict__ Hb) {
  __shared__ __align__(16) short Kl[2][64 * 64];
  __shared__ __align__(16) short Vl[2][64 * 64];
  __shared__ __align__(16) short Pl[2 * 16 * 64];
  const int wid = blockIdx.x;
  const int xcd = wid & 7, jj = wid >> 3;
  const int bh = xcd + 8 * (jj >> 4), pp = jj & 15;
  const int b = bh >> 4, hh = bh & 15;
  const int t = threadIdx.x, l = t & 63, w = t >> 6;
  const int r = l & 15, g = l >> 4;

  auto stage = [&](int buf, int kt) {
    for (int i = 0; i < 4; ++i) {
      int c = i * 128 + t;
      int row = c >> 3, ch = c & 7;
      int sch = ch ^ (row & 7);
      async16(Kh + ((size_t)bh * 1088 + kt * 64 + row) * 64 + sch * 8,
              Kl[buf] + (i * 128 + w * 64) * 8);
      async16(Vt + ((size_t)bh * 64 + row) * 1088 + kt * 64 + sch * 8,
              Vl[buf] + (i * 128 + w * 64) * 8);
    }
  };

  for (int sidx = 0; sidx < 2; ++sidx) {
    const int strip = sidx == 0 ? pp : 31 - pp;
    const int qrow0 = strip * 32 + w * 16;
    short8 qf[2];
    for (int ks = 0; ks < 2; ++ks)
      qf[ks] = *(const short8*)(Qh + ((size_t)bh * 1088 + qrow0 + r) * 64 + ks * 32 + g * 8);
    const int nt = strip / 2 + 2;
    f32x4 oacc[4] = {};
    float lsum[4] = {0.f, 0.f, 0.f, 0.f};
    stage(0, 0);
    __syncthreads();
    int cur = 0;
    for (int i = 0; i < nt; ++i) {
      const int kt = (i < nt - 1) ? i : 16;
      if (i + 1 < nt) stage(cur ^ 1, (i + 1 < nt - 1) ? (i + 1) : 16);
      for (int nc = 0; nc < 4; ++nc) {
        f32x4 sc = {};
        for (int ks = 0; ks < 2; ++ks) {
          const int row = nc * 16 + r;
          const short8 kf = *(const short8*)(Kl[cur] + row * 64 + (((ks * 4 + g) ^ (row & 7)) << 3));
          sc = __builtin_amdgcn_mfma_f32_16x16x32_bf16(qf[ks], kf, sc, 0, 0, 0);
        }
        const int col = kt * 64 + nc * 16 + r;
        for (int j = 0; j < 4; ++j) {
          const int qrow = qrow0 + g * 4 + j;
          const bool valid = (col <= qrow) || (col == 1024);
          float p = valid ? __expf(sc[j]) : 0.0f;
          unsigned short pb = f2bf(p);
          lsum[j] += bf2f(pb);
          const int prow = w * 16 + g * 4 + j;
          const int bir = (nc * 16 + r) * 2;
          char* pd = (char*)Pl + prow * 128 + ((((unsigned)bir >> 4) ^ (prow & 7)) << 4) + (bir & 15);
          *(short*)pd = (short)pb;
        }
      }
      for (int ks = 0; ks < 2; ++ks) {
        const int prow = w * 16 + r;
        const short8 pf = *(const short8*)((char*)Pl + prow * 128 + (((ks * 4 + g) ^ (r & 7)) << 4));
        for (int nd = 0; nd < 4; ++nd) {
          const int vrow = nd * 16 + r;
          const short8 vf = *(const short8*)(Vl[cur] + vrow * 64 + (((ks * 4 + g) ^ (vrow & 7)) << 3));
          oacc[nd] = __builtin_amdgcn_mfma_f32_16x16x32_bf16(pf, vf, oacc[nd], 0, 0, 0);
        }
      }
      __syncthreads();
      cur ^= 1;
    }
    float inv[4];
    for (int j = 0; j < 4; ++j) {
      float v = lsum[j];
      v += __shfl_xor(v, 1); v += __shfl_xor(v, 2);
      v += __shfl_xor(v, 4); v += __shfl_xor(v, 8);
      inv[j] = 1.0f / v;
    }
    for (int nd = 0; nd < 4; ++nd)
      for (int j = 0; j < 4; ++j) {
        const int srow = qrow0 + g * 4 + j;
        Hb[((size_t)(b * 1024 + srow)) * 1024 + hh * 64 + nd * 16 + r] = f2bf(oacc[nd][j] * inv[j]);
      }
  }
}

// ---------------- launcher ----------------
extern "C" void kernel_launch(void* const* d_in, const int* in_sizes, int n_in,
                              void* d_out, int out_size, void* d_ws, size_t ws_size,
                              hipStream_t stream) {
  const float* x     = (const float*)d_in[0];
  const float* re    = (const float*)d_in[1];
  const float* w_qkv = (const float*)d_in[3];
  const float* w_out = (const float*)d_in[4];
  const float* sink  = (const float*)d_in[5];
  char* ws = (char*)d_ws;

  unsigned short* Wq  = (unsigned short*)(ws + 0);          // 3072*1024 bf16
  unsigned short* Wo  = (unsigned short*)(ws + 6291456);    // 1024*1024 bf16
  unsigned short* Xe  = (unsigned short*)(ws + 8388608);    // 4352*1024 bf16
  unsigned short* Hb  = (unsigned short*)(ws + 17301504);   // 4096*1024 bf16
  unsigned short* Qh  = (unsigned short*)(ws + 25690112);   // 64*1088*64 bf16
  unsigned short* Kh  = (unsigned short*)(ws + 34603008);   // 64*1088*64 bf16
  unsigned short* Vt  = (unsigned short*)(ws + 43515904);   // 64*64*1088 bf16
  float*          ctT = (float*)(ws + 52428800);            // 16*1024 f32
  float*          stT = (float*)(ws + 52494336);            // 16*1024 f32
  float*          sc  = (float*)(ws + 52559872);            // scalars + 64 spread cells
  float*          out = (float*)d_out;

  k_init_trig<<<64, 256, 0, stream>>>(re, ctT, stT, sc);
  k_wnorm<<<768, 256, 0, stream>>>(w_qkv, Wq, 3072);
  k_wnorm<<<256, 256, 0, stream>>>(w_out, Wo, 1024);
  k_xext<<<4352, 256, 0, stream>>>(x, sink, Xe, sc);
  k_gemm128<1><<<34 * 24, 256, 0, stream>>>(Xe, Wq, nullptr, 3072, 1024, 24,
                                            Qh, Kh, Vt, ctT, stT, sc);
  k_attn<<<1024, 128, 0, stream>>>(Qh, Kh, Vt, Hb);
  k_rownormB<<<256, 256, 0, stream>>>(Hb, sc + 1);
  k_gemm128<0><<<64 * 8, 256, 0, stream>>>(Hb, Wo, out, 1024, 1024, 8,
                                           nullptr, nullptr, nullptr, ctT, stT, sc);
}

// Round 11
// 103.904 us; speedup vs baseline: 2.9484x; 1.1513x over previous
//
#include <hip/hip_runtime.h>
#include <hip/hip_bf16.h>
#include <cstdint>

typedef __attribute__((ext_vector_type(8))) short short8;
typedef __attribute__((ext_vector_type(4))) float f32x4;

typedef const unsigned int __attribute__((address_space(1)))* gas_ptr;
typedef unsigned int __attribute__((address_space(3)))* las_ptr;

__device__ static inline void async16(const void* g, void* l) {
  __builtin_amdgcn_global_load_lds((gas_ptr)g, (las_ptr)l, 16, 0, 0);
}

__device__ static inline unsigned short f2bf(float f) {
  union { float f; uint32_t u; } v; v.f = f;
  uint32_t u = v.u;
  uint32_t r = (u + 0x7FFFu + ((u >> 16) & 1u)) >> 16;
  return (unsigned short)r;
}
__device__ static inline float bf2f(unsigned short s) {
  union { uint32_t u; float f; } v; v.u = ((uint32_t)s) << 16; return v.f;
}

__device__ static inline float wave_sum(float v) {
  v += __shfl_xor(v, 1);  v += __shfl_xor(v, 2);  v += __shfl_xor(v, 4);
  v += __shfl_xor(v, 8);  v += __shfl_xor(v, 16); v += __shfl_xor(v, 32);
  return v;
}

#define SBAR __builtin_amdgcn_sched_barrier(0)

// ---------------- fused preamble: xext(+rownorm) | trig tables | wnorm x2 ----------------
// grid 5440: [0,4352) xext, [4352,4416) trig, [4416,5184) wnorm Wq, [5184,5440) wnorm Wo
__global__ __launch_bounds__(256) void k_prep(const float* __restrict__ x,
    const float* __restrict__ sink, const float* __restrict__ re,
    const float* __restrict__ w_qkv, const float* __restrict__ w_out,
    unsigned short* __restrict__ Xe, unsigned short* __restrict__ Wq,
    unsigned short* __restrict__ Wo,
    float* __restrict__ ctT, float* __restrict__ stT, float* __restrict__ rowsn) {
  __shared__ float red[4];
  const int bid = blockIdx.x;
  const int tid = threadIdx.x, w = tid >> 6, l = tid & 63;
  if (bid < 4352) {
    const int row = bid;
    const int c4 = tid * 4;
    float4 v = make_float4(0.f, 0.f, 0.f, 0.f);
    if (row < 4100) {
      int b = row / 1025, s = row - b * 1025;
      const float* src = (s < 1024) ? (x + ((size_t)(b * 1024 + s)) * 1024 + c4) : (sink + c4);
      v = *(const float4*)src;
    }
    *(ushort4*)(Xe + (size_t)row * 1024 + c4) =
        make_ushort4(f2bf(v.x), f2bf(v.y), f2bf(v.z), f2bf(v.w));
    float ss = v.x * v.x + v.y * v.y + v.z * v.z + v.w * v.w;
    ss = wave_sum(ss);
    if (l == 0) red[w] = ss;
    __syncthreads();
    if (tid == 0) rowsn[row] = (row < 4100) ? sqrtf(red[0] + red[1] + red[2] + red[3]) : 0.f;
  } else if (bid < 4416) {
    int i = (bid - 4352) * 256 + tid;     // 0..16383
    int s = i >> 4, r2 = i & 15;
    float f = re[s * 32 + r2];
    ctT[r2 * 1024 + s] = cosf(f);
    stT[r2 * 1024 + s] = sinf(f);
  } else {
    const float* W; unsigned short* E; int row;
    if (bid < 5184) { W = w_qkv; E = Wq; row = (bid - 4416) * 4 + w; }
    else            { W = w_out; E = Wo; row = (bid - 5184) * 4 + w; }
    const float* wr = W + (size_t)row * 1024;
    float4 v[4];
    float s = 0.f;
    #pragma unroll
    for (int i = 0; i < 4; ++i) {
      v[i] = *(const float4*)(wr + i * 256 + l * 4);
      s += v[i].x * v[i].x + v[i].y * v[i].y + v[i].z * v[i].z + v[i].w * v[i].w;
    }
    s = wave_sum(s);
    float inv = 1.0f / (0.0032f + sqrtf(s));
    unsigned short* er = E + (size_t)row * 1024;
    #pragma unroll
    for (int i = 0; i < 4; ++i) {
      ushort4 o = make_ushort4(f2bf(v[i].x * inv), f2bf(v[i].y * inv),
                               f2bf(v[i].z * inv), f2bf(v[i].w * inv));
      *(ushort4*)(er + i * 256 + l * 4) = o;
    }
  }
}

// ---------------- final norm reduction: scp[bid]=Σrowsn chunk, scp[16+bid]=Σsqrt(rowsq) ----
__global__ __launch_bounds__(256) void k_rownormC(const float* __restrict__ rowsqp,
    const float* __restrict__ rowsn, float* __restrict__ scp) {
  __shared__ float red[4];
  const int bid = blockIdx.x, t = threadIdx.x, w = t >> 6, l = t & 63;
  const int row = bid * 256 + t;
  const float4* rp = (const float4*)(rowsqp + (size_t)row * 16);
  float4 a = rp[0], b = rp[1], c = rp[2], d = rp[3];
  float s = a.x + a.y + a.z + a.w + b.x + b.y + b.z + b.w +
            c.x + c.y + c.z + c.w + d.x + d.y + d.z + d.w;
  float v = sqrtf(s);
  v = wave_sum(v);
  if (l == 0) red[w] = v;
  __syncthreads();
  if (t == 0) scp[16 + bid] = red[0] + red[1] + red[2] + red[3];
  float u = 0.f;
  for (int k = t; k < 272; k += 256) u += rowsn[bid * 272 + k];
  u = wave_sum(u);
  __syncthreads();
  if (l == 0) red[w] = u;
  __syncthreads();
  if (t == 0) scp[bid] = red[0] + red[1] + red[2] + red[3];
}

// ---------------- unified GEMM (m97 structure, swizzled, XCD-remapped) ----------
// C[M][N] = A[M][K] * B[N][K]^T.
// EPI=1: BM=128, fused QKV epilogue (RoPE+norm+Vt). EPI=0: BM=64, f32 C scaled by ratio.
template<int EPI>
__global__ __launch_bounds__(256, 4) void k_gemm128(
    const unsigned short* __restrict__ A, const unsigned short* __restrict__ B,
    float* __restrict__ C, int N, int K, int ntn,
    unsigned short* __restrict__ Qh, unsigned short* __restrict__ Kh,
    unsigned short* __restrict__ Vt,
    const float* __restrict__ ctT, const float* __restrict__ stT,
    const float* __restrict__ scp) {
  constexpr int BM = EPI ? 128 : 64;
  constexpr int MI = BM / 32;                 // acc m-fragments per wave
  __shared__ __align__(16) short SMEM[(BM + 128) * 64];
  short* Al = SMEM;                           // BM x 64
  short* Bl = SMEM + BM * 64;                 // 128 x 64
  const int t = threadIdx.x, l = t & 63, w = t >> 6;
  const int r = l & 15, g = l >> 4;
  const int wm = w >> 1, wn = w & 1;
  // bijective XCD swizzle (m204)
  const int nwg = gridDim.x;
  const int q = nwg >> 3, rr = nwg & 7;
  const int xcd = blockIdx.x & 7, loc = blockIdx.x >> 3;
  const int wgid = (xcd < rr ? xcd * (q + 1) : rr * (q + 1) + (xcd - rr) * q) + loc;
  const int tm = wgid / ntn, tn = wgid % ntn;
  const size_t am0 = (size_t)tm * BM, bn0 = (size_t)tn * 128;

  f32x4 acc[MI][4] = {};
  for (int kt = 0; kt < K; kt += 64) {
    __syncthreads();
    // stage: LDS[row][ch] = global[row][ch ^ (row&7)]  (linear dest, pre-swizzled src)
    #pragma unroll
    for (int i = 0; i < BM / 32; ++i) {
      int c = i * 256 + t;
      int row = c >> 3, sch = (c & 7) ^ (row & 7);
      async16(A + (am0 + row) * (size_t)K + kt + sch * 8, Al + (i * 256 + w * 64) * 8);
    }
    #pragma unroll
    for (int i = 0; i < 4; ++i) {
      int c = i * 256 + t;
      int row = c >> 3, sch = (c & 7) ^ (row & 7);
      async16(B + (bn0 + row) * (size_t)K + kt + sch * 8, Bl + (i * 256 + w * 64) * 8);
    }
    __syncthreads();
    #pragma unroll
    for (int ks = 0; ks < 2; ++ks) {
      short8 af[MI], bfr[4];
      #pragma unroll
      for (int mi = 0; mi < MI; ++mi) {
        const int arow = wm * (MI * 16) + mi * 16 + r;
        af[mi] = *(const short8*)(Al + arow * 64 + (((ks * 4 + g) ^ (arow & 7)) << 3));
      }
      #pragma unroll
      for (int ni = 0; ni < 4; ++ni) {
        const int brow = wn * 64 + ni * 16 + r;
        bfr[ni] = *(const short8*)(Bl + brow * 64 + (((ks * 4 + g) ^ (brow & 7)) << 3));
      }
      #pragma unroll
      for (int mi = 0; mi < MI; ++mi)
        #pragma unroll
        for (int ni = 0; ni < 4; ++ni)
          acc[mi][ni] = __builtin_amdgcn_mfma_f32_16x16x32_bf16(af[mi], bfr[ni], acc[mi][ni], 0, 0, 0);
    }
  }

  if constexpr (EPI == 0) {
    float num = 0.f, den = 0.f;
    #pragma unroll
    for (int i = 0; i < 16; ++i) { num += scp[i]; den += scp[16 + i]; }
    const float ratio = (num * (1.0f / 4100.0f)) * (4096.0f / den);
    #pragma unroll
    for (int mi = 0; mi < MI; ++mi)
      #pragma unroll
      for (int ni = 0; ni < 4; ++ni)
        #pragma unroll
        for (int j = 0; j < 4; ++j) {
          size_t row = am0 + wm * (MI * 16) + mi * 16 + g * 4 + j;
          size_t col = bn0 + wn * 64 + ni * 16 + r;
          C[row * (size_t)N + col] = acc[mi][ni][j] * ratio;
        }
  } else {
    __syncthreads();   // drain all waves' LDS reads before SMEM reuse
    const int head_global = tn * 2 + wn;   // 0..47, wave-uniform
    const int sel = head_global >> 4;      // 0=q, 1=k, 2=v
    const int h = head_global & 15;
    const int row0 = (int)am0 + wm * 64;

    if (sel < 2) {
      unsigned short* dst = (sel == 0) ? Qh : Kh;
      #pragma unroll
      for (int mi = 0; mi < 4; ++mi) {
        const int rowb = row0 + mi * 16 + g * 4;
        const int b = rowb / 1025;
        const int s0 = rowb - b * 1025;
        float cs[4], sn[4];
        if (s0 + 3 < 1024) {
          float4 c4 = *(const float4*)(ctT + r * 1024 + s0);
          float4 s4 = *(const float4*)(stT + r * 1024 + s0);
          cs[0] = c4.x; cs[1] = c4.y; cs[2] = c4.z; cs[3] = c4.w;
          sn[0] = s4.x; sn[1] = s4.y; sn[2] = s4.z; sn[3] = s4.w;
        } else {
          #pragma unroll
          for (int j = 0; j < 4; ++j) {
            const int rj = rowb + j;
            const int bj = rj / 1025, sj = rj - bj * 1025;
            cs[j] = (sj < 1024) ? ctT[r * 1024 + sj] : 1.f;
            sn[j] = (sj < 1024) ? stT[r * 1024 + sj] : 0.f;
          }
        }
        #pragma unroll
        for (int j = 0; j < 4; ++j) {
          const int row = rowb + j;
          const int b2 = row / 1025, s = row - b2 * 1025;
          const float a0 = acc[mi][0][j], a1 = acc[mi][1][j];
          const float a2 = acc[mi][2][j], a3 = acc[mi][3][j];
          const float r0 = a0 * cs[j] - a1 * sn[j];
          const float r1 = a1 * cs[j] + a0 * sn[j];
          float nrm = r0 * r0 + r1 * r1 + a2 * a2 + a3 * a3;
          nrm += __shfl_xor(nrm, 1); nrm += __shfl_xor(nrm, 2);
          nrm += __shfl_xor(nrm, 4); nrm += __shfl_xor(nrm, 8);
          const float inv = rsqrtf(nrm);
          if (row < 4100) {
            const size_t base = ((size_t)(b2 * 16 + h) * 1088 + s) * 64 + r;
            dst[base]      = f2bf(r0 * inv);
            dst[base + 16] = f2bf(r1 * inv);
            dst[base + 32] = f2bf(a2 * inv);
            dst[base + 48] = f2bf(a3 * inv);
          }
        }
      }
    } else {
      // V: per-wave LDS transpose. vs[d][slot] as ushort4 slots, slot' = slot ^ (d&15).
      short* vs = SMEM + w * 4096;   // 8 KiB per wave: 64 d-rows x 64 shorts
      #pragma unroll
      for (int mi = 0; mi < 4; ++mi) {
        const int slot = mi * 4 + g;
        #pragma unroll
        for (int ni = 0; ni < 4; ++ni) {
          const int d = ni * 16 + r;
          ushort4 pk = make_ushort4(f2bf(acc[mi][ni][0]), f2bf(acc[mi][ni][1]),
                                    f2bf(acc[mi][ni][2]), f2bf(acc[mi][ni][3]));
          *(ushort4*)(vs + d * 64 + ((slot ^ (d & 15)) << 2)) = pk;
        }
      }
      asm volatile("s_waitcnt lgkmcnt(0)" ::: "memory"); SBAR;
      #pragma unroll
      for (int ii = 0; ii < 16; ++ii) {
        const int d = ii * 4 + g;
        ushort4 vv = *(const ushort4*)(vs + d * 64 + (((r ^ (d & 15)) & 15) << 2));
        const int grow = row0 + r * 4;
        const int b0 = grow / 1025, b3 = (grow + 3) / 1025;
        if (b0 == b3 && grow + 3 < 4100) {
          const int s = grow - b0 * 1025;
          *(ushort4*)(Vt + ((size_t)(b0 * 16 + h) * 64 + d) * 1088 + s) = vv;
        } else {
          unsigned short tmp[4] = {vv.x, vv.y, vv.z, vv.w};
          for (int k2 = 0; k2 < 4; ++k2) {
            const int gr = grow + k2;
            if (gr >= 4100) break;
            const int bb = gr / 1025, ss = gr - bb * 1025;
            Vt[((size_t)(bb * 16 + h) * 64 + d) * 1088 + ss] = tmp[k2];
          }
        }
      }
    }
  }
}

// ---------------- attention: 4 waves share staged K/V across strip pair ----------------
// Block = (bh, pp). Waves 0-1: strip pp rows; waves 2-3: strip 31-pp. One staging stream.
__global__ __launch_bounds__(256) void k_attn(const unsigned short* __restrict__ Qh,
    const unsigned short* __restrict__ Kh, const unsigned short* __restrict__ Vt,
    unsigned short* __restrict__ Hb, float* __restrict__ rowsqp) {
  __shared__ __align__(16) short Kl[2][64 * 64];
  __shared__ __align__(16) short Vl[2][64 * 64];
  __shared__ __align__(16) short Pl[64 * 64];
  const int wid = blockIdx.x;
  const int xcd = wid & 7, jj = wid >> 3;
  const int bh = xcd + 8 * (jj >> 4), pp = jj & 15;
  const int b = bh >> 4, hh = bh & 15;
  const int t = threadIdx.x, l = t & 63, w = t >> 6;
  const int r = l & 15, g = l >> 4;
  const int strip = (w < 2) ? pp : 31 - pp;
  const int qrow0 = strip * 32 + (w & 1) * 16;
  const int myNc = strip / 2 + 1;            // causal tiles this wave needs
  const int NTOT = (31 - pp) / 2 + 2;        // causal tiles of long strip + sink

  auto stage = [&](int buf, int kt) {
    #pragma unroll
    for (int i = 0; i < 2; ++i) {
      int c = i * 256 + t;
      int row = c >> 3, sch = (c & 7) ^ (row & 7);
      async16(Kh + ((size_t)bh * 1088 + kt * 64 + row) * 64 + sch * 8,
              Kl[buf] + (i * 256 + w * 64) * 8);
      async16(Vt + ((size_t)bh * 64 + row) * 1088 + kt * 64 + sch * 8,
              Vl[buf] + (i * 256 + w * 64) * 8);
    }
  };

  short8 qf[2];
  #pragma unroll
  for (int ks = 0; ks < 2; ++ks)
    qf[ks] = *(const short8*)(Qh + ((size_t)bh * 1088 + qrow0 + r) * 64 + ks * 32 + g * 8);
  f32x4 oacc[4] = {};
  float lsum[4] = {0.f, 0.f, 0.f, 0.f};
  stage(0, 0);
  __syncthreads();
  int cur = 0;
  for (int i = 0; i < NTOT; ++i) {
    const int kt = (i < NTOT - 1) ? i : 16;
    if (i + 1 < NTOT) stage(cur ^ 1, (i + 1 < NTOT - 1) ? (i + 1) : 16);
    const bool active = (i < myNc) || (i == NTOT - 1);   // wave-uniform
    if (active) {
      for (int nc = 0; nc < 4; ++nc) {
        f32x4 sc = {};
        #pragma unroll
        for (int ks = 0; ks < 2; ++ks) {
          const int row = nc * 16 + r;
          const short8 kf = *(const short8*)(Kl[cur] + row * 64 + (((ks * 4 + g) ^ (row & 7)) << 3));
          sc = __builtin_amdgcn_mfma_f32_16x16x32_bf16(qf[ks], kf, sc, 0, 0, 0);
        }
        const int col = kt * 64 + nc * 16 + r;
        #pragma unroll
        for (int j = 0; j < 4; ++j) {
          const int qrow = qrow0 + g * 4 + j;
          const bool valid = (col <= qrow) || (col == 1024);
          float p = valid ? __expf(sc[j]) : 0.0f;
          unsigned short pb = f2bf(p);
          lsum[j] += bf2f(pb);
          const int prow = w * 16 + g * 4 + j;
          const int bir = (nc * 16 + r) * 2;
          char* pd = (char*)Pl + prow * 128 + ((((unsigned)bir >> 4) ^ (prow & 7)) << 4) + (bir & 15);
          *(short*)pd = (short)pb;
        }
      }
      #pragma unroll
      for (int ks = 0; ks < 2; ++ks) {
        const int prow = w * 16 + r;
        const short8 pf = *(const short8*)((char*)Pl + prow * 128 + (((ks * 4 + g) ^ (r & 7)) << 4));
        #pragma unroll
        for (int nd = 0; nd < 4; ++nd) {
          const int vrow = nd * 16 + r;
          const short8 vf = *(const short8*)(Vl[cur] + vrow * 64 + (((ks * 4 + g) ^ (vrow & 7)) << 3));
          oacc[nd] = __builtin_amdgcn_mfma_f32_16x16x32_bf16(pf, vf, oacc[nd], 0, 0, 0);
        }
      }
    }
    __syncthreads();
    cur ^= 1;
  }
  float inv[4];
  #pragma unroll
  for (int j = 0; j < 4; ++j) {
    float v = lsum[j];
    v += __shfl_xor(v, 1); v += __shfl_xor(v, 2);
    v += __shfl_xor(v, 4); v += __shfl_xor(v, 8);
    inv[j] = 1.0f / v;
  }
  #pragma unroll
  for (int j = 0; j < 4; ++j) {
    const int srow = qrow0 + g * 4 + j;
    float sq = 0.f;
    #pragma unroll
    for (int nd = 0; nd < 4; ++nd) {
      const float hv = oacc[nd][j] * inv[j];
      Hb[((size_t)(b * 1024 + srow)) * 1024 + hh * 64 + nd * 16 + r] = f2bf(hv);
      sq += hv * hv;
    }
    sq += __shfl_xor(sq, 1); sq += __shfl_xor(sq, 2);
    sq += __shfl_xor(sq, 4); sq += __shfl_xor(sq, 8);
    if (r == 0) rowsqp[(size_t)(b * 1024 + srow) * 16 + hh] = sq;
  }
}

// ---------------- launcher ----------------
extern "C" void kernel_launch(void* const* d_in, const int* in_sizes, int n_in,
                              void* d_out, int out_size, void* d_ws, size_t ws_size,
                              hipStream_t stream) {
  const float* x     = (const float*)d_in[0];
  const float* re    = (const float*)d_in[1];
  const float* w_qkv = (const float*)d_in[3];
  const float* w_out = (const float*)d_in[4];
  const float* sink  = (const float*)d_in[5];
  char* ws = (char*)d_ws;

  unsigned short* Wq   = (unsigned short*)(ws + 0);          // 3072*1024 bf16
  unsigned short* Wo   = (unsigned short*)(ws + 6291456);    // 1024*1024 bf16
  unsigned short* Xe   = (unsigned short*)(ws + 8388608);    // 4352*1024 bf16
  unsigned short* Hb   = (unsigned short*)(ws + 17301504);   // 4096*1024 bf16
  unsigned short* Qh   = (unsigned short*)(ws + 25690112);   // 64*1088*64 bf16
  unsigned short* Kh   = (unsigned short*)(ws + 34603008);   // 64*1088*64 bf16
  unsigned short* Vt   = (unsigned short*)(ws + 43515904);   // 64*64*1088 bf16
  float*          ctT  = (float*)(ws + 52428800);            // 16*1024 f32
  float*          stT  = (float*)(ws + 52494336);            // 16*1024 f32
  float*          scp  = (float*)(ws + 52559872);            // 32 f32 partials
  float*          rowsn  = (float*)(ws + 52560384);          // 4352 f32
  float*          rowsqp = (float*)(ws + 52577792);          // 4096*16 f32
  float*          out  = (float*)d_out;

  k_prep<<<5440, 256, 0, stream>>>(x, sink, re, w_qkv, w_out, Xe, Wq, Wo, ctT, stT, rowsn);
  k_gemm128<1><<<34 * 24, 256, 0, stream>>>(Xe, Wq, nullptr, 3072, 1024, 24,
                                            Qh, Kh, Vt, ctT, stT, scp);
  k_attn<<<1024, 256, 0, stream>>>(Qh, Kh, Vt, Hb, rowsqp);
  k_rownormC<<<16, 256, 0, stream>>>(rowsqp, rowsn, scp);
  k_gemm128<0><<<64 * 8, 256, 0, stream>>>(Hb, Wo, out, 1024, 1024, 8,
                                           nullptr, nullptr, nullptr, ctT, stT, scp);
}